// Round 2
// baseline (3430.133 us; speedup 1.0000x reference)
//
#include <hip/hip_runtime.h>
#include <hip/hip_bf16.h>
#include <math.h>

using u16 = unsigned short;
using s8v = __attribute__((ext_vector_type(8))) short;   // 8 bf16 (4 VGPRs) - MFMA A/B frag
using f4v = __attribute__((ext_vector_type(4))) float;   // MFMA C/D frag

__device__ __forceinline__ float b2f(u16 x) {
    unsigned int u = ((unsigned int)x) << 16;
    return __uint_as_float(u);
}
__device__ __forceinline__ u16 f2b(float f) {
    unsigned int x = __float_as_uint(f);
    unsigned int r = x + 0x7fffu + ((x >> 16) & 1u);   // RNE
    return (u16)(r >> 16);
}

// ---------------- block reduction (blockDim.x == 256) ----------------
__device__ __forceinline__ float block_sum(float v, float* buf) {
    int t = threadIdx.x;
    buf[t] = v; __syncthreads();
    for (int s = 128; s > 0; s >>= 1) {
        if (t < s) buf[t] += buf[t + s];
        __syncthreads();
    }
    float r = buf[0];
    __syncthreads();
    return r;
}

// ---------------- GEMM: C[M,N] = alpha * A[M,K] @ B[N,K]^T (bf16 in, fp32 acc) ----
// EPI: 0 -> fp32 C, 1 -> bf16 C, 2 -> atomicAdd(dotAcc, sum(C .* W)) (no C store)
#define TBM 128
#define TBN 128
#define TBK 32

template<int EPI>
__global__ __launch_bounds__(256)
void gemm_bt(const u16* __restrict__ A, const u16* __restrict__ B,
             float* __restrict__ Cf, u16* __restrict__ Cb,
             const u16* __restrict__ W, float* __restrict__ dotAcc,
             int M, int N, int K, float alpha)
{
    __shared__ __align__(16) u16 As[TBM * TBK];
    __shared__ __align__(16) u16 Bs[TBN * TBK];

    const int tid  = threadIdx.x;
    const int lane = tid & 63;
    const int wave = tid >> 6;
    const int wm   = (wave >> 1) * 64;
    const int wn   = (wave & 1) * 64;
    const int l16  = lane & 15;
    const int q4   = lane >> 4;
    const size_t row0 = (size_t)blockIdx.y * TBM;
    const size_t col0 = (size_t)blockIdx.x * TBN;

    f4v acc[4][4];
#pragma unroll
    for (int mt = 0; mt < 4; ++mt)
#pragma unroll
        for (int nt = 0; nt < 4; ++nt)
#pragma unroll
            for (int r = 0; r < 4; ++r)
                acc[mt][nt][r] = 0.f;

    // staging: 512 chunks of 8 bf16 per 128x32 tile; 2 chunks per thread per matrix
    const int q0 = tid, q1 = tid + 256;
    const int ar0 = q0 >> 2, ak0 = (q0 & 3) * 8;
    const int ar1 = q1 >> 2, ak1 = (q1 & 3) * 8;

    for (int k0 = 0; k0 < K; k0 += TBK) {
        s8v a0 = *(const s8v*)(A + (row0 + ar0) * K + k0 + ak0);
        s8v a1 = *(const s8v*)(A + (row0 + ar1) * K + k0 + ak1);
        s8v b0 = *(const s8v*)(B + (col0 + ar0) * K + k0 + ak0);
        s8v b1 = *(const s8v*)(B + (col0 + ar1) * K + k0 + ak1);
        __syncthreads();   // previous iteration's LDS reads done
        *(s8v*)(As + q0 * 8) = a0;
        *(s8v*)(As + q1 * 8) = a1;
        *(s8v*)(Bs + q0 * 8) = b0;
        *(s8v*)(Bs + q1 * 8) = b1;
        __syncthreads();

        s8v af[4], bfr[4];
#pragma unroll
        for (int mt = 0; mt < 4; ++mt)
            af[mt] = *(const s8v*)(As + (wm + mt * 16 + l16) * TBK + q4 * 8);
#pragma unroll
        for (int nt = 0; nt < 4; ++nt)
            bfr[nt] = *(const s8v*)(Bs + (wn + nt * 16 + l16) * TBK + q4 * 8);
#pragma unroll
        for (int mt = 0; mt < 4; ++mt)
#pragma unroll
            for (int nt = 0; nt < 4; ++nt)
                acc[mt][nt] = __builtin_amdgcn_mfma_f32_16x16x32_bf16(af[mt], bfr[nt], acc[mt][nt], 0, 0, 0);
    }

    if (EPI == 2) {
        float local = 0.f;
#pragma unroll
        for (int mt = 0; mt < 4; ++mt)
#pragma unroll
            for (int nt = 0; nt < 4; ++nt)
#pragma unroll
                for (int r = 0; r < 4; ++r) {
                    size_t row = row0 + wm + mt * 16 + q4 * 4 + r;
                    size_t col = col0 + wn + nt * 16 + l16;
                    local += acc[mt][nt][r] * b2f(W[row * (size_t)N + col]);
                }
        __shared__ float red[256];
        float tot = block_sum(local, red);
        if (tid == 0) atomicAdd(dotAcc, tot);
    } else {
#pragma unroll
        for (int mt = 0; mt < 4; ++mt)
#pragma unroll
            for (int nt = 0; nt < 4; ++nt)
#pragma unroll
                for (int r = 0; r < 4; ++r) {
                    size_t row = row0 + wm + mt * 16 + q4 * 4 + r;
                    size_t col = col0 + wn + nt * 16 + l16;
                    float v = acc[mt][nt][r] * alpha;
                    if (EPI == 0) Cf[row * (size_t)N + col] = v;
                    else          Cb[row * (size_t)N + col] = f2b(v);
                }
    }
}

// ---------------- elementwise / staging kernels ----------------
__global__ __launch_bounds__(256)
void rownorm_cast(const float* __restrict__ in, u16* __restrict__ out, int C) {
    int r = blockIdx.x, t = threadIdx.x;
    const float* row = in + (size_t)r * C;
    float ss = 0.f;
    for (int c = t; c < C; c += 256) { float v = row[c]; ss += v * v; }
    __shared__ float buf[256];
    float tot = block_sum(ss, buf);
    float nrm = fmaxf(sqrtf(tot), 1e-8f);
    float inv = 1.f / nrm;
    u16* orow = out + (size_t)r * C;
    for (int c = t; c < C; c += 256) orow[c] = f2b(row[c] * inv);
}

// Xn = x_hat / sqrt(x_hat . (x_hat @ S))   (x_hat bf16, XS fp32)
__global__ __launch_bounds__(256)
void mahal2(const u16* __restrict__ Xh, const float* __restrict__ XS,
            u16* __restrict__ out, int C) {
    int r = blockIdx.x, t = threadIdx.x;
    const u16* xr = Xh + (size_t)r * C;
    const float* sr = XS + (size_t)r * C;
    float s = 0.f;
    for (int c = t; c < C; c += 256) s += b2f(xr[c]) * sr[c];
    __shared__ float buf[256];
    float tot = block_sum(s, buf);
    float nrm = fmaxf(sqrtf(fmaxf(tot, 0.f)), 1e-8f);
    float inv = 1.f / nrm;
    u16* orow = out + (size_t)r * C;
    for (int c = t; c < C; c += 256) orow[c] = f2b(b2f(xr[c]) * inv);
}

__global__ __launch_bounds__(256)
void transpose_bf16(const u16* __restrict__ in, u16* __restrict__ out, int R, int C) {
    __shared__ u16 tile[32][33];
    int bx = blockIdx.x * 32, by = blockIdx.y * 32;
    int tx = threadIdx.x & 31;
    int ty = threadIdx.x >> 5;   // 0..7
    for (int i = ty; i < 32; i += 8)
        tile[i][tx] = in[(size_t)(by + i) * C + bx + tx];
    __syncthreads();
    for (int i = ty; i < 32; i += 8)
        out[(size_t)(bx + i) * R + by + tx] = tile[tx][i];
}

// ---------------- sinkhorn: u[i] = logmarg - lse_j(scale*C[i,j] + vin[j]) ------
__global__ __launch_bounds__(256)
void row_lse(const u16* __restrict__ C, const float* __restrict__ vin,
             float* __restrict__ uout, int ny, float scale, float logmarg) {
    int i = blockIdx.x, t = threadIdx.x;
    const u16* row = C + (size_t)i * ny;
    float m = -3.0e38f, s = 0.f;
    int nv = ny >> 3;
    for (int c = t; c < nv; c += 256) {
        s8v v8 = ((const s8v*)row)[c];
#pragma unroll
        for (int k = 0; k < 8; ++k) {
            float x = b2f((u16)v8[k]) * scale + vin[c * 8 + k];
            if (x > m) { s = s * __expf(m - x) + 1.f; m = x; }
            else       { s += __expf(x - m); }
        }
    }
    __shared__ float mb[256], sb[256];
    mb[t] = m; sb[t] = s; __syncthreads();
    for (int st = 128; st > 0; st >>= 1) {
        if (t < st) {
            float m1 = mb[t], m2 = mb[t + st], s1 = sb[t], s2 = sb[t + st];
            float M = fmaxf(m1, m2);
            sb[t] = s1 * __expf(m1 - M) + s2 * __expf(m2 - M);
            mb[t] = M;
        }
        __syncthreads();
    }
    if (t == 0) uout[i] = logmarg - (mb[0] + logf(sb[0]));
}

// plan[i,j] = exp(scale*C[i,j] + uin[i] + vin[j]); rowsum[i] = sum_j plan[i,j]
__global__ __launch_bounds__(256)
void plan_row(const u16* __restrict__ C, const float* __restrict__ uin,
              const float* __restrict__ vin, u16* __restrict__ plan,
              float* __restrict__ rowsum, int ny, float scale) {
    int i = blockIdx.x, t = threadIdx.x;
    const u16* row = C + (size_t)i * ny;
    float ui = uin[i], s = 0.f;
    int nv = ny >> 3;
    for (int c = t; c < nv; c += 256) {
        s8v v8 = ((const s8v*)row)[c];
        s8v pb;
#pragma unroll
        for (int k = 0; k < 8; ++k) {
            float lp = b2f((u16)v8[k]) * scale + ui + vin[c * 8 + k];
            float p = __expf(lp);
            s += p;
            pb[k] = (short)f2b(p);
        }
        if (plan) ((s8v*)(plan + (size_t)i * ny))[c] = pb;
    }
    __shared__ float buf[256];
    float tot = block_sum(s, buf);
    if (t == 0) rowsum[i] = tot;
}

__global__ __launch_bounds__(256)
void marg_kernel(const float* __restrict__ sv, int n, float target, float* __restrict__ slot) {
    int t = threadIdx.x;
    float s = 0.f;
    for (int i = t; i < n; i += 256) { float d = sv[i] - target; s += d * d; }
    __shared__ float buf[256];
    float tot = block_sum(s, buf);
    if (t == 0) atomicAdd(slot, tot);
}

// sum_j exp(lpa)*(lpa - lpu) for row i
__global__ __launch_bounds__(256)
void ot_row(const u16* __restrict__ Ca, const u16* __restrict__ Cu,
            const float* __restrict__ ua, const float* __restrict__ va,
            const float* __restrict__ uu, const float* __restrict__ vu,
            int ny, float scale, float* __restrict__ slot) {
    int i = blockIdx.x, t = threadIdx.x;
    const u16* ra = Ca + (size_t)i * ny;
    const u16* ru = Cu + (size_t)i * ny;
    float uai = ua[i], uui = uu[i];
    float local = 0.f;
    int nv = ny >> 3;
    for (int c = t; c < nv; c += 256) {
        s8v a8 = ((const s8v*)ra)[c];
        s8v u8 = ((const s8v*)ru)[c];
#pragma unroll
        for (int k = 0; k < 8; ++k) {
            int j = c * 8 + k;
            float lpa = b2f((u16)a8[k]) * scale + uai + va[j];
            float lpu = b2f((u16)u8[k]) * scale + uui + vu[j];
            local += __expf(lpa) * (lpa - lpu);
        }
    }
    __shared__ float buf[256];
    float tot = block_sum(local, buf);
    if (t == 0) atomicAdd(slot, tot);
}

__global__ __launch_bounds__(256)
void sail_row(const u16* __restrict__ cosb, int n, float temp, float* __restrict__ slot) {
    int i = blockIdx.x, t = threadIdx.x;
    const u16* row = cosb + (size_t)i * n;
    float local = 0.f;
    int nv = n >> 3;
    for (int c = t; c < nv; c += 256) {
        s8v v8 = ((const s8v*)row)[c];
#pragma unroll
        for (int k = 0; k < 8; ++k) {
            int j = c * 8 + k;
            float cv = b2f((u16)v8[k]);
            float w = cv * ((j == i) ? temp : -temp);
            float ls = fminf(w, 0.f) - log1pf(__expf(-fabsf(w)));
            local -= ls;
        }
    }
    __shared__ float buf[256];
    float tot = block_sum(local, buf);
    if (t == 0) atomicAdd(slot, tot);
}

// diag terms of pairs: L_exp sum and L_imp sum
__global__ __launch_bounds__(256)
void diag2(const u16* __restrict__ cosb, const float* __restrict__ up,
           const float* __restrict__ vp, int n, float scale,
           float* __restrict__ slotExp, float* __restrict__ slotImp) {
    int t = threadIdx.x;
    float e = 0.f, im = 0.f;
    float logn = logf((float)n);
    for (int i = t; i < n; i += 256) {
        float c = b2f(cosb[(size_t)i * n + i]);
        e  += (1.f - c) * 0.5f;
        im += scale * c + up[i] + vp[i] + logn;
    }
    __shared__ float buf[256];
    float te = block_sum(e, buf);
    float ti = block_sum(im, buf);
    if (t == 0) { atomicAdd(slotExp, te); atomicAdd(slotImp, ti); }
}

// w[i] * sum_j K[i,j]^2 * w[j]
__global__ __launch_bounds__(256)
void gw_quad(const u16* __restrict__ Kb, const float* __restrict__ wv, int n,
             float* __restrict__ slot) {
    int i = blockIdx.x, t = threadIdx.x;
    const u16* row = Kb + (size_t)i * n;
    float local = 0.f;
    int nv = n >> 3;
    for (int c = t; c < nv; c += 256) {
        s8v v8 = ((const s8v*)row)[c];
#pragma unroll
        for (int k = 0; k < 8; ++k) {
            float kv = b2f((u16)v8[k]);
            local += kv * kv * wv[c * 8 + k];
        }
    }
    __shared__ float buf[256];
    float tot = block_sum(local, buf);
    if (t == 0) atomicAdd(slot, wv[i] * tot);
}

// sum over a,b of Mf[a,b] * Tb[b,a]   (Mf: R x Cc fp32, Tb: Cc x R bf16)
__global__ __launch_bounds__(256)
void dotT(const float* __restrict__ Mf, const u16* __restrict__ Tb, int R, int Cc,
          float* __restrict__ slot) {
    int t = threadIdx.x;
    int total = R * Cc;
    float local = 0.f;
    for (int idx = blockIdx.x * 256 + t; idx < total; idx += gridDim.x * 256) {
        int a = idx / Cc, b = idx - a * Cc;
        local += Mf[idx] * b2f(Tb[(size_t)b * R + a]);
    }
    __shared__ float buf[256];
    float tot = block_sum(local, buf);
    if (t == 0) atomicAdd(slot, tot);
}

__global__ __launch_bounds__(256)
void dot_bb(const u16* __restrict__ A, const u16* __restrict__ B, int n,
            float* __restrict__ slot) {
    int t = threadIdx.x;
    float local = 0.f;
    for (int i = blockIdx.x * 256 + t; i < n; i += gridDim.x * 256)
        local += b2f(A[i]) * b2f(B[i]);
    __shared__ float buf[256];
    float tot = block_sum(local, buf);
    if (t == 0) atomicAdd(slot, tot);
}

// slots: 0 marg, 1 sail, 2 exp, 3 imp, 4 ot, 5 norm1, 6 norm2, 7 dot, 8 gw1, 9 gw2, 10 sandwich
__global__ void combine(const float* __restrict__ s, float* __restrict__ out) {
    if (threadIdx.x == 0 && blockIdx.x == 0) {
        float Np = 2048.f;
        float Nu2 = 4096.f * 4096.f;
        float total = s[0]
                    + s[1] / (Np * Np)
                    + s[2] / Np
                    - s[3] / Np
                    + s[4]
                    + (s[5] + s[6] - 2.f * s[7]) / Nu2
                    + s[8] + s[9] - 2.f * s[10];
        out[0] = total;
    }
}

// ------------------------------------------------------------------
extern "C" void kernel_launch(void* const* d_in, const int* in_sizes, int n_in,
                              void* d_out, int out_size, void* d_ws, size_t ws_size,
                              hipStream_t stream) {
    const float* fXp_in = (const float*)d_in[0];   // 2048 x 256
    const float* fYp_in = (const float*)d_in[1];   // 2048 x 256
    const float* X_in   = (const float*)d_in[2];   // 4096 x 768
    const float* Y_in   = (const float*)d_in[3];   // 4096 x 512
    const float* fX_in  = (const float*)d_in[4];   // 4096 x 256
    const float* fY_in  = (const float*)d_in[5];   // 4096 x 256
    const float* Xa_in  = (const float*)d_in[6];   // 4096 x 768
    const float* Ya_in  = (const float*)d_in[7];   // 4096 x 512
    float* out = (float*)d_out;

    char* w = (char*)d_ws;
    size_t off = 0;
    auto alloc = [&](size_t bytes) -> char* {
        char* p = w + off;
        off += (bytes + 255) & ~(size_t)255;
        return p;
    };

    const size_t N = 4096, Np = 2048, DX = 768, DY = 512, DF = 256;

    // ---- five shared 32 MB N x N slots (lifetime-scheduled) ----
    const size_t SLOT = N * N * 2;           // 33,554,432 B
    char* S1 = alloc(SLOT);
    char* S2 = alloc(SLOT);
    char* S3 = alloc(SLOT);
    char* S4 = alloc(SLOT);
    char* S5 = alloc(SLOT);

    // phase A aliases
    u16* Xa    = (u16*)S1;     // 4096x768 bf16 (6 MB)
    u16* Ya    = (u16*)S2;     // 4096x512 bf16 (4 MB)
    // phase B aliases
    float* XS  = (float*)S4;   // 4096x768 fp32 (12.6 MB)
    float* YS  = (float*)S5;   // 4096x512 fp32 (8.4 MB)
    // phase C aliases
    u16* cosp  = (u16*)S3;     // 2048x2048 bf16 (8 MB)
    u16* cospT = (u16*)S4;     // 2048x2048 bf16 (8 MB)
    // phase E/F/G aliases
    u16* Cu    = (u16*)S1;
    u16* CuT   = (u16*)S2;
    u16* plan  = (u16*)S4;
    u16* planT = (u16*)S5;
    u16* Ca    = (u16*)S3;
    u16* CaT   = (u16*)S2;     // after CuT dead
    u16* Kx    = (u16*)S1;     // after Cu dead
    u16* Ky    = (u16*)S3;     // after Ca dead
    u16* P1    = (u16*)S2;     // after CaT dead

    // ---- dedicated buffers (~60 MB) ----
    u16* XaT  = (u16*)alloc(N * DX * 2);
    u16* YaT  = (u16*)alloc(N * DY * 2);
    u16* fXp  = (u16*)alloc(Np * DF * 2);
    u16* fYp  = (u16*)alloc(Np * DF * 2);
    u16* fXn  = (u16*)alloc(N * DF * 2);
    u16* fYn  = (u16*)alloc(N * DF * 2);
    u16* fXnT = (u16*)alloc(N * DF * 2);
    u16* fYnT = (u16*)alloc(N * DF * 2);
    u16* Xu   = (u16*)alloc(N * DX * 2);
    u16* Yu   = (u16*)alloc(N * DY * 2);
    u16* Xn   = (u16*)alloc(N * DX * 2);
    u16* Yn   = (u16*)alloc(N * DY * 2);
    u16* XnT  = (u16*)alloc(N * DX * 2);
    u16* YnT  = (u16*)alloc(N * DY * 2);
    u16* Sxx  = (u16*)alloc(DX * DX * 2);
    u16* Syy  = (u16*)alloc(DY * DY * 2);
    u16* SxyT = (u16*)alloc(DY * DX * 2);       // SxyT[b][a] = Sxy[a][b]
    u16* Tb   = (u16*)alloc(N * DY * 2);        // Xn @ Sxy
    u16* Gx   = (u16*)alloc(DX * DX * 2);
    u16* Gy   = (u16*)alloc(DY * DY * 2);
    u16* Gfx  = (u16*)alloc(DF * DF * 2);
    u16* Gfy  = (u16*)alloc(DF * DF * 2);
    u16* A1b  = (u16*)alloc(DX * DF * 2);
    u16* B1Tb = (u16*)alloc(DY * DF * 2);
    u16* Hb   = (u16*)alloc(DX * DY * 2);
    float* H2 = (float*)alloc(DX * DY * 4);
    float* D1 = (float*)alloc(DX * DY * 4);
    float* up = (float*)alloc(Np * 4);
    float* vp = (float*)alloc(Np * 4);
    float* uu = (float*)alloc(N * 4);
    float* vu = (float*)alloc(N * 4);
    float* ua = (float*)alloc(N * 4);
    float* va = (float*)alloc(N * 4);
    float* ap = (float*)alloc(Np * 4);
    float* bp = (float*)alloc(Np * 4);
    float* au = (float*)alloc(N * 4);
    float* bu = (float*)alloc(N * 4);
    float* slots = (float*)alloc(64 * 4);

    const float SCALE = 20.f;   // 1/eps

#define GEMM_F32(A_, B_, C_, M_, N_, K_, al_) \
    gemm_bt<0><<<dim3((N_) / 128, (M_) / 128), 256, 0, stream>>>((A_), (B_), (C_), nullptr, nullptr, nullptr, (M_), (N_), (K_), (al_))
#define GEMM_B16(A_, B_, C_, M_, N_, K_, al_) \
    gemm_bt<1><<<dim3((N_) / 128, (M_) / 128), 256, 0, stream>>>((A_), (B_), nullptr, (C_), nullptr, nullptr, (M_), (N_), (K_), (al_))
#define GEMM_DOT(A_, B_, W_, S_, M_, N_, K_) \
    gemm_bt<2><<<dim3((N_) / 128, (M_) / 128), 256, 0, stream>>>((A_), (B_), nullptr, nullptr, (W_), (S_), (M_), (N_), (K_), 1.0f)

    hipMemsetAsync(slots, 0, 64 * 4, stream);

    // ===== Phase A: anchor covariances =====
    rownorm_cast<<<4096, 256, 0, stream>>>(Xa_in, Xa, 768);
    rownorm_cast<<<4096, 256, 0, stream>>>(Ya_in, Ya, 512);
    transpose_bf16<<<dim3(768 / 32, 4096 / 32), 256, 0, stream>>>(Xa, XaT, 4096, 768);
    transpose_bf16<<<dim3(512 / 32, 4096 / 32), 256, 0, stream>>>(Ya, YaT, 4096, 512);
    GEMM_B16(XaT, XaT, Sxx, 768, 768, 4096, 1.f / 4096.f);
    GEMM_B16(YaT, YaT, Syy, 512, 512, 4096, 1.f / 4096.f);
    GEMM_B16(YaT, XaT, SxyT, 512, 768, 4096, 1.f / 4096.f);
    // Xa (S1), Ya (S2) dead

    // ===== Phase B: row norms + Mahalanobis normalization =====
    rownorm_cast<<<2048, 256, 0, stream>>>(fXp_in, fXp, 256);
    rownorm_cast<<<2048, 256, 0, stream>>>(fYp_in, fYp, 256);
    rownorm_cast<<<4096, 256, 0, stream>>>(fX_in, fXn, 256);
    rownorm_cast<<<4096, 256, 0, stream>>>(fY_in, fYn, 256);
    rownorm_cast<<<4096, 256, 0, stream>>>(X_in, Xu, 768);
    rownorm_cast<<<4096, 256, 0, stream>>>(Y_in, Yu, 512);

    GEMM_F32(Xu, Sxx, XS, 4096, 768, 768, 1.f);     // x_hat @ Sxx (Sxx sym)
    GEMM_F32(Yu, Syy, YS, 4096, 512, 512, 1.f);
    mahal2<<<4096, 256, 0, stream>>>(Xu, XS, Xn, 768);
    mahal2<<<4096, 256, 0, stream>>>(Yu, YS, Yn, 512);
    // XS (S4), YS (S5) dead
    transpose_bf16<<<dim3(768 / 32, 4096 / 32), 256, 0, stream>>>(Xn, XnT, 4096, 768);
    transpose_bf16<<<dim3(512 / 32, 4096 / 32), 256, 0, stream>>>(Yn, YnT, 4096, 512);
    transpose_bf16<<<dim3(256 / 32, 4096 / 32), 256, 0, stream>>>(fXn, fXnT, 4096, 256);
    transpose_bf16<<<dim3(256 / 32, 4096 / 32), 256, 0, stream>>>(fYn, fYnT, 4096, 256);

    // ===== Phase C: pairs block (sinkhorn_p + sail + diag) =====
    GEMM_B16(fXp, fYp, cosp, 2048, 2048, 256, 1.f);
    GEMM_B16(fYp, fXp, cospT, 2048, 2048, 256, 1.f);
    {
        hipMemsetAsync(up, 0, Np * 4, stream);
        hipMemsetAsync(vp, 0, Np * 4, stream);
        float la = -logf(2048.f), lb = -logf(2048.f);
        for (int it = 0; it < 10; ++it) {
            row_lse<<<2048, 256, 0, stream>>>(cosp, vp, up, 2048, SCALE, la);
            row_lse<<<2048, 256, 0, stream>>>(cospT, up, vp, 2048, SCALE, lb);
        }
    }
    plan_row<<<2048, 256, 0, stream>>>(cosp, up, vp, nullptr, ap, 2048, SCALE);
    plan_row<<<2048, 256, 0, stream>>>(cospT, vp, up, nullptr, bp, 2048, SCALE);
    marg_kernel<<<1, 256, 0, stream>>>(ap, 2048, 1.f / 2048.f, slots + 0);
    marg_kernel<<<1, 256, 0, stream>>>(bp, 2048, 1.f / 2048.f, slots + 0);
    sail_row<<<2048, 256, 0, stream>>>(cosp, 2048, 10.f, slots + 1);
    diag2<<<1, 256, 0, stream>>>(cosp, up, vp, 2048, SCALE, slots + 2, slots + 3);
    // cosp (S3), cospT (S4) dead

    // ===== Phase D: L_div gram matrices =====
    GEMM_B16(XnT, XnT, Gx, 768, 768, 4096, 1.f);
    GEMM_B16(YnT, YnT, Gy, 512, 512, 4096, 1.f);
    GEMM_B16(fXnT, fXnT, Gfx, 256, 256, 4096, 1.f);
    GEMM_B16(fYnT, fYnT, Gfy, 256, 256, 4096, 1.f);
    GEMM_B16(XnT, fXnT, A1b, 768, 256, 4096, 1.f);  // Xn^T fXn
    GEMM_B16(YnT, fYnT, B1Tb, 512, 256, 4096, 1.f); // Yn^T fYn
    GEMM_B16(Gx, SxyT, Hb, 768, 512, 768, 1.f);     // Gx @ Sxy
    GEMM_F32(Hb, Gy, H2, 768, 512, 512, 1.f);       // (Gx Sxy) @ Gy   (Gy sym)
    GEMM_F32(A1b, B1Tb, D1, 768, 512, 256, 1.f);    // (Xn^T fXn)(fYn^T Yn)
    dotT<<<192, 256, 0, stream>>>(H2, SxyT, 768, 512, slots + 5);
    dot_bb<<<64, 256, 0, stream>>>(Gfx, Gfy, 256 * 256, slots + 6);
    dotT<<<192, 256, 0, stream>>>(D1, SxyT, 768, 512, slots + 7);

    // ===== Phase E: latent sinkhorn =====
    GEMM_B16(fXn, fYn, Cu, 4096, 4096, 256, 1.f);    // -> S1
    GEMM_B16(fYn, fXn, CuT, 4096, 4096, 256, 1.f);   // -> S2
    {
        hipMemsetAsync(uu, 0, N * 4, stream);
        hipMemsetAsync(vu, 0, N * 4, stream);
        float la = -logf(4096.f), lb = -logf(4096.f);
        for (int it = 0; it < 10; ++it) {
            row_lse<<<4096, 256, 0, stream>>>(Cu, vu, uu, 4096, SCALE, la);
            row_lse<<<4096, 256, 0, stream>>>(CuT, uu, vu, 4096, SCALE, lb);
        }
    }
    plan_row<<<4096, 256, 0, stream>>>(Cu, uu, vu, plan, au, 4096, SCALE);    // -> S4
    plan_row<<<4096, 256, 0, stream>>>(CuT, vu, uu, planT, bu, 4096, SCALE);  // -> S5
    marg_kernel<<<1, 256, 0, stream>>>(au, 4096, 1.f / 4096.f, slots + 0);
    marg_kernel<<<1, 256, 0, stream>>>(bu, 4096, 1.f / 4096.f, slots + 0);
    // CuT (S2) dead; Cu (S1) still needed by ot_row

    // ===== Phase F: anchor sinkhorn + L_ot =====
    GEMM_B16(Xn, SxyT, Tb, 4096, 512, 768, 1.f);    // T = Xn @ Sxy
    GEMM_B16(Tb, Yn, Ca, 4096, 4096, 512, 1.f);     // -> S3
    GEMM_B16(Yn, Tb, CaT, 4096, 4096, 512, 1.f);    // -> S2
    {
        hipMemsetAsync(ua, 0, N * 4, stream);
        hipMemsetAsync(va, 0, N * 4, stream);
        float la = -logf(4096.f), lb = -logf(4096.f);
        for (int it = 0; it < 10; ++it) {
            row_lse<<<4096, 256, 0, stream>>>(Ca, va, ua, 4096, SCALE, la);
            row_lse<<<4096, 256, 0, stream>>>(CaT, ua, va, 4096, SCALE, lb);
        }
    }
    ot_row<<<4096, 256, 0, stream>>>(Ca, Cu, ua, va, uu, vu, 4096, SCALE, slots + 4);
    // Cu (S1), Ca (S3), CaT (S2) dead

    // ===== Phase G: Gromov-Wasserstein =====
    GEMM_B16(Xu, Xu, Kx, 4096, 4096, 768, 1.f);     // -> S1
    GEMM_B16(Yu, Yu, Ky, 4096, 4096, 512, 1.f);     // -> S3
    gw_quad<<<4096, 256, 0, stream>>>(Kx, au, 4096, slots + 8);
    gw_quad<<<4096, 256, 0, stream>>>(Ky, bu, 4096, slots + 9);
    GEMM_B16(Kx, planT, P1, 4096, 4096, 4096, 1.f); // Kx @ plan -> S2
    GEMM_DOT(P1, Ky, plan, slots + 10, 4096, 4096, 4096);  // sum((P1@Ky).*plan)

    combine<<<1, 1, 0, stream>>>(slots, out);

#undef GEMM_F32
#undef GEMM_B16
#undef GEMM_DOT
}

// Round 3
// 2214.015 us; speedup vs baseline: 1.5493x; 1.5493x over previous
//
#include <hip/hip_runtime.h>
#include <hip/hip_bf16.h>
#include <math.h>

using u16 = unsigned short;
using s8v = __attribute__((ext_vector_type(8))) short;   // 8 bf16 (4 VGPRs) - MFMA A/B frag
using s4v = __attribute__((ext_vector_type(4))) short;   // 4 bf16
using f4v = __attribute__((ext_vector_type(4))) float;   // MFMA C/D frag

__device__ __forceinline__ float b2f(u16 x) {
    unsigned int u = ((unsigned int)x) << 16;
    return __uint_as_float(u);
}
__device__ __forceinline__ u16 f2b(float f) {
    unsigned int x = __float_as_uint(f);
    unsigned int r = x + 0x7fffu + ((x >> 16) & 1u);   // RNE
    return (u16)(r >> 16);
}

// ---------------- reductions ----------------
__device__ __forceinline__ float block_sum(float v, float* buf) {
    int t = threadIdx.x;
    buf[t] = v; __syncthreads();
    for (int s = 128; s > 0; s >>= 1) {
        if (t < s) buf[t] += buf[t + s];
        __syncthreads();
    }
    float r = buf[0];
    __syncthreads();
    return r;
}

__device__ __forceinline__ float wave_sum(float v) {
#pragma unroll
    for (int off = 32; off; off >>= 1) v += __shfl_xor(v, off, 64);
    return v;
}

// online-LSE pair reduce across wave: (m, s) -> all lanes get combined
__device__ __forceinline__ void wave_lse(float& m, float& s) {
#pragma unroll
    for (int off = 32; off; off >>= 1) {
        float m2 = __shfl_xor(m, off, 64);
        float s2 = __shfl_xor(s, off, 64);
        float M = fmaxf(m, m2);
        s = s * __expf(m - M) + s2 * __expf(m2 - M);
        m = M;
    }
}

// combine 4 per-wave partials -> one atomicAdd per block
__device__ __forceinline__ void block_atomic4(float wval, float* slot) {
    __shared__ float wb[4];
    int lane = threadIdx.x & 63, wv = threadIdx.x >> 6;
    if (lane == 0) wb[wv] = wval;
    __syncthreads();
    if (threadIdx.x == 0) atomicAdd(slot, wb[0] + wb[1] + wb[2] + wb[3]);
}

// ---------------- GEMM: C[M,N] = alpha * A[M,K] @ B[N,K]^T (bf16 in, fp32 acc) ----
// EPI: 0 -> fp32 C, 1 -> bf16 C, 2 -> atomicAdd(dotAcc, sum(C .* W)) (no C store)
#define TBM 128
#define TBN 128
#define TBK 32

template<int EPI>
__global__ __launch_bounds__(256)
void gemm_bt(const u16* __restrict__ A, const u16* __restrict__ B,
             float* __restrict__ Cf, u16* __restrict__ Cb,
             const u16* __restrict__ W, float* __restrict__ dotAcc,
             int M, int N, int K, float alpha)
{
    __shared__ __align__(16) u16 As[TBM * TBK];
    __shared__ __align__(16) u16 Bs[TBN * TBK];

    const int tid  = threadIdx.x;
    const int lane = tid & 63;
    const int wave = tid >> 6;
    const int wm   = (wave >> 1) * 64;
    const int wn   = (wave & 1) * 64;
    const int l16  = lane & 15;
    const int q4   = lane >> 4;
    const size_t row0 = (size_t)blockIdx.y * TBM;
    const size_t col0 = (size_t)blockIdx.x * TBN;

    f4v acc[4][4];
#pragma unroll
    for (int mt = 0; mt < 4; ++mt)
#pragma unroll
        for (int nt = 0; nt < 4; ++nt)
#pragma unroll
            for (int r = 0; r < 4; ++r)
                acc[mt][nt][r] = 0.f;

    const int q0 = tid, q1 = tid + 256;
    const int ar0 = q0 >> 2, ak0 = (q0 & 3) * 8;
    const int ar1 = q1 >> 2, ak1 = (q1 & 3) * 8;

    for (int k0 = 0; k0 < K; k0 += TBK) {
        s8v a0 = *(const s8v*)(A + (row0 + ar0) * K + k0 + ak0);
        s8v a1 = *(const s8v*)(A + (row0 + ar1) * K + k0 + ak1);
        s8v b0 = *(const s8v*)(B + (col0 + ar0) * K + k0 + ak0);
        s8v b1 = *(const s8v*)(B + (col0 + ar1) * K + k0 + ak1);
        __syncthreads();
        *(s8v*)(As + q0 * 8) = a0;
        *(s8v*)(As + q1 * 8) = a1;
        *(s8v*)(Bs + q0 * 8) = b0;
        *(s8v*)(Bs + q1 * 8) = b1;
        __syncthreads();

        s8v af[4], bfr[4];
#pragma unroll
        for (int mt = 0; mt < 4; ++mt)
            af[mt] = *(const s8v*)(As + (wm + mt * 16 + l16) * TBK + q4 * 8);
#pragma unroll
        for (int nt = 0; nt < 4; ++nt)
            bfr[nt] = *(const s8v*)(Bs + (wn + nt * 16 + l16) * TBK + q4 * 8);
#pragma unroll
        for (int mt = 0; mt < 4; ++mt)
#pragma unroll
            for (int nt = 0; nt < 4; ++nt)
                acc[mt][nt] = __builtin_amdgcn_mfma_f32_16x16x32_bf16(af[mt], bfr[nt], acc[mt][nt], 0, 0, 0);
    }

    if (EPI == 2) {
        float local = 0.f;
#pragma unroll
        for (int mt = 0; mt < 4; ++mt)
#pragma unroll
            for (int nt = 0; nt < 4; ++nt)
#pragma unroll
                for (int r = 0; r < 4; ++r) {
                    size_t row = row0 + wm + mt * 16 + q4 * 4 + r;
                    size_t col = col0 + wn + nt * 16 + l16;
                    local += acc[mt][nt][r] * b2f(W[row * (size_t)N + col]);
                }
        __shared__ float red[256];
        float tot = block_sum(local, red);
        if (tid == 0) atomicAdd(dotAcc, tot);
    } else {
#pragma unroll
        for (int mt = 0; mt < 4; ++mt)
#pragma unroll
            for (int nt = 0; nt < 4; ++nt)
#pragma unroll
                for (int r = 0; r < 4; ++r) {
                    size_t row = row0 + wm + mt * 16 + q4 * 4 + r;
                    size_t col = col0 + wn + nt * 16 + l16;
                    float v = acc[mt][nt][r] * alpha;
                    if (EPI == 0) Cf[row * (size_t)N + col] = v;
                    else          Cb[row * (size_t)N + col] = f2b(v);
                }
    }
}

// ---------------- wave-per-row elementwise / staging ----------------
// one wave per row; 4 rows per 256-thread block
__global__ __launch_bounds__(256)
void rownorm_w(const float* __restrict__ in, u16* __restrict__ out, int nrows, int C) {
    int row = (blockIdx.x * 256 + threadIdx.x) >> 6;
    int lane = threadIdx.x & 63;
    if (row >= nrows) return;
    const float4* r4 = (const float4*)(in + (size_t)row * C);
    int nv = C >> 2;
    float ss = 0.f;
    for (int c = lane; c < nv; c += 64) {
        float4 v = r4[c];
        ss += v.x * v.x + v.y * v.y + v.z * v.z + v.w * v.w;
    }
    ss = wave_sum(ss);
    float inv = 1.f / fmaxf(sqrtf(ss), 1e-8f);
    s4v* o4 = (s4v*)(out + (size_t)row * C);
    for (int c = lane; c < nv; c += 64) {
        float4 v = r4[c];
        s4v o;
        o[0] = (short)f2b(v.x * inv); o[1] = (short)f2b(v.y * inv);
        o[2] = (short)f2b(v.z * inv); o[3] = (short)f2b(v.w * inv);
        o4[c] = o;
    }
}

// Xn = x_hat / sqrt(x_hat . (x_hat @ S))   (x_hat bf16, XS fp32)
__global__ __launch_bounds__(256)
void mahal_w(const u16* __restrict__ Xh, const float* __restrict__ XS,
             u16* __restrict__ out, int nrows, int C) {
    int row = (blockIdx.x * 256 + threadIdx.x) >> 6;
    int lane = threadIdx.x & 63;
    if (row >= nrows) return;
    const s4v* x4 = (const s4v*)(Xh + (size_t)row * C);
    const float4* s4 = (const float4*)(XS + (size_t)row * C);
    int nv = C >> 2;
    float s = 0.f;
    for (int c = lane; c < nv; c += 64) {
        s4v x = x4[c]; float4 v = s4[c];
        s += b2f((u16)x[0]) * v.x + b2f((u16)x[1]) * v.y
           + b2f((u16)x[2]) * v.z + b2f((u16)x[3]) * v.w;
    }
    s = wave_sum(s);
    float inv = 1.f / fmaxf(sqrtf(fmaxf(s, 0.f)), 1e-8f);
    s4v* o4 = (s4v*)(out + (size_t)row * C);
    for (int c = lane; c < nv; c += 64) {
        s4v x = x4[c], o;
#pragma unroll
        for (int k = 0; k < 4; ++k) o[k] = (short)f2b(b2f((u16)x[k]) * inv);
        o4[c] = o;
    }
}

__global__ __launch_bounds__(256)
void transpose_bf16(const u16* __restrict__ in, u16* __restrict__ out, int R, int C) {
    __shared__ u16 tile[32][33];
    int bx = blockIdx.x * 32, by = blockIdx.y * 32;
    int tx = threadIdx.x & 31;
    int ty = threadIdx.x >> 5;   // 0..7
    for (int i = ty; i < 32; i += 8)
        tile[i][tx] = in[(size_t)(by + i) * C + bx + tx];
    __syncthreads();
    for (int i = ty; i < 32; i += 8)
        out[(size_t)(bx + i) * R + by + tx] = tile[tx][i];
}

// ---------------- sinkhorn row pass: u[i] = logmarg - lse_j(scale*C[i,j]+vin[j])
__global__ __launch_bounds__(256)
void row_lse_w(const u16* __restrict__ C, const float* __restrict__ vin,
               float* __restrict__ uout, int nrows, int ny, float scale, float logmarg) {
    int row = (blockIdx.x * 256 + threadIdx.x) >> 6;
    int lane = threadIdx.x & 63;
    if (row >= nrows) return;
    const s8v* r8 = (const s8v*)(C + (size_t)row * ny);
    const float4* v4 = (const float4*)vin;
    int nv = ny >> 3;
    float m = -3.0e38f, s = 0.f;
    for (int c = lane; c < nv; c += 64) {
        s8v v8 = r8[c];
        float4 va = v4[c * 2], vb = v4[c * 2 + 1];
        float xs[8];
        xs[0] = b2f((u16)v8[0]) * scale + va.x;
        xs[1] = b2f((u16)v8[1]) * scale + va.y;
        xs[2] = b2f((u16)v8[2]) * scale + va.z;
        xs[3] = b2f((u16)v8[3]) * scale + va.w;
        xs[4] = b2f((u16)v8[4]) * scale + vb.x;
        xs[5] = b2f((u16)v8[5]) * scale + vb.y;
        xs[6] = b2f((u16)v8[6]) * scale + vb.z;
        xs[7] = b2f((u16)v8[7]) * scale + vb.w;
#pragma unroll
        for (int k = 0; k < 8; ++k) {
            float M = fmaxf(m, xs[k]);
            s = s * __expf(m - M) + __expf(xs[k] - M);
            m = M;
        }
    }
    wave_lse(m, s);
    if (lane == 0) uout[row] = logmarg - (m + logf(s));
}

// plan[i,j] = exp(scale*C[i,j]+uin[i]+vin[j]); rowsum[i] = sum_j
__global__ __launch_bounds__(256)
void plan_row_w(const u16* __restrict__ C, const float* __restrict__ uin,
                const float* __restrict__ vin, u16* __restrict__ plan,
                float* __restrict__ rowsum, int nrows, int ny, float scale) {
    int row = (blockIdx.x * 256 + threadIdx.x) >> 6;
    int lane = threadIdx.x & 63;
    if (row >= nrows) return;
    const s8v* r8 = (const s8v*)(C + (size_t)row * ny);
    s8v* p8 = plan ? (s8v*)(plan + (size_t)row * ny) : nullptr;
    const float4* v4 = (const float4*)vin;
    float ui = uin[row], s = 0.f;
    int nv = ny >> 3;
    for (int c = lane; c < nv; c += 64) {
        s8v v8 = r8[c], pb;
        float4 va = v4[c * 2], vb = v4[c * 2 + 1];
        float vv[8] = {va.x, va.y, va.z, va.w, vb.x, vb.y, vb.z, vb.w};
#pragma unroll
        for (int k = 0; k < 8; ++k) {
            float p = __expf(b2f((u16)v8[k]) * scale + ui + vv[k]);
            s += p;
            pb[k] = (short)f2b(p);
        }
        if (p8) p8[c] = pb;
    }
    s = wave_sum(s);
    if (lane == 0) rowsum[row] = s;
}

__global__ __launch_bounds__(256)
void marg_kernel(const float* __restrict__ sv, int n, float target, float* __restrict__ slot) {
    int t = threadIdx.x;
    float s = 0.f;
    for (int i = t; i < n; i += 256) { float d = sv[i] - target; s += d * d; }
    __shared__ float buf[256];
    float tot = block_sum(s, buf);
    if (t == 0) atomicAdd(slot, tot);
}

// sum_j exp(lpa)*(lpa - lpu) for row i
__global__ __launch_bounds__(256)
void ot_row_w(const u16* __restrict__ Ca, const u16* __restrict__ Cu,
              const float* __restrict__ ua, const float* __restrict__ va,
              const float* __restrict__ uu, const float* __restrict__ vu,
              int nrows, int ny, float scale, float* __restrict__ slot) {
    int row = (blockIdx.x * 256 + threadIdx.x) >> 6;
    int lane = threadIdx.x & 63;
    float local = 0.f;
    if (row < nrows) {
        const s8v* ra = (const s8v*)(Ca + (size_t)row * ny);
        const s8v* ru = (const s8v*)(Cu + (size_t)row * ny);
        const float4* va4 = (const float4*)va;
        const float4* vu4 = (const float4*)vu;
        float uai = ua[row], uui = uu[row];
        int nv = ny >> 3;
        for (int c = lane; c < nv; c += 64) {
            s8v a8 = ra[c], u8 = ru[c];
            float4 a0 = va4[c * 2], a1 = va4[c * 2 + 1];
            float4 u0 = vu4[c * 2], u1 = vu4[c * 2 + 1];
            float av[8] = {a0.x, a0.y, a0.z, a0.w, a1.x, a1.y, a1.z, a1.w};
            float uv[8] = {u0.x, u0.y, u0.z, u0.w, u1.x, u1.y, u1.z, u1.w};
#pragma unroll
            for (int k = 0; k < 8; ++k) {
                float lpa = b2f((u16)a8[k]) * scale + uai + av[k];
                float lpu = b2f((u16)u8[k]) * scale + uui + uv[k];
                local += __expf(lpa) * (lpa - lpu);
            }
        }
    }
    local = wave_sum(local);
    block_atomic4(local, slot);
}

__global__ __launch_bounds__(256)
void sail_row_w(const u16* __restrict__ cosb, int n, float temp, float* __restrict__ slot) {
    int row = (blockIdx.x * 256 + threadIdx.x) >> 6;
    int lane = threadIdx.x & 63;
    float local = 0.f;
    if (row < n) {
        const s8v* r8 = (const s8v*)(cosb + (size_t)row * n);
        int nv = n >> 3;
        for (int c = lane; c < nv; c += 64) {
            s8v v8 = r8[c];
#pragma unroll
            for (int k = 0; k < 8; ++k) {
                int j = c * 8 + k;
                float cv = b2f((u16)v8[k]);
                float wgt = cv * ((j == row) ? temp : -temp);
                local -= fminf(wgt, 0.f) - log1pf(__expf(-fabsf(wgt)));
            }
        }
    }
    local = wave_sum(local);
    block_atomic4(local, slot);
}

// diag terms of pairs: L_exp sum and L_imp sum
__global__ __launch_bounds__(256)
void diag2(const u16* __restrict__ cosb, const float* __restrict__ up,
           const float* __restrict__ vp, int n, float scale,
           float* __restrict__ slotExp, float* __restrict__ slotImp) {
    int t = threadIdx.x;
    float e = 0.f, im = 0.f;
    float logn = logf((float)n);
    for (int i = t; i < n; i += 256) {
        float c = b2f(cosb[(size_t)i * n + i]);
        e  += (1.f - c) * 0.5f;
        im += scale * c + up[i] + vp[i] + logn;
    }
    __shared__ float buf[256];
    float te = block_sum(e, buf);
    float ti = block_sum(im, buf);
    if (t == 0) { atomicAdd(slotExp, te); atomicAdd(slotImp, ti); }
}

// w[i] * sum_j K[i,j]^2 * w[j]
__global__ __launch_bounds__(256)
void gw_quad_w(const u16* __restrict__ Kb, const float* __restrict__ wv, int n,
               float* __restrict__ slot) {
    int row = (blockIdx.x * 256 + threadIdx.x) >> 6;
    int lane = threadIdx.x & 63;
    float local = 0.f;
    if (row < n) {
        const s8v* r8 = (const s8v*)(Kb + (size_t)row * n);
        const float4* w4 = (const float4*)wv;
        int nv = n >> 3;
        for (int c = lane; c < nv; c += 64) {
            s8v v8 = r8[c];
            float4 w0 = w4[c * 2], w1 = w4[c * 2 + 1];
            float ww[8] = {w0.x, w0.y, w0.z, w0.w, w1.x, w1.y, w1.z, w1.w};
#pragma unroll
            for (int k = 0; k < 8; ++k) {
                float kv = b2f((u16)v8[k]);
                local += kv * kv * ww[k];
            }
        }
        local = wave_sum(local) * wv[row];
        if (lane != 0) local = 0.f;
    }
    // one atomic per block (lane0 of each wave contributes its row's value)
    block_atomic4(local, slot);
}

// sum over a,b of Mf[a,b] * Tb[b,a]   (Mf: R x Cc fp32, Tb: Cc x R bf16)
__global__ __launch_bounds__(256)
void dotT(const float* __restrict__ Mf, const u16* __restrict__ Tb, int R, int Cc,
          float* __restrict__ slot) {
    int t = threadIdx.x;
    int total = R * Cc;
    float local = 0.f;
    for (int idx = blockIdx.x * 256 + t; idx < total; idx += gridDim.x * 256) {
        int a = idx / Cc, b = idx - a * Cc;
        local += Mf[idx] * b2f(Tb[(size_t)b * R + a]);
    }
    __shared__ float buf[256];
    float tot = block_sum(local, buf);
    if (t == 0) atomicAdd(slot, tot);
}

__global__ __launch_bounds__(256)
void dot_bb(const u16* __restrict__ A, const u16* __restrict__ B, int n,
            float* __restrict__ slot) {
    int t = threadIdx.x;
    float local = 0.f;
    for (int i = blockIdx.x * 256 + t; i < n; i += gridDim.x * 256)
        local += b2f(A[i]) * b2f(B[i]);
    __shared__ float buf[256];
    float tot = block_sum(local, buf);
    if (t == 0) atomicAdd(slot, tot);
}

// slots: 0 marg, 1 sail, 2 exp, 3 imp, 4 ot, 5 norm1, 6 norm2, 7 dot, 8 gw1, 9 gw2, 10 sandwich
__global__ void combine(const float* __restrict__ s, float* __restrict__ out) {
    if (threadIdx.x == 0 && blockIdx.x == 0) {
        float Np = 2048.f;
        float Nu2 = 4096.f * 4096.f;
        float total = s[0]
                    + s[1] / (Np * Np)
                    + s[2] / Np
                    - s[3] / Np
                    + s[4]
                    + (s[5] + s[6] - 2.f * s[7]) / Nu2
                    + s[8] + s[9] - 2.f * s[10];
        out[0] = total;
    }
}

// ------------------------------------------------------------------
extern "C" void kernel_launch(void* const* d_in, const int* in_sizes, int n_in,
                              void* d_out, int out_size, void* d_ws, size_t ws_size,
                              hipStream_t stream) {
    const float* fXp_in = (const float*)d_in[0];   // 2048 x 256
    const float* fYp_in = (const float*)d_in[1];   // 2048 x 256
    const float* X_in   = (const float*)d_in[2];   // 4096 x 768
    const float* Y_in   = (const float*)d_in[3];   // 4096 x 512
    const float* fX_in  = (const float*)d_in[4];   // 4096 x 256
    const float* fY_in  = (const float*)d_in[5];   // 4096 x 256
    const float* Xa_in  = (const float*)d_in[6];   // 4096 x 768
    const float* Ya_in  = (const float*)d_in[7];   // 4096 x 512
    float* out = (float*)d_out;

    char* w = (char*)d_ws;
    size_t off = 0;
    auto alloc = [&](size_t bytes) -> char* {
        char* p = w + off;
        off += (bytes + 255) & ~(size_t)255;
        return p;
    };

    const size_t N = 4096, Np = 2048, DX = 768, DY = 512, DF = 256;

    // ---- five shared 32 MB N x N slots (lifetime-scheduled) ----
    const size_t SLOT = N * N * 2;
    char* S1 = alloc(SLOT);
    char* S2 = alloc(SLOT);
    char* S3 = alloc(SLOT);
    char* S4 = alloc(SLOT);
    char* S5 = alloc(SLOT);

    u16* Xa    = (u16*)S1;
    u16* Ya    = (u16*)S2;
    float* XS  = (float*)S4;
    float* YS  = (float*)S5;
    u16* cosp  = (u16*)S3;
    u16* cospT = (u16*)S4;
    u16* Cu    = (u16*)S1;
    u16* CuT   = (u16*)S2;
    u16* plan  = (u16*)S4;
    u16* planT = (u16*)S5;
    u16* Ca    = (u16*)S3;
    u16* CaT   = (u16*)S2;
    u16* Kx    = (u16*)S1;
    u16* Ky    = (u16*)S3;
    u16* P1    = (u16*)S2;

    u16* XaT  = (u16*)alloc(N * DX * 2);
    u16* YaT  = (u16*)alloc(N * DY * 2);
    u16* fXp  = (u16*)alloc(Np * DF * 2);
    u16* fYp  = (u16*)alloc(Np * DF * 2);
    u16* fXn  = (u16*)alloc(N * DF * 2);
    u16* fYn  = (u16*)alloc(N * DF * 2);
    u16* fXnT = (u16*)alloc(N * DF * 2);
    u16* fYnT = (u16*)alloc(N * DF * 2);
    u16* Xu   = (u16*)alloc(N * DX * 2);
    u16* Yu   = (u16*)alloc(N * DY * 2);
    u16* Xn   = (u16*)alloc(N * DX * 2);
    u16* Yn   = (u16*)alloc(N * DY * 2);
    u16* XnT  = (u16*)alloc(N * DX * 2);
    u16* YnT  = (u16*)alloc(N * DY * 2);
    u16* Sxx  = (u16*)alloc(DX * DX * 2);
    u16* Syy  = (u16*)alloc(DY * DY * 2);
    u16* SxyT = (u16*)alloc(DY * DX * 2);
    u16* Tb   = (u16*)alloc(N * DY * 2);
    u16* Gx   = (u16*)alloc(DX * DX * 2);
    u16* Gy   = (u16*)alloc(DY * DY * 2);
    u16* Gfx  = (u16*)alloc(DF * DF * 2);
    u16* Gfy  = (u16*)alloc(DF * DF * 2);
    u16* A1b  = (u16*)alloc(DX * DF * 2);
    u16* B1Tb = (u16*)alloc(DY * DF * 2);
    u16* Hb   = (u16*)alloc(DX * DY * 2);
    float* H2 = (float*)alloc(DX * DY * 4);
    float* D1 = (float*)alloc(DX * DY * 4);
    float* up = (float*)alloc(Np * 4);
    float* vp = (float*)alloc(Np * 4);
    float* uu = (float*)alloc(N * 4);
    float* vu = (float*)alloc(N * 4);
    float* ua = (float*)alloc(N * 4);
    float* va = (float*)alloc(N * 4);
    float* ap = (float*)alloc(Np * 4);
    float* bp = (float*)alloc(Np * 4);
    float* au = (float*)alloc(N * 4);
    float* bu = (float*)alloc(N * 4);
    float* slots = (float*)alloc(64 * 4);

    const float SCALE = 20.f;   // 1/eps

#define GEMM_F32(A_, B_, C_, M_, N_, K_, al_) \
    gemm_bt<0><<<dim3((N_) / 128, (M_) / 128), 256, 0, stream>>>((A_), (B_), (C_), nullptr, nullptr, nullptr, (M_), (N_), (K_), (al_))
#define GEMM_B16(A_, B_, C_, M_, N_, K_, al_) \
    gemm_bt<1><<<dim3((N_) / 128, (M_) / 128), 256, 0, stream>>>((A_), (B_), nullptr, (C_), nullptr, nullptr, (M_), (N_), (K_), (al_))
#define GEMM_DOT(A_, B_, W_, S_, M_, N_, K_) \
    gemm_bt<2><<<dim3((N_) / 128, (M_) / 128), 256, 0, stream>>>((A_), (B_), nullptr, nullptr, (W_), (S_), (M_), (N_), (K_), 1.0f)

    hipMemsetAsync(slots, 0, 64 * 4, stream);

    // ===== Phase A: anchor covariances =====
    rownorm_w<<<1024, 256, 0, stream>>>(Xa_in, Xa, 4096, 768);
    rownorm_w<<<1024, 256, 0, stream>>>(Ya_in, Ya, 4096, 512);
    transpose_bf16<<<dim3(768 / 32, 4096 / 32), 256, 0, stream>>>(Xa, XaT, 4096, 768);
    transpose_bf16<<<dim3(512 / 32, 4096 / 32), 256, 0, stream>>>(Ya, YaT, 4096, 512);
    GEMM_B16(XaT, XaT, Sxx, 768, 768, 4096, 1.f / 4096.f);
    GEMM_B16(YaT, YaT, Syy, 512, 512, 4096, 1.f / 4096.f);
    GEMM_B16(YaT, XaT, SxyT, 512, 768, 4096, 1.f / 4096.f);

    // ===== Phase B: row norms + Mahalanobis normalization =====
    rownorm_w<<<512, 256, 0, stream>>>(fXp_in, fXp, 2048, 256);
    rownorm_w<<<512, 256, 0, stream>>>(fYp_in, fYp, 2048, 256);
    rownorm_w<<<1024, 256, 0, stream>>>(fX_in, fXn, 4096, 256);
    rownorm_w<<<1024, 256, 0, stream>>>(fY_in, fYn, 4096, 256);
    rownorm_w<<<1024, 256, 0, stream>>>(X_in, Xu, 4096, 768);
    rownorm_w<<<1024, 256, 0, stream>>>(Y_in, Yu, 4096, 512);

    GEMM_F32(Xu, Sxx, XS, 4096, 768, 768, 1.f);
    GEMM_F32(Yu, Syy, YS, 4096, 512, 512, 1.f);
    mahal_w<<<1024, 256, 0, stream>>>(Xu, XS, Xn, 4096, 768);
    mahal_w<<<1024, 256, 0, stream>>>(Yu, YS, Yn, 4096, 512);
    transpose_bf16<<<dim3(768 / 32, 4096 / 32), 256, 0, stream>>>(Xn, XnT, 4096, 768);
    transpose_bf16<<<dim3(512 / 32, 4096 / 32), 256, 0, stream>>>(Yn, YnT, 4096, 512);
    transpose_bf16<<<dim3(256 / 32, 4096 / 32), 256, 0, stream>>>(fXn, fXnT, 4096, 256);
    transpose_bf16<<<dim3(256 / 32, 4096 / 32), 256, 0, stream>>>(fYn, fYnT, 4096, 256);

    // ===== Phase C: pairs block =====
    GEMM_B16(fXp, fYp, cosp, 2048, 2048, 256, 1.f);
    GEMM_B16(fYp, fXp, cospT, 2048, 2048, 256, 1.f);
    {
        hipMemsetAsync(up, 0, Np * 4, stream);
        hipMemsetAsync(vp, 0, Np * 4, stream);
        float la = -logf(2048.f), lb = -logf(2048.f);
        for (int it = 0; it < 10; ++it) {
            row_lse_w<<<512, 256, 0, stream>>>(cosp, vp, up, 2048, 2048, SCALE, la);
            row_lse_w<<<512, 256, 0, stream>>>(cospT, up, vp, 2048, 2048, SCALE, lb);
        }
    }
    plan_row_w<<<512, 256, 0, stream>>>(cosp, up, vp, nullptr, ap, 2048, 2048, SCALE);
    plan_row_w<<<512, 256, 0, stream>>>(cospT, vp, up, nullptr, bp, 2048, 2048, SCALE);
    marg_kernel<<<1, 256, 0, stream>>>(ap, 2048, 1.f / 2048.f, slots + 0);
    marg_kernel<<<1, 256, 0, stream>>>(bp, 2048, 1.f / 2048.f, slots + 0);
    sail_row_w<<<512, 256, 0, stream>>>(cosp, 2048, 10.f, slots + 1);
    diag2<<<1, 256, 0, stream>>>(cosp, up, vp, 2048, SCALE, slots + 2, slots + 3);

    // ===== Phase D: L_div gram matrices =====
    GEMM_B16(XnT, XnT, Gx, 768, 768, 4096, 1.f);
    GEMM_B16(YnT, YnT, Gy, 512, 512, 4096, 1.f);
    GEMM_B16(fXnT, fXnT, Gfx, 256, 256, 4096, 1.f);
    GEMM_B16(fYnT, fYnT, Gfy, 256, 256, 4096, 1.f);
    GEMM_B16(XnT, fXnT, A1b, 768, 256, 4096, 1.f);
    GEMM_B16(YnT, fYnT, B1Tb, 512, 256, 4096, 1.f);
    GEMM_B16(Gx, SxyT, Hb, 768, 512, 768, 1.f);
    GEMM_F32(Hb, Gy, H2, 768, 512, 512, 1.f);
    GEMM_F32(A1b, B1Tb, D1, 768, 512, 256, 1.f);
    dotT<<<192, 256, 0, stream>>>(H2, SxyT, 768, 512, slots + 5);
    dot_bb<<<64, 256, 0, stream>>>(Gfx, Gfy, 256 * 256, slots + 6);
    dotT<<<192, 256, 0, stream>>>(D1, SxyT, 768, 512, slots + 7);

    // ===== Phase E: latent sinkhorn =====
    GEMM_B16(fXn, fYn, Cu, 4096, 4096, 256, 1.f);
    GEMM_B16(fYn, fXn, CuT, 4096, 4096, 256, 1.f);
    {
        hipMemsetAsync(uu, 0, N * 4, stream);
        hipMemsetAsync(vu, 0, N * 4, stream);
        float la = -logf(4096.f), lb = -logf(4096.f);
        for (int it = 0; it < 10; ++it) {
            row_lse_w<<<1024, 256, 0, stream>>>(Cu, vu, uu, 4096, 4096, SCALE, la);
            row_lse_w<<<1024, 256, 0, stream>>>(CuT, uu, vu, 4096, 4096, SCALE, lb);
        }
    }
    plan_row_w<<<1024, 256, 0, stream>>>(Cu, uu, vu, plan, au, 4096, 4096, SCALE);
    plan_row_w<<<1024, 256, 0, stream>>>(CuT, vu, uu, planT, bu, 4096, 4096, SCALE);
    marg_kernel<<<1, 256, 0, stream>>>(au, 4096, 1.f / 4096.f, slots + 0);
    marg_kernel<<<1, 256, 0, stream>>>(bu, 4096, 1.f / 4096.f, slots + 0);

    // ===== Phase F: anchor sinkhorn + L_ot =====
    GEMM_B16(Xn, SxyT, Tb, 4096, 512, 768, 1.f);
    GEMM_B16(Tb, Yn, Ca, 4096, 4096, 512, 1.f);
    GEMM_B16(Yn, Tb, CaT, 4096, 4096, 512, 1.f);
    {
        hipMemsetAsync(ua, 0, N * 4, stream);
        hipMemsetAsync(va, 0, N * 4, stream);
        float la = -logf(4096.f), lb = -logf(4096.f);
        for (int it = 0; it < 10; ++it) {
            row_lse_w<<<1024, 256, 0, stream>>>(Ca, va, ua, 4096, 4096, SCALE, la);
            row_lse_w<<<1024, 256, 0, stream>>>(CaT, ua, va, 4096, 4096, SCALE, lb);
        }
    }
    ot_row_w<<<1024, 256, 0, stream>>>(Ca, Cu, ua, va, uu, vu, 4096, 4096, SCALE, slots + 4);

    // ===== Phase G: Gromov-Wasserstein =====
    GEMM_B16(Xu, Xu, Kx, 4096, 4096, 768, 1.f);
    GEMM_B16(Yu, Yu, Ky, 4096, 4096, 512, 1.f);
    gw_quad_w<<<1024, 256, 0, stream>>>(Kx, au, 4096, slots + 8);
    gw_quad_w<<<1024, 256, 0, stream>>>(Ky, bu, 4096, slots + 9);
    GEMM_B16(Kx, planT, P1, 4096, 4096, 4096, 1.f);
    GEMM_DOT(P1, Ky, plan, slots + 10, 4096, 4096, 4096);

    combine<<<1, 1, 0, stream>>>(slots, out);

#undef GEMM_F32
#undef GEMM_B16
#undef GEMM_DOT
}

// Round 4
// 1529.689 us; speedup vs baseline: 2.2424x; 1.4474x over previous
//
#include <hip/hip_runtime.h>
#include <hip/hip_bf16.h>
#include <math.h>

using u16 = unsigned short;
using s8v = __attribute__((ext_vector_type(8))) short;   // 8 bf16 (4 VGPRs) - MFMA A/B frag
using s4v = __attribute__((ext_vector_type(4))) short;   // 4 bf16
using f4v = __attribute__((ext_vector_type(4))) float;   // MFMA C/D frag

__device__ __forceinline__ float b2f(u16 x) {
    unsigned int u = ((unsigned int)x) << 16;
    return __uint_as_float(u);
}
__device__ __forceinline__ u16 f2b(float f) {
    unsigned int x = __float_as_uint(f);
    unsigned int r = x + 0x7fffu + ((x >> 16) & 1u);   // RNE
    return (u16)(r >> 16);
}

// async global->LDS, 16B per lane; lds base must be wave-uniform (lane scatter = lane*16)
__device__ __forceinline__ void a16(u16* lds, const u16* g) {
    __builtin_amdgcn_global_load_lds((__attribute__((address_space(1))) void*)g,
                                     (__attribute__((address_space(3))) void*)lds,
                                     16, 0, 0);
}

// ---------------- reductions ----------------
__device__ __forceinline__ float block_sum(float v, float* buf) {
    int t = threadIdx.x;
    buf[t] = v; __syncthreads();
    for (int s = 128; s > 0; s >>= 1) {
        if (t < s) buf[t] += buf[t + s];
        __syncthreads();
    }
    float r = buf[0];
    __syncthreads();
    return r;
}

__device__ __forceinline__ float wave_sum(float v) {
#pragma unroll
    for (int off = 32; off; off >>= 1) v += __shfl_xor(v, off, 64);
    return v;
}

// combine 4 per-wave partials -> one atomicAdd per block
__device__ __forceinline__ void block_atomic4(float wval, float* slot) {
    __shared__ float wb[4];
    int lane = threadIdx.x & 63, wv = threadIdx.x >> 6;
    if (lane == 0) wb[wv] = wval;
    __syncthreads();
    if (threadIdx.x == 0) atomicAdd(slot, wb[0] + wb[1] + wb[2] + wb[3]);
}

// ---------------- GEMM: C[M,N] = alpha * A[M,K] @ B[N,K]^T (bf16 in, fp32 acc) ----
// A/B row stride = ld (full K). blockIdx.z selects K-chunk of size K (split-K).
// EPI: 0 -> fp32 C, 1 -> bf16 C, 2 -> atomicAdd(dotAcc, sum(C .* W)), 3 -> atomicAdd fp32 C
#define TBM 128
#define TBN 128
#define TBK 32

template<int EPI>
__global__ __launch_bounds__(256)
void gemm_bt(const u16* __restrict__ A, const u16* __restrict__ B,
             float* __restrict__ Cf, u16* __restrict__ Cb,
             const u16* __restrict__ W, float* __restrict__ dotAcc,
             int M, int N, int K, int ld, float alpha)
{
    __shared__ __align__(16) u16 As[TBM * TBK];
    __shared__ __align__(16) u16 Bs[TBN * TBK];

    const int tid  = threadIdx.x;
    const int lane = tid & 63;
    const int wave = tid >> 6;
    const int wm   = (wave >> 1) * 64;
    const int wn   = (wave & 1) * 64;
    const int l16  = lane & 15;
    const int q4   = lane >> 4;
    const size_t row0 = (size_t)blockIdx.y * TBM;
    const size_t col0 = (size_t)blockIdx.x * TBN;
    const int kOff = blockIdx.z * K;

    f4v acc[4][4];
#pragma unroll
    for (int mt = 0; mt < 4; ++mt)
#pragma unroll
        for (int nt = 0; nt < 4; ++nt)
#pragma unroll
            for (int r = 0; r < 4; ++r)
                acc[mt][nt][r] = 0.f;

    // async staging: 512 16B-chunks per 128x32 tile; wave w covers chunks [w*128, w*128+128)
    // chunk c: row = c>>2, k-oct = c&3; LDS elem offset = c*8 (row-major [128][32])
    const int ar0 = wave * 32 + (lane >> 2);        // chunk c0 = wave*128 + lane
    const int ar1 = ar0 + 16;                       // chunk c1 = c0 + 64
    const int akk = (lane & 3) * 8;
    const u16* gA0 = A + (row0 + ar0) * ld + kOff + akk;
    const u16* gA1 = A + (row0 + ar1) * ld + kOff + akk;
    const u16* gB0 = B + (col0 + ar0) * ld + kOff + akk;
    const u16* gB1 = B + (col0 + ar1) * ld + kOff + akk;
    u16* lA0 = As + wave * 1024;
    u16* lA1 = As + wave * 1024 + 512;
    u16* lB0 = Bs + wave * 1024;
    u16* lB1 = Bs + wave * 1024 + 512;

    for (int k0 = 0; k0 < K; k0 += TBK) {
        __syncthreads();                 // previous iteration's LDS reads done
        a16(lA0, gA0 + k0);
        a16(lA1, gA1 + k0);
        a16(lB0, gB0 + k0);
        a16(lB1, gB1 + k0);
        __syncthreads();                 // drains vmcnt before use

        s8v af[4], bfr[4];
#pragma unroll
        for (int mt = 0; mt < 4; ++mt)
            af[mt] = *(const s8v*)(As + (wm + mt * 16 + l16) * TBK + q4 * 8);
#pragma unroll
        for (int nt = 0; nt < 4; ++nt)
            bfr[nt] = *(const s8v*)(Bs + (wn + nt * 16 + l16) * TBK + q4 * 8);
#pragma unroll
        for (int mt = 0; mt < 4; ++mt)
#pragma unroll
            for (int nt = 0; nt < 4; ++nt)
                acc[mt][nt] = __builtin_amdgcn_mfma_f32_16x16x32_bf16(af[mt], bfr[nt], acc[mt][nt], 0, 0, 0);
    }

    if (EPI == 2) {
        float local = 0.f;
#pragma unroll
        for (int mt = 0; mt < 4; ++mt)
#pragma unroll
            for (int nt = 0; nt < 4; ++nt)
#pragma unroll
                for (int r = 0; r < 4; ++r) {
                    size_t row = row0 + wm + mt * 16 + q4 * 4 + r;
                    size_t col = col0 + wn + nt * 16 + l16;
                    local += acc[mt][nt][r] * b2f(W[row * (size_t)N + col]);
                }
        __shared__ float red[256];
        float tot = block_sum(local, red);
        if (tid == 0) atomicAdd(dotAcc, tot);
    } else {
#pragma unroll
        for (int mt = 0; mt < 4; ++mt)
#pragma unroll
            for (int nt = 0; nt < 4; ++nt)
#pragma unroll
                for (int r = 0; r < 4; ++r) {
                    size_t row = row0 + wm + mt * 16 + q4 * 4 + r;
                    size_t col = col0 + wn + nt * 16 + l16;
                    float v = acc[mt][nt][r] * alpha;
                    if (EPI == 0)      Cf[row * (size_t)N + col] = v;
                    else if (EPI == 1) Cb[row * (size_t)N + col] = f2b(v);
                    else               atomicAdd(&Cf[row * (size_t)N + col], v);
                }
    }
}

// ---------------- wave-per-row elementwise / staging ----------------
__global__ __launch_bounds__(256)
void rownorm_w(const float* __restrict__ in, u16* __restrict__ out, int nrows, int C) {
    int row = (blockIdx.x * 256 + threadIdx.x) >> 6;
    int lane = threadIdx.x & 63;
    if (row >= nrows) return;
    const float4* r4 = (const float4*)(in + (size_t)row * C);
    int nv = C >> 2;
    float ss = 0.f;
    for (int c = lane; c < nv; c += 64) {
        float4 v = r4[c];
        ss += v.x * v.x + v.y * v.y + v.z * v.z + v.w * v.w;
    }
    ss = wave_sum(ss);
    float inv = 1.f / fmaxf(sqrtf(ss), 1e-8f);
    s4v* o4 = (s4v*)(out + (size_t)row * C);
    for (int c = lane; c < nv; c += 64) {
        float4 v = r4[c];
        s4v o;
        o[0] = (short)f2b(v.x * inv); o[1] = (short)f2b(v.y * inv);
        o[2] = (short)f2b(v.z * inv); o[3] = (short)f2b(v.w * inv);
        o4[c] = o;
    }
}

__global__ __launch_bounds__(256)
void mahal_w(const u16* __restrict__ Xh, const float* __restrict__ XS,
             u16* __restrict__ out, int nrows, int C) {
    int row = (blockIdx.x * 256 + threadIdx.x) >> 6;
    int lane = threadIdx.x & 63;
    if (row >= nrows) return;
    const s4v* x4 = (const s4v*)(Xh + (size_t)row * C);
    const float4* s4 = (const float4*)(XS + (size_t)row * C);
    int nv = C >> 2;
    float s = 0.f;
    for (int c = lane; c < nv; c += 64) {
        s4v x = x4[c]; float4 v = s4[c];
        s += b2f((u16)x[0]) * v.x + b2f((u16)x[1]) * v.y
           + b2f((u16)x[2]) * v.z + b2f((u16)x[3]) * v.w;
    }
    s = wave_sum(s);
    float inv = 1.f / fmaxf(sqrtf(fmaxf(s, 0.f)), 1e-8f);
    s4v* o4 = (s4v*)(out + (size_t)row * C);
    for (int c = lane; c < nv; c += 64) {
        s4v x = x4[c], o;
#pragma unroll
        for (int k = 0; k < 4; ++k) o[k] = (short)f2b(b2f((u16)x[k]) * inv);
        o4[c] = o;
    }
}

__global__ __launch_bounds__(256)
void transpose_bf16(const u16* __restrict__ in, u16* __restrict__ out, int R, int C) {
    __shared__ u16 tile[32][33];
    int bx = blockIdx.x * 32, by = blockIdx.y * 32;
    int tx = threadIdx.x & 31;
    int ty = threadIdx.x >> 5;
    for (int i = ty; i < 32; i += 8)
        tile[i][tx] = in[(size_t)(by + i) * C + bx + tx];
    __syncthreads();
    for (int i = ty; i < 32; i += 8)
        out[(size_t)(bx + i) * R + by + tx] = tile[tx][i];
}

__global__ __launch_bounds__(256)
void cast_f2b(const float* __restrict__ in, u16* __restrict__ out, int n) {
    for (int i = blockIdx.x * 256 + threadIdx.x; i < n; i += gridDim.x * 256)
        out[i] = f2b(in[i]);
}

// ---------------- sinkhorn row pass (no-max sum-exp; logits bounded ~|32|) -----
// u[i] = logmarg - log(sum_j exp(scale*C[i,j] + vin[j]))
__device__ __forceinline__ float row_sumexp(const u16* __restrict__ rowp,
                                            const float* __restrict__ vin,
                                            int ny, float scale, int lane) {
    const s8v* r8 = (const s8v*)rowp;
    const float4* v4 = (const float4*)vin;
    int nv = ny >> 3;
    float s = 0.f;
    for (int c = lane; c < nv; c += 64) {
        s8v v8 = r8[c];
        float4 va = v4[c * 2], vb = v4[c * 2 + 1];
        s += __expf(b2f((u16)v8[0]) * scale + va.x);
        s += __expf(b2f((u16)v8[1]) * scale + va.y);
        s += __expf(b2f((u16)v8[2]) * scale + va.z);
        s += __expf(b2f((u16)v8[3]) * scale + va.w);
        s += __expf(b2f((u16)v8[4]) * scale + vb.x);
        s += __expf(b2f((u16)v8[5]) * scale + vb.y);
        s += __expf(b2f((u16)v8[6]) * scale + vb.z);
        s += __expf(b2f((u16)v8[7]) * scale + vb.w);
    }
    return wave_sum(s);
}

__global__ __launch_bounds__(256)
void row_lse_w(const u16* __restrict__ C, const float* __restrict__ vin,
               float* __restrict__ uout, int nrows, int ny, float scale, float logmarg) {
    int row = (blockIdx.x * 256 + threadIdx.x) >> 6;
    int lane = threadIdx.x & 63;
    if (row >= nrows) return;
    float s = row_sumexp(C + (size_t)row * ny, vin, ny, scale, lane);
    if (lane == 0) uout[row] = logmarg - __logf(s);
}

// fused dual-problem pass: blocks [0,1024) -> problem 1, [1024,2048) -> problem 2
__global__ __launch_bounds__(256)
void row_lse_dual(const u16* __restrict__ C1, const float* __restrict__ v1, float* __restrict__ u1,
                  const u16* __restrict__ C2, const float* __restrict__ v2, float* __restrict__ u2,
                  int n, float scale, float logmarg) {
    int gw = (blockIdx.x * 256 + threadIdx.x) >> 6;
    int lane = threadIdx.x & 63;
    const u16* C = (gw < n) ? C1 : C2;
    const float* v = (gw < n) ? v1 : v2;
    float* u = (gw < n) ? u1 : u2;
    int row = (gw < n) ? gw : gw - n;
    if (row >= n) return;
    float s = row_sumexp(C + (size_t)row * n, v, n, scale, lane);
    if (lane == 0) u[row] = logmarg - __logf(s);
}

// plan[i,j] = exp(scale*C[i,j]+uin[i]+vin[j]); rowsum[i] = sum_j
__global__ __launch_bounds__(256)
void plan_row_w(const u16* __restrict__ C, const float* __restrict__ uin,
                const float* __restrict__ vin, u16* __restrict__ plan,
                float* __restrict__ rowsum, int nrows, int ny, float scale) {
    int row = (blockIdx.x * 256 + threadIdx.x) >> 6;
    int lane = threadIdx.x & 63;
    if (row >= nrows) return;
    const s8v* r8 = (const s8v*)(C + (size_t)row * ny);
    s8v* p8 = plan ? (s8v*)(plan + (size_t)row * ny) : nullptr;
    const float4* v4 = (const float4*)vin;
    float ui = uin[row], s = 0.f;
    int nv = ny >> 3;
    for (int c = lane; c < nv; c += 64) {
        s8v v8 = r8[c], pb;
        float4 va = v4[c * 2], vb = v4[c * 2 + 1];
        float vv[8] = {va.x, va.y, va.z, va.w, vb.x, vb.y, vb.z, vb.w};
#pragma unroll
        for (int k = 0; k < 8; ++k) {
            float p = __expf(b2f((u16)v8[k]) * scale + ui + vv[k]);
            s += p;
            pb[k] = (short)f2b(p);
        }
        if (p8) p8[c] = pb;
    }
    s = wave_sum(s);
    if (lane == 0) rowsum[row] = s;
}

__global__ __launch_bounds__(256)
void marg_kernel(const float* __restrict__ sv, int n, float target, float* __restrict__ slot) {
    int t = threadIdx.x;
    float s = 0.f;
    for (int i = t; i < n; i += 256) { float d = sv[i] - target; s += d * d; }
    __shared__ float buf[256];
    float tot = block_sum(s, buf);
    if (t == 0) atomicAdd(slot, tot);
}

__global__ __launch_bounds__(256)
void ot_row_w(const u16* __restrict__ Ca, const u16* __restrict__ Cu,
              const float* __restrict__ ua, const float* __restrict__ va,
              const float* __restrict__ uu, const float* __restrict__ vu,
              int nrows, int ny, float scale, float* __restrict__ slot) {
    int row = (blockIdx.x * 256 + threadIdx.x) >> 6;
    int lane = threadIdx.x & 63;
    float local = 0.f;
    if (row < nrows) {
        const s8v* ra = (const s8v*)(Ca + (size_t)row * ny);
        const s8v* ru = (const s8v*)(Cu + (size_t)row * ny);
        const float4* va4 = (const float4*)va;
        const float4* vu4 = (const float4*)vu;
        float uai = ua[row], uui = uu[row];
        int nv = ny >> 3;
        for (int c = lane; c < nv; c += 64) {
            s8v a8 = ra[c], u8 = ru[c];
            float4 a0 = va4[c * 2], a1 = va4[c * 2 + 1];
            float4 u0 = vu4[c * 2], u1 = vu4[c * 2 + 1];
            float av[8] = {a0.x, a0.y, a0.z, a0.w, a1.x, a1.y, a1.z, a1.w};
            float uv[8] = {u0.x, u0.y, u0.z, u0.w, u1.x, u1.y, u1.z, u1.w};
#pragma unroll
            for (int k = 0; k < 8; ++k) {
                float lpa = b2f((u16)a8[k]) * scale + uai + av[k];
                float lpu = b2f((u16)u8[k]) * scale + uui + uv[k];
                local += __expf(lpa) * (lpa - lpu);
            }
        }
    }
    local = wave_sum(local);
    block_atomic4(local, slot);
}

__global__ __launch_bounds__(256)
void sail_row_w(const u16* __restrict__ cosb, int n, float temp, float* __restrict__ slot) {
    int row = (blockIdx.x * 256 + threadIdx.x) >> 6;
    int lane = threadIdx.x & 63;
    float local = 0.f;
    if (row < n) {
        const s8v* r8 = (const s8v*)(cosb + (size_t)row * n);
        int nv = n >> 3;
        for (int c = lane; c < nv; c += 64) {
            s8v v8 = r8[c];
#pragma unroll
            for (int k = 0; k < 8; ++k) {
                int j = c * 8 + k;
                float cv = b2f((u16)v8[k]);
                float wgt = cv * ((j == row) ? temp : -temp);
                local -= fminf(wgt, 0.f) - log1pf(__expf(-fabsf(wgt)));
            }
        }
    }
    local = wave_sum(local);
    block_atomic4(local, slot);
}

__global__ __launch_bounds__(256)
void diag2(const u16* __restrict__ cosb, const float* __restrict__ up,
           const float* __restrict__ vp, int n, float scale,
           float* __restrict__ slotExp, float* __restrict__ slotImp) {
    int t = threadIdx.x;
    float e = 0.f, im = 0.f;
    float logn = logf((float)n);
    for (int i = t; i < n; i += 256) {
        float c = b2f(cosb[(size_t)i * n + i]);
        e  += (1.f - c) * 0.5f;
        im += scale * c + up[i] + vp[i] + logn;
    }
    __shared__ float buf[256];
    float te = block_sum(e, buf);
    float ti = block_sum(im, buf);
    if (t == 0) { atomicAdd(slotExp, te); atomicAdd(slotImp, ti); }
}

__global__ __launch_bounds__(256)
void gw_quad_w(const u16* __restrict__ Kb, const float* __restrict__ wv, int n,
               float* __restrict__ slot) {
    int row = (blockIdx.x * 256 + threadIdx.x) >> 6;
    int lane = threadIdx.x & 63;
    float local = 0.f;
    if (row < n) {
        const s8v* r8 = (const s8v*)(Kb + (size_t)row * n);
        const float4* w4 = (const float4*)wv;
        int nv = n >> 3;
        for (int c = lane; c < nv; c += 64) {
            s8v v8 = r8[c];
            float4 w0 = w4[c * 2], w1 = w4[c * 2 + 1];
            float ww[8] = {w0.x, w0.y, w0.z, w0.w, w1.x, w1.y, w1.z, w1.w};
#pragma unroll
            for (int k = 0; k < 8; ++k) {
                float kv = b2f((u16)v8[k]);
                local += kv * kv * ww[k];
            }
        }
        local = wave_sum(local) * wv[row];
        if (lane != 0) local = 0.f;
    }
    block_atomic4(local, slot);
}

// sum over a,b of Mf[a,b] * Tb[b,a]   (Mf: R x Cc fp32, Tb: Cc x R bf16)
__global__ __launch_bounds__(256)
void dotT(const float* __restrict__ Mf, const u16* __restrict__ Tb, int R, int Cc,
          float* __restrict__ slot) {
    int t = threadIdx.x;
    int total = R * Cc;
    float local = 0.f;
    for (int idx = blockIdx.x * 256 + t; idx < total; idx += gridDim.x * 256) {
        int a = idx / Cc, b = idx - a * Cc;
        local += Mf[idx] * b2f(Tb[(size_t)b * R + a]);
    }
    __shared__ float buf[256];
    float tot = block_sum(local, buf);
    if (t == 0) atomicAdd(slot, tot);
}

__global__ __launch_bounds__(256)
void dot_bb(const u16* __restrict__ A, const u16* __restrict__ B, int n,
            float* __restrict__ slot) {
    int t = threadIdx.x;
    float local = 0.f;
    for (int i = blockIdx.x * 256 + t; i < n; i += gridDim.x * 256)
        local += b2f(A[i]) * b2f(B[i]);
    __shared__ float buf[256];
    float tot = block_sum(local, buf);
    if (t == 0) atomicAdd(slot, tot);
}

// slots: 0 marg, 1 sail, 2 exp, 3 imp, 4 ot, 5 norm1, 6 norm2, 7 dot, 8 gw1, 9 gw2, 10 sandwich
__global__ void combine(const float* __restrict__ s, float* __restrict__ out) {
    if (threadIdx.x == 0 && blockIdx.x == 0) {
        float Np = 2048.f;
        float Nu2 = 4096.f * 4096.f;
        float total = s[0]
                    + s[1] / (Np * Np)
                    + s[2] / Np
                    - s[3] / Np
                    + s[4]
                    + (s[5] + s[6] - 2.f * s[7]) / Nu2
                    + s[8] + s[9] - 2.f * s[10];
        out[0] = total;
    }
}

// ------------------------------------------------------------------
extern "C" void kernel_launch(void* const* d_in, const int* in_sizes, int n_in,
                              void* d_out, int out_size, void* d_ws, size_t ws_size,
                              hipStream_t stream) {
    const float* fXp_in = (const float*)d_in[0];   // 2048 x 256
    const float* fYp_in = (const float*)d_in[1];   // 2048 x 256
    const float* X_in   = (const float*)d_in[2];   // 4096 x 768
    const float* Y_in   = (const float*)d_in[3];   // 4096 x 512
    const float* fX_in  = (const float*)d_in[4];   // 4096 x 256
    const float* fY_in  = (const float*)d_in[5];   // 4096 x 256
    const float* Xa_in  = (const float*)d_in[6];   // 4096 x 768
    const float* Ya_in  = (const float*)d_in[7];   // 4096 x 512
    float* out = (float*)d_out;

    char* w = (char*)d_ws;
    size_t off = 0;
    auto alloc = [&](size_t bytes) -> char* {
        char* p = w + off;
        off += (bytes + 255) & ~(size_t)255;
        return p;
    };

    const size_t N = 4096, Np = 2048, DX = 768, DY = 512, DF = 256;

    // ---- five shared 32 MB N x N slots (lifetime-scheduled) ----
    const size_t SLOT = N * N * 2;
    char* S1 = alloc(SLOT);
    char* S2 = alloc(SLOT);
    char* S3 = alloc(SLOT);
    char* S4 = alloc(SLOT);
    char* S5 = alloc(SLOT);

    u16* Xa    = (u16*)S1;
    u16* Ya    = (u16*)S2;
    float* XS  = (float*)S4;
    float* YS  = (float*)S5;
    u16* cosp  = (u16*)S3;
    u16* cospT = (u16*)S4;
    u16* Cu    = (u16*)S1;
    u16* CuT   = (u16*)S2;
    u16* Ca    = (u16*)S3;
    u16* CaT   = (u16*)S4;     // alive through anchor sinkhorn only
    u16* plan  = (u16*)S5;
    u16* planT = (u16*)S4;     // after CaT dead
    u16* Kx    = (u16*)S1;     // after Cu dead
    u16* Ky    = (u16*)S3;     // after Ca dead
    u16* P1    = (u16*)S2;     // after CuT dead

    // ---- dedicated bf16 buffers ----
    u16* XaT  = (u16*)alloc(N * DX * 2);
    u16* YaT  = (u16*)alloc(N * DY * 2);
    u16* fXp  = (u16*)alloc(Np * DF * 2);
    u16* fYp  = (u16*)alloc(Np * DF * 2);
    u16* fXn  = (u16*)alloc(N * DF * 2);
    u16* fYn  = (u16*)alloc(N * DF * 2);
    u16* fXnT = (u16*)alloc(N * DF * 2);
    u16* fYnT = (u16*)alloc(N * DF * 2);
    u16* Xu   = (u16*)alloc(N * DX * 2);
    u16* Yu   = (u16*)alloc(N * DY * 2);
    u16* Xn   = (u16*)alloc(N * DX * 2);
    u16* Yn   = (u16*)alloc(N * DY * 2);
    u16* XnT  = (u16*)alloc(N * DX * 2);
    u16* YnT  = (u16*)alloc(N * DY * 2);
    u16* Sxx  = (u16*)alloc(DX * DX * 2);
    u16* Syy  = (u16*)alloc(DY * DY * 2);
    u16* SxyT = (u16*)alloc(DY * DX * 2);
    u16* Tb   = (u16*)alloc(N * DY * 2);
    u16* Gx   = (u16*)alloc(DX * DX * 2);
    u16* Gy   = (u16*)alloc(DY * DY * 2);
    u16* Gfx  = (u16*)alloc(DF * DF * 2);
    u16* Gfy  = (u16*)alloc(DF * DF * 2);
    u16* A1b  = (u16*)alloc(DX * DF * 2);
    u16* B1Tb = (u16*)alloc(DY * DF * 2);
    u16* Hb   = (u16*)alloc(DX * DY * 2);
    float* H2 = (float*)alloc(DX * DY * 4);
    float* D1 = (float*)alloc(DX * DY * 4);
    float* ap = (float*)alloc(Np * 4);
    float* bp = (float*)alloc(Np * 4);
    float* au = (float*)alloc(N * 4);
    float* bu = (float*)alloc(N * 4);

    // ---- zero zone: slots + potentials + split-K fp32 accumulators (ONE memset) ----
    char* zero_begin = w + off;
    float* slots = (float*)alloc(64 * 4);
    float* up = (float*)alloc(Np * 4);
    float* vp = (float*)alloc(Np * 4);
    float* uu = (float*)alloc(N * 4);
    float* vu = (float*)alloc(N * 4);
    float* ua = (float*)alloc(N * 4);
    float* va = (float*)alloc(N * 4);
    float* SxxF  = (float*)alloc(DX * DX * 4);
    float* SyyF  = (float*)alloc(DY * DY * 4);
    float* SxyTF = (float*)alloc(DY * DX * 4);
    float* GxF   = (float*)alloc(DX * DX * 4);
    float* GyF   = (float*)alloc(DY * DY * 4);
    float* GfxF  = (float*)alloc(DF * DF * 4);
    float* GfyF  = (float*)alloc(DF * DF * 4);
    float* A1F   = (float*)alloc(DX * DF * 4);
    float* B1F   = (float*)alloc(DY * DF * 4);
    size_t zero_bytes = (size_t)((w + off) - zero_begin);

    const float SCALE = 20.f;   // 1/eps

#define GEMM_F32(A_, B_, C_, M_, N_, K_, al_) \
    gemm_bt<0><<<dim3((N_) / 128, (M_) / 128), 256, 0, stream>>>((A_), (B_), (C_), nullptr, nullptr, nullptr, (M_), (N_), (K_), (K_), (al_))
#define GEMM_B16(A_, B_, C_, M_, N_, K_, al_) \
    gemm_bt<1><<<dim3((N_) / 128, (M_) / 128), 256, 0, stream>>>((A_), (B_), nullptr, (C_), nullptr, nullptr, (M_), (N_), (K_), (K_), (al_))
#define GEMM_DOT(A_, B_, W_, S_, M_, N_, K_) \
    gemm_bt<2><<<dim3((N_) / 128, (M_) / 128), 256, 0, stream>>>((A_), (B_), nullptr, nullptr, (W_), (S_), (M_), (N_), (K_), (K_), 1.0f)
// split-K (8-way) into fp32 accumulator, then cast to bf16
#define GEMM_SK(A_, B_, CF_, CB_, M_, N_, Kfull_, al_) \
    do { \
        gemm_bt<3><<<dim3((N_) / 128, (M_) / 128, 8), 256, 0, stream>>>((A_), (B_), (CF_), nullptr, nullptr, nullptr, (M_), (N_), (Kfull_) / 8, (Kfull_), (al_)); \
        cast_f2b<<<256, 256, 0, stream>>>((CF_), (CB_), (M_) * (N_)); \
    } while (0)

    hipMemsetAsync(zero_begin, 0, zero_bytes, stream);

    // ===== Phase A: anchor covariances (split-K) =====
    rownorm_w<<<1024, 256, 0, stream>>>(Xa_in, Xa, 4096, 768);
    rownorm_w<<<1024, 256, 0, stream>>>(Ya_in, Ya, 4096, 512);
    transpose_bf16<<<dim3(768 / 32, 4096 / 32), 256, 0, stream>>>(Xa, XaT, 4096, 768);
    transpose_bf16<<<dim3(512 / 32, 4096 / 32), 256, 0, stream>>>(Ya, YaT, 4096, 512);
    GEMM_SK(XaT, XaT, SxxF, Sxx, 768, 768, 4096, 1.f / 4096.f);
    GEMM_SK(YaT, YaT, SyyF, Syy, 512, 512, 4096, 1.f / 4096.f);
    GEMM_SK(YaT, XaT, SxyTF, SxyT, 512, 768, 4096, 1.f / 4096.f);

    // ===== Phase B: row norms + Mahalanobis normalization =====
    rownorm_w<<<512, 256, 0, stream>>>(fXp_in, fXp, 2048, 256);
    rownorm_w<<<512, 256, 0, stream>>>(fYp_in, fYp, 2048, 256);
    rownorm_w<<<1024, 256, 0, stream>>>(fX_in, fXn, 4096, 256);
    rownorm_w<<<1024, 256, 0, stream>>>(fY_in, fYn, 4096, 256);
    rownorm_w<<<1024, 256, 0, stream>>>(X_in, Xu, 4096, 768);
    rownorm_w<<<1024, 256, 0, stream>>>(Y_in, Yu, 4096, 512);

    GEMM_F32(Xu, Sxx, XS, 4096, 768, 768, 1.f);
    GEMM_F32(Yu, Syy, YS, 4096, 512, 512, 1.f);
    mahal_w<<<1024, 256, 0, stream>>>(Xu, XS, Xn, 4096, 768);
    mahal_w<<<1024, 256, 0, stream>>>(Yu, YS, Yn, 4096, 512);
    transpose_bf16<<<dim3(768 / 32, 4096 / 32), 256, 0, stream>>>(Xn, XnT, 4096, 768);
    transpose_bf16<<<dim3(512 / 32, 4096 / 32), 256, 0, stream>>>(Yn, YnT, 4096, 512);
    transpose_bf16<<<dim3(256 / 32, 4096 / 32), 256, 0, stream>>>(fXn, fXnT, 4096, 256);
    transpose_bf16<<<dim3(256 / 32, 4096 / 32), 256, 0, stream>>>(fYn, fYnT, 4096, 256);

    // ===== Phase C: pairs block =====
    GEMM_B16(fXp, fYp, cosp, 2048, 2048, 256, 1.f);
    GEMM_B16(fYp, fXp, cospT, 2048, 2048, 256, 1.f);
    {
        float la = -logf(2048.f), lb = -logf(2048.f);
        for (int it = 0; it < 10; ++it) {
            row_lse_w<<<512, 256, 0, stream>>>(cosp, vp, up, 2048, 2048, SCALE, la);
            row_lse_w<<<512, 256, 0, stream>>>(cospT, up, vp, 2048, 2048, SCALE, lb);
        }
    }
    plan_row_w<<<512, 256, 0, stream>>>(cosp, up, vp, nullptr, ap, 2048, 2048, SCALE);
    plan_row_w<<<512, 256, 0, stream>>>(cospT, vp, up, nullptr, bp, 2048, 2048, SCALE);
    marg_kernel<<<1, 256, 0, stream>>>(ap, 2048, 1.f / 2048.f, slots + 0);
    marg_kernel<<<1, 256, 0, stream>>>(bp, 2048, 1.f / 2048.f, slots + 0);
    sail_row_w<<<512, 256, 0, stream>>>(cosp, 2048, 10.f, slots + 1);
    diag2<<<1, 256, 0, stream>>>(cosp, up, vp, 2048, SCALE, slots + 2, slots + 3);

    // ===== Phase D: L_div gram matrices (split-K on K=4096) =====
    GEMM_SK(XnT, XnT, GxF, Gx, 768, 768, 4096, 1.f);
    GEMM_SK(YnT, YnT, GyF, Gy, 512, 512, 4096, 1.f);
    GEMM_SK(fXnT, fXnT, GfxF, Gfx, 256, 256, 4096, 1.f);
    GEMM_SK(fYnT, fYnT, GfyF, Gfy, 256, 256, 4096, 1.f);
    GEMM_SK(XnT, fXnT, A1F, A1b, 768, 256, 4096, 1.f);
    GEMM_SK(YnT, fYnT, B1F, B1Tb, 512, 256, 4096, 1.f);
    GEMM_B16(Gx, SxyT, Hb, 768, 512, 768, 1.f);
    GEMM_F32(Hb, Gy, H2, 768, 512, 512, 1.f);
    GEMM_F32(A1b, B1Tb, D1, 768, 512, 256, 1.f);
    dotT<<<192, 256, 0, stream>>>(H2, SxyT, 768, 512, slots + 5);
    dot_bb<<<64, 256, 0, stream>>>(Gfx, Gfy, 256 * 256, slots + 6);
    dotT<<<192, 256, 0, stream>>>(D1, SxyT, 768, 512, slots + 7);

    // ===== Phase E+F: latent & anchor sinkhorns, fused per half-iteration =====
    GEMM_B16(fXn, fYn, Cu, 4096, 4096, 256, 1.f);    // -> S1
    GEMM_B16(fYn, fXn, CuT, 4096, 4096, 256, 1.f);   // -> S2
    GEMM_B16(Xn, SxyT, Tb, 4096, 512, 768, 1.f);
    GEMM_B16(Tb, Yn, Ca, 4096, 4096, 512, 1.f);      // -> S3
    GEMM_B16(Yn, Tb, CaT, 4096, 4096, 512, 1.f);     // -> S4
    {
        float lm = -logf(4096.f);
        for (int it = 0; it < 10; ++it) {
            row_lse_dual<<<2048, 256, 0, stream>>>(Cu, vu, uu, Ca, va, ua, 4096, SCALE, lm);
            row_lse_dual<<<2048, 256, 0, stream>>>(CuT, uu, vu, CaT, ua, va, 4096, SCALE, lm);
        }
    }
    // CaT (S4) dead after sinkhorn
    plan_row_w<<<1024, 256, 0, stream>>>(Cu, uu, vu, plan, au, 4096, 4096, SCALE);    // -> S5
    plan_row_w<<<1024, 256, 0, stream>>>(CuT, vu, uu, planT, bu, 4096, 4096, SCALE);  // -> S4
    marg_kernel<<<1, 256, 0, stream>>>(au, 4096, 1.f / 4096.f, slots + 0);
    marg_kernel<<<1, 256, 0, stream>>>(bu, 4096, 1.f / 4096.f, slots + 0);
    ot_row_w<<<1024, 256, 0, stream>>>(Ca, Cu, ua, va, uu, vu, 4096, 4096, SCALE, slots + 4);
    // Cu (S1), CuT (S2), Ca (S3) dead

    // ===== Phase G: Gromov-Wasserstein =====
    GEMM_B16(Xu, Xu, Kx, 4096, 4096, 768, 1.f);     // -> S1
    GEMM_B16(Yu, Yu, Ky, 4096, 4096, 512, 1.f);     // -> S3
    gw_quad_w<<<1024, 256, 0, stream>>>(Kx, au, 4096, slots + 8);
    gw_quad_w<<<1024, 256, 0, stream>>>(Ky, bu, 4096, slots + 9);
    GEMM_B16(Kx, planT, P1, 4096, 4096, 4096, 1.f); // Kx @ plan -> S2
    GEMM_DOT(P1, Ky, plan, slots + 10, 4096, 4096, 4096);

    combine<<<1, 1, 0, stream>>>(slots, out);

#undef GEMM_F32
#undef GEMM_B16
#undef GEMM_DOT
#undef GEMM_SK
}

// Round 5
// 1299.201 us; speedup vs baseline: 2.6402x; 1.1774x over previous
//
#include <hip/hip_runtime.h>
#include <hip/hip_bf16.h>
#include <math.h>

using u16 = unsigned short;
using s8v = __attribute__((ext_vector_type(8))) short;   // 8 bf16 (4 VGPRs) - MFMA A/B frag
using s4v = __attribute__((ext_vector_type(4))) short;   // 4 bf16
using f4v = __attribute__((ext_vector_type(4))) float;   // MFMA C/D frag

__device__ __forceinline__ float b2f(u16 x) {
    unsigned int u = ((unsigned int)x) << 16;
    return __uint_as_float(u);
}
__device__ __forceinline__ u16 f2b(float f) {
    unsigned int x = __float_as_uint(f);
    unsigned int r = x + 0x7fffu + ((x >> 16) & 1u);   // RNE
    return (u16)(r >> 16);
}

// async global->LDS, 16B per lane; lds base wave-uniform (lane scatter = lane*16)
__device__ __forceinline__ void a16(u16* lds, const u16* g) {
    __builtin_amdgcn_global_load_lds((__attribute__((address_space(1))) void*)g,
                                     (__attribute__((address_space(3))) void*)lds,
                                     16, 0, 0);
}

// ---------------- reductions ----------------
__device__ __forceinline__ float block_sum(float v, float* buf) {
    int t = threadIdx.x;
    buf[t] = v; __syncthreads();
    for (int s = 128; s > 0; s >>= 1) {
        if (t < s) buf[t] += buf[t + s];
        __syncthreads();
    }
    float r = buf[0];
    __syncthreads();
    return r;
}

__device__ __forceinline__ float wave_sum(float v) {
#pragma unroll
    for (int off = 32; off; off >>= 1) v += __shfl_xor(v, off, 64);
    return v;
}

__device__ __forceinline__ void block_atomic4(float wval, float* slot) {
    __shared__ float wb[4];
    int lane = threadIdx.x & 63, wv = threadIdx.x >> 6;
    if (lane == 0) wb[wv] = wval;
    __syncthreads();
    if (threadIdx.x == 0) atomicAdd(slot, wb[0] + wb[1] + wb[2] + wb[3]);
}

// ---------------- GEMM core macros ----------------
#define TBM 128
#define TBN 128
#define TBK 32

// EPI: 0 -> fp32 C, 1 -> bf16 C, 2 -> atomicAdd(dotAcc, sum(C .* W)), 3 -> atomicAdd fp32 C
template<int EPI>
__global__ __launch_bounds__(256)
void gemm_bt(const u16* __restrict__ A, const u16* __restrict__ B,
             float* __restrict__ Cf, u16* __restrict__ Cb,
             const u16* __restrict__ W, float* __restrict__ dotAcc,
             int M, int N, int K, int ld, float alpha)
{
    __shared__ __align__(16) u16 As[TBM * TBK];
    __shared__ __align__(16) u16 Bs[TBN * TBK];

    const int tid  = threadIdx.x;
    const int lane = tid & 63;
    const int wave = tid >> 6;
    const int wm   = (wave >> 1) * 64;
    const int wn   = (wave & 1) * 64;
    const int l16  = lane & 15;
    const int q4   = lane >> 4;
    const size_t row0 = (size_t)blockIdx.y * TBM;
    const size_t col0 = (size_t)blockIdx.x * TBN;
    const int kOff = blockIdx.z * K;

    f4v acc[4][4];
#pragma unroll
    for (int mt = 0; mt < 4; ++mt)
#pragma unroll
        for (int nt = 0; nt < 4; ++nt)
#pragma unroll
            for (int r = 0; r < 4; ++r)
                acc[mt][nt][r] = 0.f;

    const int ar0 = wave * 32 + (lane >> 2);
    const int ar1 = ar0 + 16;
    const int akk = (lane & 3) * 8;
    const u16* gA0 = A + (row0 + ar0) * ld + kOff + akk;
    const u16* gA1 = A + (row0 + ar1) * ld + kOff + akk;
    const u16* gB0 = B + (col0 + ar0) * ld + kOff + akk;
    const u16* gB1 = B + (col0 + ar1) * ld + kOff + akk;
    u16* lA0 = As + wave * 1024;
    u16* lA1 = As + wave * 1024 + 512;
    u16* lB0 = Bs + wave * 1024;
    u16* lB1 = Bs + wave * 1024 + 512;

    for (int k0 = 0; k0 < K; k0 += TBK) {
        __syncthreads();
        a16(lA0, gA0 + k0);
        a16(lA1, gA1 + k0);
        a16(lB0, gB0 + k0);
        a16(lB1, gB1 + k0);
        __syncthreads();

        s8v af[4], bfr[4];
#pragma unroll
        for (int mt = 0; mt < 4; ++mt)
            af[mt] = *(const s8v*)(As + (wm + mt * 16 + l16) * TBK + q4 * 8);
#pragma unroll
        for (int nt = 0; nt < 4; ++nt)
            bfr[nt] = *(const s8v*)(Bs + (wn + nt * 16 + l16) * TBK + q4 * 8);
#pragma unroll
        for (int mt = 0; mt < 4; ++mt)
#pragma unroll
            for (int nt = 0; nt < 4; ++nt)
                acc[mt][nt] = __builtin_amdgcn_mfma_f32_16x16x32_bf16(af[mt], bfr[nt], acc[mt][nt], 0, 0, 0);
    }

    if (EPI == 2) {
        float local = 0.f;
#pragma unroll
        for (int mt = 0; mt < 4; ++mt)
#pragma unroll
            for (int nt = 0; nt < 4; ++nt)
#pragma unroll
                for (int r = 0; r < 4; ++r) {
                    size_t row = row0 + wm + mt * 16 + q4 * 4 + r;
                    size_t col = col0 + wn + nt * 16 + l16;
                    local += acc[mt][nt][r] * b2f(W[row * (size_t)N + col]);
                }
        __shared__ float red[256];
        float tot = block_sum(local, red);
        if (tid == 0) atomicAdd(dotAcc, tot);
    } else {
#pragma unroll
        for (int mt = 0; mt < 4; ++mt)
#pragma unroll
            for (int nt = 0; nt < 4; ++nt)
#pragma unroll
                for (int r = 0; r < 4; ++r) {
                    size_t row = row0 + wm + mt * 16 + q4 * 4 + r;
                    size_t col = col0 + wn + nt * 16 + l16;
                    float v = acc[mt][nt][r] * alpha;
                    if (EPI == 0)      Cf[row * (size_t)N + col] = v;
                    else if (EPI == 1) Cb[row * (size_t)N + col] = f2b(v);
                    else               atomicAdd(&Cf[row * (size_t)N + col], v);
                }
    }
}

// ---------------- batched split-K GEMM (K=4096, ld=4096, Kc=512, EPI3) --------
struct BG { const u16* A; const u16* B; float* C; int M, Nn, tN, tEnd; };
struct BGArgs { BG d[6]; int n; float alpha; };

__global__ __launch_bounds__(256)
void bgemm(BGArgs g)
{
    __shared__ __align__(16) u16 As[TBM * TBK];
    __shared__ __align__(16) u16 Bs[TBN * TBK];

    int bi = 0;
    while (bi < g.n - 1 && (int)blockIdx.x >= g.d[bi].tEnd) ++bi;
    const BG& d = g.d[bi];
    const int tStart = bi ? g.d[bi - 1].tEnd : 0;
    const int local = blockIdx.x - tStart;
    const int tm = local / d.tN;
    const int tn = local - tm * d.tN;

    const int tid  = threadIdx.x;
    const int lane = tid & 63;
    const int wave = tid >> 6;
    const int wm   = (wave >> 1) * 64;
    const int wn   = (wave & 1) * 64;
    const int l16  = lane & 15;
    const int q4   = lane >> 4;
    const size_t row0 = (size_t)tm * TBM;
    const size_t col0 = (size_t)tn * TBN;
    const int kOff = blockIdx.y * 512;
    const int ld = 4096;

    f4v acc[4][4];
#pragma unroll
    for (int mt = 0; mt < 4; ++mt)
#pragma unroll
        for (int nt = 0; nt < 4; ++nt)
#pragma unroll
            for (int r = 0; r < 4; ++r)
                acc[mt][nt][r] = 0.f;

    const int ar0 = wave * 32 + (lane >> 2);
    const int ar1 = ar0 + 16;
    const int akk = (lane & 3) * 8;
    const u16* gA0 = d.A + (row0 + ar0) * ld + kOff + akk;
    const u16* gA1 = d.A + (row0 + ar1) * ld + kOff + akk;
    const u16* gB0 = d.B + (col0 + ar0) * ld + kOff + akk;
    const u16* gB1 = d.B + (col0 + ar1) * ld + kOff + akk;
    u16* lA0 = As + wave * 1024;
    u16* lA1 = As + wave * 1024 + 512;
    u16* lB0 = Bs + wave * 1024;
    u16* lB1 = Bs + wave * 1024 + 512;

    for (int k0 = 0; k0 < 512; k0 += TBK) {
        __syncthreads();
        a16(lA0, gA0 + k0);
        a16(lA1, gA1 + k0);
        a16(lB0, gB0 + k0);
        a16(lB1, gB1 + k0);
        __syncthreads();

        s8v af[4], bfr[4];
#pragma unroll
        for (int mt = 0; mt < 4; ++mt)
            af[mt] = *(const s8v*)(As + (wm + mt * 16 + l16) * TBK + q4 * 8);
#pragma unroll
        for (int nt = 0; nt < 4; ++nt)
            bfr[nt] = *(const s8v*)(Bs + (wn + nt * 16 + l16) * TBK + q4 * 8);
#pragma unroll
        for (int mt = 0; mt < 4; ++mt)
#pragma unroll
            for (int nt = 0; nt < 4; ++nt)
                acc[mt][nt] = __builtin_amdgcn_mfma_f32_16x16x32_bf16(af[mt], bfr[nt], acc[mt][nt], 0, 0, 0);
    }

#pragma unroll
    for (int mt = 0; mt < 4; ++mt)
#pragma unroll
        for (int nt = 0; nt < 4; ++nt)
#pragma unroll
            for (int r = 0; r < 4; ++r) {
                size_t row = row0 + wm + mt * 16 + q4 * 4 + r;
                size_t col = col0 + wn + nt * 16 + l16;
                atomicAdd(&d.C[row * (size_t)d.Nn + col], acc[mt][nt][r] * g.alpha);
            }
}

// ---------------- batched rownorm (wave-per-row, 8 problems) ----------------
struct RN { const float* in; u16* out; int C; int rEnd; };
struct RNArgs { RN d[8]; int n; };

__global__ __launch_bounds__(256)
void rownorm_batch(RNArgs a) {
    int gw = (blockIdx.x * 256 + threadIdx.x) >> 6;
    int lane = threadIdx.x & 63;
    int i = 0;
    while (i < a.n - 1 && gw >= a.d[i].rEnd) ++i;
    if (gw >= a.d[i].rEnd) return;
    int row = gw - (i ? a.d[i - 1].rEnd : 0);
    int C = a.d[i].C;
    const float4* r4 = (const float4*)(a.d[i].in + (size_t)row * C);
    int nv = C >> 2;
    float ss = 0.f;
    for (int c = lane; c < nv; c += 64) {
        float4 v = r4[c];
        ss += v.x * v.x + v.y * v.y + v.z * v.z + v.w * v.w;
    }
    ss = wave_sum(ss);
    float inv = 1.f / fmaxf(sqrtf(ss), 1e-8f);
    s4v* o4 = (s4v*)(a.d[i].out + (size_t)row * C);
    for (int c = lane; c < nv; c += 64) {
        float4 v = r4[c];
        s4v o;
        o[0] = (short)f2b(v.x * inv); o[1] = (short)f2b(v.y * inv);
        o[2] = (short)f2b(v.z * inv); o[3] = (short)f2b(v.w * inv);
        o4[c] = o;
    }
}

__global__ __launch_bounds__(256)
void mahal_w(const u16* __restrict__ Xh, const float* __restrict__ XS,
             u16* __restrict__ out, int nrows, int C) {
    int row = (blockIdx.x * 256 + threadIdx.x) >> 6;
    int lane = threadIdx.x & 63;
    if (row >= nrows) return;
    const s4v* x4 = (const s4v*)(Xh + (size_t)row * C);
    const float4* s4 = (const float4*)(XS + (size_t)row * C);
    int nv = C >> 2;
    float s = 0.f;
    for (int c = lane; c < nv; c += 64) {
        s4v x = x4[c]; float4 v = s4[c];
        s += b2f((u16)x[0]) * v.x + b2f((u16)x[1]) * v.y
           + b2f((u16)x[2]) * v.z + b2f((u16)x[3]) * v.w;
    }
    s = wave_sum(s);
    float inv = 1.f / fmaxf(sqrtf(fmaxf(s, 0.f)), 1e-8f);
    s4v* o4 = (s4v*)(out + (size_t)row * C);
    for (int c = lane; c < nv; c += 64) {
        s4v x = x4[c], o;
#pragma unroll
        for (int k = 0; k < 4; ++k) o[k] = (short)f2b(b2f((u16)x[k]) * inv);
        o4[c] = o;
    }
}

// ---------------- batched 32x32 transpose ----------------
struct TP { const u16* in; u16* out; int R, C, tC, tEnd; };
struct TPArgs { TP d[4]; int n; };

__global__ __launch_bounds__(256)
void transpose_batch(TPArgs a) {
    __shared__ u16 tile[32][33];
    int t = blockIdx.x;
    int i = 0;
    while (i < a.n - 1 && t >= a.d[i].tEnd) ++i;
    int local = t - (i ? a.d[i - 1].tEnd : 0);
    const TP& d = a.d[i];
    int ty = local / d.tC, tx = local - ty * d.tC;
    int bx = tx * 32, by = ty * 32;
    int lx = threadIdx.x & 31;
    int lyy = threadIdx.x >> 5;
    for (int r = lyy; r < 32; r += 8)
        tile[r][lx] = d.in[(size_t)(by + r) * d.C + bx + lx];
    __syncthreads();
    for (int r = lyy; r < 32; r += 8)
        d.out[(size_t)(bx + r) * d.R + by + lx] = tile[lx][r];
}

__global__ __launch_bounds__(256)
void cast_f2b(const float* __restrict__ in, u16* __restrict__ out, int n) {
    for (int i = blockIdx.x * 256 + threadIdx.x; i < n; i += gridDim.x * 256)
        out[i] = f2b(in[i]);
}

// ---------------- sinkhorn row pass (no-max sum-exp; logits bounded) ----------
__device__ __forceinline__ float row_sumexp(const u16* __restrict__ rowp,
                                            const float* __restrict__ vin,
                                            int ny, float scale, int lane) {
    const s8v* r8 = (const s8v*)rowp;
    const float4* v4 = (const float4*)vin;
    int nv = ny >> 3;
    float s = 0.f;
    for (int c = lane; c < nv; c += 64) {
        s8v v8 = r8[c];
        float4 va = v4[c * 2], vb = v4[c * 2 + 1];
        s += __expf(b2f((u16)v8[0]) * scale + va.x);
        s += __expf(b2f((u16)v8[1]) * scale + va.y);
        s += __expf(b2f((u16)v8[2]) * scale + va.z);
        s += __expf(b2f((u16)v8[3]) * scale + va.w);
        s += __expf(b2f((u16)v8[4]) * scale + vb.x);
        s += __expf(b2f((u16)v8[5]) * scale + vb.y);
        s += __expf(b2f((u16)v8[6]) * scale + vb.z);
        s += __expf(b2f((u16)v8[7]) * scale + vb.w);
    }
    return wave_sum(s);
}

// three problems per pass: P1 (4096), P2 (4096), P3 (2048)
__global__ __launch_bounds__(256)
void row_lse_tri(const u16* __restrict__ C1, const float* __restrict__ v1, float* __restrict__ u1,
                 const u16* __restrict__ C2, const float* __restrict__ v2, float* __restrict__ u2,
                 const u16* __restrict__ C3, const float* __restrict__ v3, float* __restrict__ u3,
                 float scale, float lm12, float lm3) {
    int gw = (blockIdx.x * 256 + threadIdx.x) >> 6;
    int lane = threadIdx.x & 63;
    if (gw < 4096) {
        float s = row_sumexp(C1 + (size_t)gw * 4096, v1, 4096, scale, lane);
        if (lane == 0) u1[gw] = lm12 - __logf(s);
    } else if (gw < 8192) {
        int row = gw - 4096;
        float s = row_sumexp(C2 + (size_t)row * 4096, v2, 4096, scale, lane);
        if (lane == 0) u2[row] = lm12 - __logf(s);
    } else {
        int row = gw - 8192;
        if (row >= 2048) return;
        float s = row_sumexp(C3 + (size_t)row * 2048, v3, 2048, scale, lane);
        if (lane == 0) u3[row] = lm3 - __logf(s);
    }
}

// plan row body: writes plan row (optional), returns rowsum
__device__ __forceinline__ float plan_body(const u16* __restrict__ rowp, u16* __restrict__ prow,
                                           float ui, const float* __restrict__ vin,
                                           int ny, float scale, int lane) {
    const s8v* r8 = (const s8v*)rowp;
    s8v* p8 = (s8v*)prow;
    const float4* v4 = (const float4*)vin;
    int nv = ny >> 3;
    float s = 0.f;
    for (int c = lane; c < nv; c += 64) {
        s8v v8 = r8[c], pb;
        float4 va = v4[c * 2], vb = v4[c * 2 + 1];
        float vv[8] = {va.x, va.y, va.z, va.w, vb.x, vb.y, vb.z, vb.w};
#pragma unroll
        for (int k = 0; k < 8; ++k) {
            float p = __expf(b2f((u16)v8[k]) * scale + ui + vv[k]);
            s += p;
            pb[k] = (short)f2b(p);
        }
        if (p8) p8[c] = pb;
    }
    return wave_sum(s);
}

// 4 problems: plan(Cu), planT(CuT), pairs rowsums (cosp), pairs colsums (cospT)
__global__ __launch_bounds__(256)
void plan_quad(const u16* __restrict__ Cu, const u16* __restrict__ CuT,
               const u16* __restrict__ cosp, const u16* __restrict__ cospT,
               const float* __restrict__ uu, const float* __restrict__ vu,
               const float* __restrict__ up, const float* __restrict__ vp,
               u16* __restrict__ plan, u16* __restrict__ planT,
               float* __restrict__ au, float* __restrict__ bu,
               float* __restrict__ ap, float* __restrict__ bp, float scale) {
    int gw = (blockIdx.x * 256 + threadIdx.x) >> 6;
    int lane = threadIdx.x & 63;
    if (gw < 4096) {
        float s = plan_body(Cu + (size_t)gw * 4096, plan + (size_t)gw * 4096, uu[gw], vu, 4096, scale, lane);
        if (lane == 0) au[gw] = s;
    } else if (gw < 8192) {
        int r = gw - 4096;
        float s = plan_body(CuT + (size_t)r * 4096, planT + (size_t)r * 4096, vu[r], uu, 4096, scale, lane);
        if (lane == 0) bu[r] = s;
    } else if (gw < 10240) {
        int r = gw - 8192;
        float s = plan_body(cosp + (size_t)r * 2048, nullptr, up[r], vp, 2048, scale, lane);
        if (lane == 0) ap[r] = s;
    } else {
        int r = gw - 10240;
        if (r >= 2048) return;
        float s = plan_body(cospT + (size_t)r * 2048, nullptr, vp[r], up, 2048, scale, lane);
        if (lane == 0) bp[r] = s;
    }
}

// 4 marginal-deviation reductions in one dispatch
__global__ __launch_bounds__(256)
void marg4(const float* __restrict__ ap, const float* __restrict__ bp,
           const float* __restrict__ au, const float* __restrict__ bu,
           float* __restrict__ slot) {
    const float* sv; int n; float target;
    if (blockIdx.x == 0)      { sv = ap; n = 2048; target = 1.f / 2048.f; }
    else if (blockIdx.x == 1) { sv = bp; n = 2048; target = 1.f / 2048.f; }
    else if (blockIdx.x == 2) { sv = au; n = 4096; target = 1.f / 4096.f; }
    else                      { sv = bu; n = 4096; target = 1.f / 4096.f; }
    int t = threadIdx.x;
    float s = 0.f;
    for (int i = t; i < n; i += 256) { float d = sv[i] - target; s += d * d; }
    __shared__ float buf[256];
    float tot = block_sum(s, buf);
    if (t == 0) atomicAdd(slot, tot);
}

__global__ __launch_bounds__(256)
void ot_row_w(const u16* __restrict__ Ca, const u16* __restrict__ Cu,
              const float* __restrict__ ua, const float* __restrict__ va,
              const float* __restrict__ uu, const float* __restrict__ vu,
              int nrows, int ny, float scale, float* __restrict__ slot) {
    int row = (blockIdx.x * 256 + threadIdx.x) >> 6;
    int lane = threadIdx.x & 63;
    float local = 0.f;
    if (row < nrows) {
        const s8v* ra = (const s8v*)(Ca + (size_t)row * ny);
        const s8v* ru = (const s8v*)(Cu + (size_t)row * ny);
        const float4* va4 = (const float4*)va;
        const float4* vu4 = (const float4*)vu;
        float uai = ua[row], uui = uu[row];
        int nv = ny >> 3;
        for (int c = lane; c < nv; c += 64) {
            s8v a8 = ra[c], u8 = ru[c];
            float4 a0 = va4[c * 2], a1 = va4[c * 2 + 1];
            float4 u0 = vu4[c * 2], u1 = vu4[c * 2 + 1];
            float av[8] = {a0.x, a0.y, a0.z, a0.w, a1.x, a1.y, a1.z, a1.w};
            float uv[8] = {u0.x, u0.y, u0.z, u0.w, u1.x, u1.y, u1.z, u1.w};
#pragma unroll
            for (int k = 0; k < 8; ++k) {
                float lpa = b2f((u16)a8[k]) * scale + uai + av[k];
                float lpu = b2f((u16)u8[k]) * scale + uui + uv[k];
                local += __expf(lpa) * (lpa - lpu);
            }
        }
    }
    local = wave_sum(local);
    block_atomic4(local, slot);
}

__global__ __launch_bounds__(256)
void sail_row_w(const u16* __restrict__ cosb, int n, float temp, float* __restrict__ slot) {
    int row = (blockIdx.x * 256 + threadIdx.x) >> 6;
    int lane = threadIdx.x & 63;
    float local = 0.f;
    if (row < n) {
        const s8v* r8 = (const s8v*)(cosb + (size_t)row * n);
        int nv = n >> 3;
        for (int c = lane; c < nv; c += 64) {
            s8v v8 = r8[c];
#pragma unroll
            for (int k = 0; k < 8; ++k) {
                int j = c * 8 + k;
                float cv = b2f((u16)v8[k]);
                float wgt = cv * ((j == row) ? temp : -temp);
                local -= fminf(wgt, 0.f) - log1pf(__expf(-fabsf(wgt)));
            }
        }
    }
    local = wave_sum(local);
    block_atomic4(local, slot);
}

__global__ __launch_bounds__(256)
void diag2(const u16* __restrict__ cosb, const float* __restrict__ up,
           const float* __restrict__ vp, int n, float scale,
           float* __restrict__ slotExp, float* __restrict__ slotImp) {
    int t = threadIdx.x;
    float e = 0.f, im = 0.f;
    float logn = logf((float)n);
    for (int i = t; i < n; i += 256) {
        float c = b2f(cosb[(size_t)i * n + i]);
        e  += (1.f - c) * 0.5f;
        im += scale * c + up[i] + vp[i] + logn;
    }
    __shared__ float buf[256];
    float te = block_sum(e, buf);
    float ti = block_sum(im, buf);
    if (t == 0) { atomicAdd(slotExp, te); atomicAdd(slotImp, ti); }
}

// dual GW quad-form: blocks [0,1024) -> (Kx,au)->s1, [1024,2048) -> (Ky,bu)->s2
__global__ __launch_bounds__(256)
void gw_dual(const u16* __restrict__ Kx, const float* __restrict__ au,
             const u16* __restrict__ Ky, const float* __restrict__ bu,
             float* __restrict__ s1, float* __restrict__ s2) {
    bool first = blockIdx.x < 1024;
    const u16* Kb = first ? Kx : Ky;
    const float* wv = first ? au : bu;
    float* slot = first ? s1 : s2;
    int row = (((blockIdx.x & 1023) * 256) + threadIdx.x) >> 6;
    int lane = threadIdx.x & 63;
    float local = 0.f;
    if (row < 4096) {
        const s8v* r8 = (const s8v*)(Kb + (size_t)row * 4096);
        const float4* w4 = (const float4*)wv;
        for (int c = lane; c < 512; c += 64) {
            s8v v8 = r8[c];
            float4 w0 = w4[c * 2], w1 = w4[c * 2 + 1];
            float ww[8] = {w0.x, w0.y, w0.z, w0.w, w1.x, w1.y, w1.z, w1.w};
#pragma unroll
            for (int k = 0; k < 8; ++k) {
                float kv = b2f((u16)v8[k]);
                local += kv * kv * ww[k];
            }
        }
        local = wave_sum(local) * wv[row];
        if (lane != 0) local = 0.f;
    }
    block_atomic4(local, slot);
}

// sum over a,b of Mf[a,b] * Tb[b,a]
__global__ __launch_bounds__(256)
void dotT(const float* __restrict__ Mf, const u16* __restrict__ Tb, int R, int Cc,
          float* __restrict__ slot) {
    int t = threadIdx.x;
    int total = R * Cc;
    float local = 0.f;
    for (int idx = blockIdx.x * 256 + t; idx < total; idx += gridDim.x * 256) {
        int a = idx / Cc, b = idx - a * Cc;
        local += Mf[idx] * b2f(Tb[(size_t)b * R + a]);
    }
    __shared__ float buf[256];
    float tot = block_sum(local, buf);
    if (t == 0) atomicAdd(slot, tot);
}

__global__ __launch_bounds__(256)
void dot_bb(const u16* __restrict__ A, const u16* __restrict__ B, int n,
            float* __restrict__ slot) {
    int t = threadIdx.x;
    float local = 0.f;
    for (int i = blockIdx.x * 256 + t; i < n; i += gridDim.x * 256)
        local += b2f(A[i]) * b2f(B[i]);
    __shared__ float buf[256];
    float tot = block_sum(local, buf);
    if (t == 0) atomicAdd(slot, tot);
}

// slots: 0 marg, 1 sail, 2 exp, 3 imp, 4 ot, 5 norm1, 6 norm2, 7 dot, 8 gw1, 9 gw2, 10 sandwich
__global__ void combine(const float* __restrict__ s, float* __restrict__ out) {
    if (threadIdx.x == 0 && blockIdx.x == 0) {
        float Np = 2048.f;
        float Nu2 = 4096.f * 4096.f;
        float total = s[0]
                    + s[1] / (Np * Np)
                    + s[2] / Np
                    - s[3] / Np
                    + s[4]
                    + (s[5] + s[6] - 2.f * s[7]) / Nu2
                    + s[8] + s[9] - 2.f * s[10];
        out[0] = total;
    }
}

// ------------------------------------------------------------------
extern "C" void kernel_launch(void* const* d_in, const int* in_sizes, int n_in,
                              void* d_out, int out_size, void* d_ws, size_t ws_size,
                              hipStream_t stream) {
    const float* fXp_in = (const float*)d_in[0];   // 2048 x 256
    const float* fYp_in = (const float*)d_in[1];   // 2048 x 256
    const float* X_in   = (const float*)d_in[2];   // 4096 x 768
    const float* Y_in   = (const float*)d_in[3];   // 4096 x 512
    const float* fX_in  = (const float*)d_in[4];   // 4096 x 256
    const float* fY_in  = (const float*)d_in[5];   // 4096 x 256
    const float* Xa_in  = (const float*)d_in[6];   // 4096 x 768
    const float* Ya_in  = (const float*)d_in[7];   // 4096 x 512
    float* out = (float*)d_out;

    char* w = (char*)d_ws;
    size_t off = 0;
    auto alloc = [&](size_t bytes) -> char* {
        char* p = w + off;
        off += (bytes + 255) & ~(size_t)255;
        return p;
    };

    const size_t N = 4096, Np = 2048, DX = 768, DY = 512, DF = 256;

    // ---- five shared 32 MB N x N slots (lifetime-scheduled) ----
    const size_t SLOT = N * N * 2;
    char* S1 = alloc(SLOT);
    char* S2 = alloc(SLOT);
    char* S3 = alloc(SLOT);
    char* S4 = alloc(SLOT);
    char* S5 = alloc(SLOT);

    // S1: Xa -> Cu -> Kx
    u16* Xa   = (u16*)S1;
    u16* Cu   = (u16*)S1;
    u16* Kx   = (u16*)S1;
    // S2: Ya -> CuT -> P1
    u16* Ya   = (u16*)S2;
    u16* CuT  = (u16*)S2;
    u16* P1   = (u16*)S2;
    // S3: Ca -> Ky
    u16* Ca   = (u16*)S3;
    u16* Ky   = (u16*)S3;
    // S4: XaT+YaT -> XS -> XnT+YnT -> CaT -> planT
    u16* XaT  = (u16*)S4;
    u16* YaT  = (u16*)(S4 + N * DX * 2);
    float* XS = (float*)S4;
    u16* XnT  = (u16*)S4;
    u16* YnT  = (u16*)(S4 + N * DX * 2);
    u16* CaT  = (u16*)S4;
    u16* planT= (u16*)S4;
    // S5: YS -> Tb -> plan
    float* YS = (float*)S5;
    u16* Tb   = (u16*)S5;
    u16* plan = (u16*)S5;

    // ---- dedicated bf16 buffers ----
    u16* fXp  = (u16*)alloc(Np * DF * 2);
    u16* fYp  = (u16*)alloc(Np * DF * 2);
    u16* fXn  = (u16*)alloc(N * DF * 2);
    u16* fYn  = (u16*)alloc(N * DF * 2);
    u16* fXnT = (u16*)alloc(N * DF * 2);
    u16* fYnT = (u16*)alloc(N * DF * 2);
    u16* Xu   = (u16*)alloc(N * DX * 2);
    u16* Yu   = (u16*)alloc(N * DY * 2);
    u16* Xn   = (u16*)alloc(N * DX * 2);
    u16* Yn   = (u16*)alloc(N * DY * 2);
    // batch1 bf16 outputs (contiguous, order must match fp32 accumulators)
    u16* Sxx  = (u16*)alloc(DX * DX * 2);
    u16* Syy  = (u16*)alloc(DY * DY * 2);
    u16* SxyT = (u16*)alloc(DY * DX * 2);
    // batch2 bf16 outputs (contiguous)
    u16* Gx   = (u16*)alloc(DX * DX * 2);
    u16* Gy   = (u16*)alloc(DY * DY * 2);
    u16* Gfx  = (u16*)alloc(DF * DF * 2);
    u16* Gfy  = (u16*)alloc(DF * DF * 2);
    u16* A1b  = (u16*)alloc(DX * DF * 2);
    u16* B1Tb = (u16*)alloc(DY * DF * 2);
    u16* Hb   = (u16*)alloc(DX * DY * 2);
    u16* cosp = (u16*)alloc(Np * Np * 2);
    u16* cospT= (u16*)alloc(Np * Np * 2);
    float* ap = (float*)alloc(Np * 4);
    float* bp = (float*)alloc(Np * 4);
    float* au = (float*)alloc(N * 4);
    float* bu = (float*)alloc(N * 4);

    // ---- zero zone (ONE memset): slots + potentials + fp32 accumulators ----
    char* zero_begin = w + off;
    float* slots = (float*)alloc(64 * 4);
    float* up = (float*)alloc(Np * 4);
    float* vp = (float*)alloc(Np * 4);
    float* uu = (float*)alloc(N * 4);
    float* vu = (float*)alloc(N * 4);
    float* ua = (float*)alloc(N * 4);
    float* va = (float*)alloc(N * 4);
    float* SxxF  = (float*)alloc(DX * DX * 4);   // batch1 fp32 (contiguous)
    float* SyyF  = (float*)alloc(DY * DY * 4);
    float* SxyTF = (float*)alloc(DY * DX * 4);
    float* GxF   = (float*)alloc(DX * DX * 4);   // batch2 fp32 (contiguous)
    float* GyF   = (float*)alloc(DY * DY * 4);
    float* GfxF  = (float*)alloc(DF * DF * 4);
    float* GfyF  = (float*)alloc(DF * DF * 4);
    float* A1F   = (float*)alloc(DX * DF * 4);
    float* B1F   = (float*)alloc(DY * DF * 4);
    float* HbF   = (float*)alloc(DX * DY * 4);
    float* H2    = (float*)alloc(DX * DY * 4);
    float* D1    = (float*)alloc(DX * DY * 4);
    size_t zero_bytes = (size_t)((w + off) - zero_begin);

    const float SCALE = 20.f;   // 1/eps

#define GEMM_F32(A_, B_, C_, M_, N_, K_, al_) \
    gemm_bt<0><<<dim3((N_) / 128, (M_) / 128), 256, 0, stream>>>((A_), (B_), (C_), nullptr, nullptr, nullptr, (M_), (N_), (K_), (K_), (al_))
#define GEMM_B16(A_, B_, C_, M_, N_, K_, al_) \
    gemm_bt<1><<<dim3((N_) / 128, (M_) / 128), 256, 0, stream>>>((A_), (B_), nullptr, (C_), nullptr, nullptr, (M_), (N_), (K_), (K_), (al_))
#define GEMM_DOT(A_, B_, W_, S_, M_, N_, K_) \
    gemm_bt<2><<<dim3((N_) / 128, (M_) / 128), 256, 0, stream>>>((A_), (B_), nullptr, nullptr, (W_), (S_), (M_), (N_), (K_), (K_), 1.0f)
#define GEMM_SKF(A_, B_, CF_, M_, N_, Kfull_, SPL_, al_) \
    gemm_bt<3><<<dim3((N_) / 128, (M_) / 128, (SPL_)), 256, 0, stream>>>((A_), (B_), (CF_), nullptr, nullptr, nullptr, (M_), (N_), (Kfull_) / (SPL_), (Kfull_), (al_))

    hipMemsetAsync(zero_begin, 0, zero_bytes, stream);

    // ===== 1. all row-normalizations (8 problems, one dispatch) =====
    {
        RNArgs a;
        a.d[0] = {Xa_in, Xa, 768, 4096};
        a.d[1] = {Ya_in, Ya, 512, 8192};
        a.d[2] = {fXp_in, fXp, 256, 10240};
        a.d[3] = {fYp_in, fYp, 256, 12288};
        a.d[4] = {fX_in, fXn, 256, 16384};
        a.d[5] = {fY_in, fYn, 256, 20480};
        a.d[6] = {X_in, Xu, 768, 24576};
        a.d[7] = {Y_in, Yu, 512, 28672};
        a.n = 8;
        rownorm_batch<<<7168, 256, 0, stream>>>(a);
    }

    // ===== 2. transposes batch A: XaT, YaT, fXnT, fYnT =====
    {
        TPArgs a;
        a.d[0] = {Xa, XaT, 4096, 768, 24, 3072};
        a.d[1] = {Ya, YaT, 4096, 512, 16, 5120};
        a.d[2] = {fXn, fXnT, 4096, 256, 8, 6144};
        a.d[3] = {fYn, fYnT, 4096, 256, 8, 7168};
        a.n = 4;
        transpose_batch<<<7168, 256, 0, stream>>>(a);
    }

    // ===== 3. batch1: anchor covariances (split-K8) + cast =====
    {
        BGArgs g;
        g.d[0] = {XaT, XaT, SxxF, 768, 768, 6, 36};
        g.d[1] = {YaT, YaT, SyyF, 512, 512, 4, 52};
        g.d[2] = {YaT, XaT, SxyTF, 512, 768, 6, 76};
        g.n = 3; g.alpha = 1.f / 4096.f;
        bgemm<<<dim3(76, 8), 256, 0, stream>>>(g);
        cast_f2b<<<256, 256, 0, stream>>>(SxxF, Sxx, 768 * 768 + 512 * 512 + 512 * 768);
    }

    // ===== 4. Mahalanobis normalization =====
    GEMM_F32(Xu, Sxx, XS, 4096, 768, 768, 1.f);   // -> S4 (XaT/YaT dead)
    GEMM_F32(Yu, Syy, YS, 4096, 512, 512, 1.f);   // -> S5
    mahal_w<<<1024, 256, 0, stream>>>(Xu, XS, Xn, 4096, 768);
    mahal_w<<<1024, 256, 0, stream>>>(Yu, YS, Yn, 4096, 512);

    // ===== 5. transposes batch B: XnT, YnT (clobber XS in S4) =====
    {
        TPArgs a;
        a.d[0] = {Xn, XnT, 4096, 768, 24, 3072};
        a.d[1] = {Yn, YnT, 4096, 512, 16, 5120};
        a.n = 2;
        transpose_batch<<<5120, 256, 0, stream>>>(a);
    }

    // ===== 6. batch2: L_div gram matrices (split-K8) + cast =====
    {
        BGArgs g;
        g.d[0] = {XnT, XnT, GxF, 768, 768, 6, 36};
        g.d[1] = {YnT, YnT, GyF, 512, 512, 4, 52};
        g.d[2] = {fXnT, fXnT, GfxF, 256, 256, 2, 56};
        g.d[3] = {fYnT, fYnT, GfyF, 256, 256, 2, 60};
        g.d[4] = {XnT, fXnT, A1F, 768, 256, 2, 72};
        g.d[5] = {YnT, fYnT, B1F, 512, 256, 2, 80};
        g.n = 6; g.alpha = 1.f;
        bgemm<<<dim3(80, 8), 256, 0, stream>>>(g);
        cast_f2b<<<256, 256, 0, stream>>>(GxF, Gx,
            768 * 768 + 512 * 512 + 256 * 256 + 256 * 256 + 768 * 256 + 512 * 256);
    }

    // ===== 7. pairs cost matrices =====
    GEMM_B16(fXp, fYp, cosp, 2048, 2048, 256, 1.f);
    GEMM_B16(fYp, fXp, cospT, 2048, 2048, 256, 1.f);

    // ===== 8. L_div tail: Hb -> H2, D1 (split-K, fp32-atomic epilogues) =====
    GEMM_SKF(Gx, SxyT, HbF, 768, 512, 768, 4, 1.f);
    cast_f2b<<<256, 256, 0, stream>>>(HbF, Hb, 768 * 512);
    GEMM_SKF(Hb, Gy, H2, 768, 512, 512, 4, 1.f);
    GEMM_SKF(A1b, B1Tb, D1, 768, 512, 256, 2, 1.f);
    dotT<<<192, 256, 0, stream>>>(H2, SxyT, 768, 512, slots + 5);
    dot_bb<<<64, 256, 0, stream>>>(Gfx, Gfy, 256 * 256, slots + 6);
    dotT<<<192, 256, 0, stream>>>(D1, SxyT, 768, 512, slots + 7);

    // ===== 9. cost matrices for both big sinkhorns =====
    GEMM_B16(Xn, SxyT, Tb, 4096, 512, 768, 1.f);     // -> S5 (YS dead)
    GEMM_B16(Tb, Yn, Ca, 4096, 4096, 512, 1.f);      // -> S3
    GEMM_B16(Yn, Tb, CaT, 4096, 4096, 512, 1.f);     // -> S4 (XnT/YnT dead after batch2)
    GEMM_B16(fXn, fYn, Cu, 4096, 4096, 256, 1.f);    // -> S1
    GEMM_B16(fYn, fXn, CuT, 4096, 4096, 256, 1.f);   // -> S2

    // ===== 10. triple-fused sinkhorn (latent + anchor + pairs), 10 iters =====
    {
        float lm12 = -logf(4096.f), lm3 = -logf(2048.f);
        for (int it = 0; it < 10; ++it) {
            row_lse_tri<<<2560, 256, 0, stream>>>(Cu, vu, uu, Ca, va, ua, cosp, vp, up, SCALE, lm12, lm3);
            row_lse_tri<<<2560, 256, 0, stream>>>(CuT, uu, vu, CaT, ua, va, cospT, up, vp, SCALE, lm12, lm3);
        }
    }

    // ===== 11. plans + all marginal row/col sums (one dispatch) =====
    plan_quad<<<3072, 256, 0, stream>>>(Cu, CuT, cosp, cospT, uu, vu, up, vp,
                                        plan, planT, au, bu, ap, bp, SCALE);
    marg4<<<4, 256, 0, stream>>>(ap, bp, au, bu, slots + 0);
    diag2<<<1, 256, 0, stream>>>(cosp, up, vp, 2048, SCALE, slots + 2, slots + 3);
    sail_row_w<<<512, 256, 0, stream>>>(cosp, 2048, 10.f, slots + 1);

    // ===== 12. L_ot (reads Ca + Cu before they are clobbered) =====
    ot_row_w<<<1024, 256, 0, stream>>>(Ca, Cu, ua, va, uu, vu, 4096, 4096, SCALE, slots + 4);

    // ===== 13. Gromov-Wasserstein =====
    GEMM_B16(Xu, Xu, Kx, 4096, 4096, 768, 1.f);     // -> S1 (Cu dead)
    GEMM_B16(Yu, Yu, Ky, 4096, 4096, 512, 1.f);     // -> S3 (Ca dead)
    gw_dual<<<2048, 256, 0, stream>>>(Kx, au, Ky, bu, slots + 8, slots + 9);
    GEMM_B16(Kx, planT, P1, 4096, 4096, 4096, 1.f); // -> S2 (CuT dead)
    GEMM_DOT(P1, Ky, plan, slots + 10, 4096, 4096, 4096);

    combine<<<1, 1, 0, stream>>>(slots, out);

#undef GEMM_F32
#undef GEMM_B16
#undef GEMM_DOT
#undef GEMM_SKF
}

// Round 6
// 986.139 us; speedup vs baseline: 3.4783x; 1.3175x over previous
//
#include <hip/hip_runtime.h>
#include <hip/hip_bf16.h>
#include <math.h>

using u16 = unsigned short;
using s8v = __attribute__((ext_vector_type(8))) short;   // 8 bf16 (4 VGPRs) - MFMA A/B frag
using s4v = __attribute__((ext_vector_type(4))) short;   // 4 bf16
using f4v = __attribute__((ext_vector_type(4))) float;   // MFMA C/D frag

__device__ __forceinline__ float b2f(u16 x) {
    unsigned int u = ((unsigned int)x) << 16;
    return __uint_as_float(u);
}
__device__ __forceinline__ u16 f2b(float f) {
    unsigned int x = __float_as_uint(f);
    unsigned int r = x + 0x7fffu + ((x >> 16) & 1u);   // RNE
    return (u16)(r >> 16);
}

// async global->LDS, 16B per lane; lds base wave-uniform (lane scatter = lane*16)
__device__ __forceinline__ void a16(u16* lds, const u16* g) {
    __builtin_amdgcn_global_load_lds((__attribute__((address_space(1))) void*)g,
                                     (__attribute__((address_space(3))) void*)lds,
                                     16, 0, 0);
}

// ---------------- reductions ----------------
__device__ __forceinline__ float block_sum(float v, float* buf) {
    int t = threadIdx.x;
    buf[t] = v; __syncthreads();
    for (int s = 128; s > 0; s >>= 1) {
        if (t < s) buf[t] += buf[t + s];
        __syncthreads();
    }
    float r = buf[0];
    __syncthreads();
    return r;
}

__device__ __forceinline__ float wave_sum(float v) {
#pragma unroll
    for (int off = 32; off; off >>= 1) v += __shfl_xor(v, off, 64);
    return v;
}

__device__ __forceinline__ void block_atomic4(float wval, float* slot) {
    __shared__ float wb[4];
    int lane = threadIdx.x & 63, wv = threadIdx.x >> 6;
    if (lane == 0) wb[wv] = wval;
    __syncthreads();
    if (threadIdx.x == 0) atomicAdd(slot, wb[0] + wb[1] + wb[2] + wb[3]);
}

// ---------------- GEMM core ----------------
#define TBM 128
#define TBN 128
#define TBK 32

// EPI: 0 -> fp32 C, 1 -> bf16 C, 3 -> atomicAdd fp32 C
template<int EPI>
__global__ __launch_bounds__(256)
void gemm_bt(const u16* __restrict__ A, const u16* __restrict__ B,
             float* __restrict__ Cf, u16* __restrict__ Cb,
             int M, int N, int K, int ld, float alpha)
{
    __shared__ __align__(16) u16 As[TBM * TBK];
    __shared__ __align__(16) u16 Bs[TBN * TBK];

    const int tid  = threadIdx.x;
    const int lane = tid & 63;
    const int wave = tid >> 6;
    const int wm   = (wave >> 1) * 64;
    const int wn   = (wave & 1) * 64;
    const int l16  = lane & 15;
    const int q4   = lane >> 4;
    const size_t row0 = (size_t)blockIdx.y * TBM;
    const size_t col0 = (size_t)blockIdx.x * TBN;
    const int kOff = blockIdx.z * K;

    f4v acc[4][4];
#pragma unroll
    for (int mt = 0; mt < 4; ++mt)
#pragma unroll
        for (int nt = 0; nt < 4; ++nt)
#pragma unroll
            for (int r = 0; r < 4; ++r)
                acc[mt][nt][r] = 0.f;

    const int ar0 = wave * 32 + (lane >> 2);
    const int ar1 = ar0 + 16;
    const int akk = (lane & 3) * 8;
    const u16* gA0 = A + (row0 + ar0) * ld + kOff + akk;
    const u16* gA1 = A + (row0 + ar1) * ld + kOff + akk;
    const u16* gB0 = B + (col0 + ar0) * ld + kOff + akk;
    const u16* gB1 = B + (col0 + ar1) * ld + kOff + akk;
    u16* lA0 = As + wave * 1024;
    u16* lA1 = As + wave * 1024 + 512;
    u16* lB0 = Bs + wave * 1024;
    u16* lB1 = Bs + wave * 1024 + 512;

    for (int k0 = 0; k0 < K; k0 += TBK) {
        __syncthreads();
        a16(lA0, gA0 + k0);
        a16(lA1, gA1 + k0);
        a16(lB0, gB0 + k0);
        a16(lB1, gB1 + k0);
        __syncthreads();

        s8v af[4], bfr[4];
#pragma unroll
        for (int mt = 0; mt < 4; ++mt)
            af[mt] = *(const s8v*)(As + (wm + mt * 16 + l16) * TBK + q4 * 8);
#pragma unroll
        for (int nt = 0; nt < 4; ++nt)
            bfr[nt] = *(const s8v*)(Bs + (wn + nt * 16 + l16) * TBK + q4 * 8);
#pragma unroll
        for (int mt = 0; mt < 4; ++mt)
#pragma unroll
            for (int nt = 0; nt < 4; ++nt)
                acc[mt][nt] = __builtin_amdgcn_mfma_f32_16x16x32_bf16(af[mt], bfr[nt], acc[mt][nt], 0, 0, 0);
    }

#pragma unroll
    for (int mt = 0; mt < 4; ++mt)
#pragma unroll
        for (int nt = 0; nt < 4; ++nt)
#pragma unroll
            for (int r = 0; r < 4; ++r) {
                size_t row = row0 + wm + mt * 16 + q4 * 4 + r;
                size_t col = col0 + wn + nt * 16 + l16;
                float v = acc[mt][nt][r] * alpha;
                if (EPI == 0)      Cf[row * (size_t)N + col] = v;
                else if (EPI == 1) Cb[row * (size_t)N + col] = f2b(v);
                else               atomicAdd(&Cf[row * (size_t)N + col], v);
            }
}

// ---------------- batched split-K GEMM (ld=4096, Kc=512, fp32-atomic epi) -----
struct BG { const u16* A; const u16* B; float* C; int M, Nn, tN, tEnd; };
struct BGArgs { BG d[6]; int n; float alpha; };

__global__ __launch_bounds__(256)
void bgemm(BGArgs g)
{
    __shared__ __align__(16) u16 As[TBM * TBK];
    __shared__ __align__(16) u16 Bs[TBN * TBK];

    int bi = 0;
    while (bi < g.n - 1 && (int)blockIdx.x >= g.d[bi].tEnd) ++bi;
    const BG& d = g.d[bi];
    const int tStart = bi ? g.d[bi - 1].tEnd : 0;
    const int local = blockIdx.x - tStart;
    const int tm = local / d.tN;
    const int tn = local - tm * d.tN;

    const int tid  = threadIdx.x;
    const int lane = tid & 63;
    const int wave = tid >> 6;
    const int wm   = (wave >> 1) * 64;
    const int wn   = (wave & 1) * 64;
    const int l16  = lane & 15;
    const int q4   = lane >> 4;
    const size_t row0 = (size_t)tm * TBM;
    const size_t col0 = (size_t)tn * TBN;
    const int kOff = blockIdx.y * 512;
    const int ld = 4096;

    f4v acc[4][4];
#pragma unroll
    for (int mt = 0; mt < 4; ++mt)
#pragma unroll
        for (int nt = 0; nt < 4; ++nt)
#pragma unroll
            for (int r = 0; r < 4; ++r)
                acc[mt][nt][r] = 0.f;

    const int ar0 = wave * 32 + (lane >> 2);
    const int ar1 = ar0 + 16;
    const int akk = (lane & 3) * 8;
    const u16* gA0 = d.A + (row0 + ar0) * ld + kOff + akk;
    const u16* gA1 = d.A + (row0 + ar1) * ld + kOff + akk;
    const u16* gB0 = d.B + (col0 + ar0) * ld + kOff + akk;
    const u16* gB1 = d.B + (col0 + ar1) * ld + kOff + akk;
    u16* lA0 = As + wave * 1024;
    u16* lA1 = As + wave * 1024 + 512;
    u16* lB0 = Bs + wave * 1024;
    u16* lB1 = Bs + wave * 1024 + 512;

    for (int k0 = 0; k0 < 512; k0 += TBK) {
        __syncthreads();
        a16(lA0, gA0 + k0);
        a16(lA1, gA1 + k0);
        a16(lB0, gB0 + k0);
        a16(lB1, gB1 + k0);
        __syncthreads();

        s8v af[4], bfr[4];
#pragma unroll
        for (int mt = 0; mt < 4; ++mt)
            af[mt] = *(const s8v*)(As + (wm + mt * 16 + l16) * TBK + q4 * 8);
#pragma unroll
        for (int nt = 0; nt < 4; ++nt)
            bfr[nt] = *(const s8v*)(Bs + (wn + nt * 16 + l16) * TBK + q4 * 8);
#pragma unroll
        for (int mt = 0; mt < 4; ++mt)
#pragma unroll
            for (int nt = 0; nt < 4; ++nt)
                acc[mt][nt] = __builtin_amdgcn_mfma_f32_16x16x32_bf16(af[mt], bfr[nt], acc[mt][nt], 0, 0, 0);
    }

#pragma unroll
    for (int mt = 0; mt < 4; ++mt)
#pragma unroll
        for (int nt = 0; nt < 4; ++nt)
#pragma unroll
            for (int r = 0; r < 4; ++r) {
                size_t row = row0 + wm + mt * 16 + q4 * 4 + r;
                size_t col = col0 + wn + nt * 16 + l16;
                atomicAdd(&d.C[row * (size_t)d.Nn + col], acc[mt][nt][r] * g.alpha);
            }
}

// ---------------- batched rownorm ----------------
struct RN { const float* in; u16* out; int C; int rEnd; };
struct RNArgs { RN d[8]; int n; };

__global__ __launch_bounds__(256)
void rownorm_batch(RNArgs a) {
    int gw = (blockIdx.x * 256 + threadIdx.x) >> 6;
    int lane = threadIdx.x & 63;
    int i = 0;
    while (i < a.n - 1 && gw >= a.d[i].rEnd) ++i;
    if (gw >= a.d[i].rEnd) return;
    int row = gw - (i ? a.d[i - 1].rEnd : 0);
    int C = a.d[i].C;
    const float4* r4 = (const float4*)(a.d[i].in + (size_t)row * C);
    int nv = C >> 2;
    float ss = 0.f;
    for (int c = lane; c < nv; c += 64) {
        float4 v = r4[c];
        ss += v.x * v.x + v.y * v.y + v.z * v.z + v.w * v.w;
    }
    ss = wave_sum(ss);
    float inv = 1.f / fmaxf(sqrtf(ss), 1e-8f);
    s4v* o4 = (s4v*)(a.d[i].out + (size_t)row * C);
    for (int c = lane; c < nv; c += 64) {
        float4 v = r4[c];
        s4v o;
        o[0] = (short)f2b(v.x * inv); o[1] = (short)f2b(v.y * inv);
        o[2] = (short)f2b(v.z * inv); o[3] = (short)f2b(v.w * inv);
        o4[c] = o;
    }
}

__global__ __launch_bounds__(256)
void mahal_w(const u16* __restrict__ Xh, const float* __restrict__ XS,
             u16* __restrict__ out, int nrows, int C) {
    int row = (blockIdx.x * 256 + threadIdx.x) >> 6;
    int lane = threadIdx.x & 63;
    if (row >= nrows) return;
    const s4v* x4 = (const s4v*)(Xh + (size_t)row * C);
    const float4* s4 = (const float4*)(XS + (size_t)row * C);
    int nv = C >> 2;
    float s = 0.f;
    for (int c = lane; c < nv; c += 64) {
        s4v x = x4[c]; float4 v = s4[c];
        s += b2f((u16)x[0]) * v.x + b2f((u16)x[1]) * v.y
           + b2f((u16)x[2]) * v.z + b2f((u16)x[3]) * v.w;
    }
    s = wave_sum(s);
    float inv = 1.f / fmaxf(sqrtf(fmaxf(s, 0.f)), 1e-8f);
    s4v* o4 = (s4v*)(out + (size_t)row * C);
    for (int c = lane; c < nv; c += 64) {
        s4v x = x4[c], o;
#pragma unroll
        for (int k = 0; k < 4; ++k) o[k] = (short)f2b(b2f((u16)x[k]) * inv);
        o4[c] = o;
    }
}

// ---------------- batched 32x32 transpose (optional per-input-row scale) ------
struct TP { const u16* in; u16* out; int R, C, tC, tEnd; const float* s; };
struct TPArgs { TP d[6]; int n; };

__global__ __launch_bounds__(256)
void transpose_batch(TPArgs a) {
    __shared__ u16 tile[32][33];
    int t = blockIdx.x;
    int i = 0;
    while (i < a.n - 1 && t >= a.d[i].tEnd) ++i;
    int local = t - (i ? a.d[i - 1].tEnd : 0);
    const TP& d = a.d[i];
    int ty = local / d.tC, tx = local - ty * d.tC;
    int bx = tx * 32, by = ty * 32;
    int lx = threadIdx.x & 31;
    int lyy = threadIdx.x >> 5;
    for (int r = lyy; r < 32; r += 8)
        tile[r][lx] = d.in[(size_t)(by + r) * d.C + bx + lx];
    __syncthreads();
    for (int r = lyy; r < 32; r += 8) {
        u16 val = tile[lx][r];
        if (d.s) val = f2b(b2f(val) * d.s[by + lx]);
        d.out[(size_t)(bx + r) * d.R + by + lx] = val;
    }
}

__global__ __launch_bounds__(256)
void cast_f2b(const float* __restrict__ in, u16* __restrict__ out, int n) {
    for (int i = blockIdx.x * 256 + threadIdx.x; i < n; i += gridDim.x * 256)
        out[i] = f2b(in[i]);
}

// ---------------- sinkhorn row pass (no-max sum-exp; logits bounded) ----------
__device__ __forceinline__ float row_sumexp(const u16* __restrict__ rowp,
                                            const float* __restrict__ vin,
                                            int ny, float scale, int lane) {
    const s8v* r8 = (const s8v*)rowp;
    const float4* v4 = (const float4*)vin;
    int nv = ny >> 3;
    float s = 0.f;
    for (int c = lane; c < nv; c += 64) {
        s8v v8 = r8[c];
        float4 va = v4[c * 2], vb = v4[c * 2 + 1];
        s += __expf(b2f((u16)v8[0]) * scale + va.x);
        s += __expf(b2f((u16)v8[1]) * scale + va.y);
        s += __expf(b2f((u16)v8[2]) * scale + va.z);
        s += __expf(b2f((u16)v8[3]) * scale + va.w);
        s += __expf(b2f((u16)v8[4]) * scale + vb.x);
        s += __expf(b2f((u16)v8[5]) * scale + vb.y);
        s += __expf(b2f((u16)v8[6]) * scale + vb.z);
        s += __expf(b2f((u16)v8[7]) * scale + vb.w);
    }
    return wave_sum(s);
}

// three problems per pass: P1 (4096), P2 (4096), P3 (2048)
__global__ __launch_bounds__(256)
void row_lse_tri(const u16* __restrict__ C1, const float* __restrict__ v1, float* __restrict__ u1,
                 const u16* __restrict__ C2, const float* __restrict__ v2, float* __restrict__ u2,
                 const u16* __restrict__ C3, const float* __restrict__ v3, float* __restrict__ u3,
                 float scale, float lm12, float lm3) {
    int gw = (blockIdx.x * 256 + threadIdx.x) >> 6;
    int lane = threadIdx.x & 63;
    if (gw < 4096) {
        float s = row_sumexp(C1 + (size_t)gw * 4096, v1, 4096, scale, lane);
        if (lane == 0) u1[gw] = lm12 - __logf(s);
    } else if (gw < 8192) {
        int row = gw - 4096;
        float s = row_sumexp(C2 + (size_t)row * 4096, v2, 4096, scale, lane);
        if (lane == 0) u2[row] = lm12 - __logf(s);
    } else {
        int row = gw - 8192;
        if (row >= 2048) return;
        float s = row_sumexp(C3 + (size_t)row * 2048, v3, 2048, scale, lane);
        if (lane == 0) u3[row] = lm3 - __logf(s);
    }
}

// plan row body: writes plan row (optional), returns rowsum
__device__ __forceinline__ float plan_body(const u16* __restrict__ rowp, u16* __restrict__ prow,
                                           float ui, const float* __restrict__ vin,
                                           int ny, float scale, int lane) {
    const s8v* r8 = (const s8v*)rowp;
    s8v* p8 = (s8v*)prow;
    const float4* v4 = (const float4*)vin;
    int nv = ny >> 3;
    float s = 0.f;
    for (int c = lane; c < nv; c += 64) {
        s8v v8 = r8[c], pb;
        float4 va = v4[c * 2], vb = v4[c * 2 + 1];
        float vv[8] = {va.x, va.y, va.z, va.w, vb.x, vb.y, vb.z, vb.w};
#pragma unroll
        for (int k = 0; k < 8; ++k) {
            float p = __expf(b2f((u16)v8[k]) * scale + ui + vv[k]);
            s += p;
            pb[k] = (short)f2b(p);
        }
        if (p8) p8[c] = pb;
    }
    return wave_sum(s);
}

// 4 problems: plan(Cu), colsums(CuT), pairs rowsums (cosp), pairs colsums (cospT)
__global__ __launch_bounds__(256)
void plan_quad(const u16* __restrict__ Cu, const u16* __restrict__ CuT,
               const u16* __restrict__ cosp, const u16* __restrict__ cospT,
               const float* __restrict__ uu, const float* __restrict__ vu,
               const float* __restrict__ up, const float* __restrict__ vp,
               u16* __restrict__ plan,
               float* __restrict__ au, float* __restrict__ bu,
               float* __restrict__ ap, float* __restrict__ bp, float scale) {
    int gw = (blockIdx.x * 256 + threadIdx.x) >> 6;
    int lane = threadIdx.x & 63;
    if (gw < 4096) {
        float s = plan_body(Cu + (size_t)gw * 4096, plan + (size_t)gw * 4096, uu[gw], vu, 4096, scale, lane);
        if (lane == 0) au[gw] = s;
    } else if (gw < 8192) {
        int r = gw - 4096;
        float s = plan_body(CuT + (size_t)r * 4096, nullptr, vu[r], uu, 4096, scale, lane);
        if (lane == 0) bu[r] = s;
    } else if (gw < 10240) {
        int r = gw - 8192;
        float s = plan_body(cosp + (size_t)r * 2048, nullptr, up[r], vp, 2048, scale, lane);
        if (lane == 0) ap[r] = s;
    } else {
        int r = gw - 10240;
        if (r >= 2048) return;
        float s = plan_body(cospT + (size_t)r * 2048, nullptr, vp[r], up, 2048, scale, lane);
        if (lane == 0) bp[r] = s;
    }
}

// 4 marginal-deviation reductions in one dispatch
__global__ __launch_bounds__(256)
void marg4(const float* __restrict__ ap, const float* __restrict__ bp,
           const float* __restrict__ au, const float* __restrict__ bu,
           float* __restrict__ slot) {
    const float* sv; int n; float target;
    if (blockIdx.x == 0)      { sv = ap; n = 2048; target = 1.f / 2048.f; }
    else if (blockIdx.x == 1) { sv = bp; n = 2048; target = 1.f / 2048.f; }
    else if (blockIdx.x == 2) { sv = au; n = 4096; target = 1.f / 4096.f; }
    else                      { sv = bu; n = 4096; target = 1.f / 4096.f; }
    int t = threadIdx.x;
    float s = 0.f;
    for (int i = t; i < n; i += 256) { float d = sv[i] - target; s += d * d; }
    __shared__ float buf[256];
    float tot = block_sum(s, buf);
    if (t == 0) atomicAdd(slot, tot);
}

__global__ __launch_bounds__(256)
void ot_row_w(const u16* __restrict__ Ca, const u16* __restrict__ Cu,
              const float* __restrict__ ua, const float* __restrict__ va,
              const float* __restrict__ uu, const float* __restrict__ vu,
              int nrows, int ny, float scale, float* __restrict__ slot) {
    int row = (blockIdx.x * 256 + threadIdx.x) >> 6;
    int lane = threadIdx.x & 63;
    float local = 0.f;
    if (row < nrows) {
        const s8v* ra = (const s8v*)(Ca + (size_t)row * ny);
        const s8v* ru = (const s8v*)(Cu + (size_t)row * ny);
        const float4* va4 = (const float4*)va;
        const float4* vu4 = (const float4*)vu;
        float uai = ua[row], uui = uu[row];
        int nv = ny >> 3;
        for (int c = lane; c < nv; c += 64) {
            s8v a8 = ra[c], u8 = ru[c];
            float4 a0 = va4[c * 2], a1 = va4[c * 2 + 1];
            float4 u0 = vu4[c * 2], u1 = vu4[c * 2 + 1];
            float av[8] = {a0.x, a0.y, a0.z, a0.w, a1.x, a1.y, a1.z, a1.w};
            float uv[8] = {u0.x, u0.y, u0.z, u0.w, u1.x, u1.y, u1.z, u1.w};
#pragma unroll
            for (int k = 0; k < 8; ++k) {
                float lpa = b2f((u16)a8[k]) * scale + uai + av[k];
                float lpu = b2f((u16)u8[k]) * scale + uui + uv[k];
                local += __expf(lpa) * (lpa - lpu);
            }
        }
    }
    local = wave_sum(local);
    block_atomic4(local, slot);
}

__global__ __launch_bounds__(256)
void sail_row_w(const u16* __restrict__ cosb, int n, float temp, float* __restrict__ slot) {
    int row = (blockIdx.x * 256 + threadIdx.x) >> 6;
    int lane = threadIdx.x & 63;
    float local = 0.f;
    if (row < n) {
        const s8v* r8 = (const s8v*)(cosb + (size_t)row * n);
        int nv = n >> 3;
        for (int c = lane; c < nv; c += 64) {
            s8v v8 = r8[c];
#pragma unroll
            for (int k = 0; k < 8; ++k) {
                int j = c * 8 + k;
                float cv = b2f((u16)v8[k]);
                float wgt = cv * ((j == row) ? temp : -temp);
                local -= fminf(wgt, 0.f) - log1pf(__expf(-fabsf(wgt)));
            }
        }
    }
    local = wave_sum(local);
    block_atomic4(local, slot);
}

__global__ __launch_bounds__(256)
void diag2(const u16* __restrict__ cosb, const float* __restrict__ up,
           const float* __restrict__ vp, int n, float scale,
           float* __restrict__ slotExp, float* __restrict__ slotImp) {
    int t = threadIdx.x;
    float e = 0.f, im = 0.f;
    float logn = logf((float)n);
    for (int i = t; i < n; i += 256) {
        float c = b2f(cosb[(size_t)i * n + i]);
        e  += (1.f - c) * 0.5f;
        im += scale * c + up[i] + vp[i] + logn;
    }
    __shared__ float buf[256];
    float te = block_sum(e, buf);
    float ti = block_sum(im, buf);
    if (t == 0) { atomicAdd(slotExp, te); atomicAdd(slotImp, ti); }
}

// sum over a,b of Mf[a,b] * Tb[b,a]
__global__ __launch_bounds__(256)
void dotT(const float* __restrict__ Mf, const u16* __restrict__ Tb, int R, int Cc,
          float* __restrict__ slot) {
    int t = threadIdx.x;
    int total = R * Cc;
    float local = 0.f;
    for (int idx = blockIdx.x * 256 + t; idx < total; idx += gridDim.x * 256) {
        int a = idx / Cc, b = idx - a * Cc;
        local += Mf[idx] * b2f(Tb[(size_t)b * R + a]);
    }
    __shared__ float buf[256];
    float tot = block_sum(local, buf);
    if (t == 0) atomicAdd(slot, tot);
}

__global__ __launch_bounds__(256)
void dot_bb(const u16* __restrict__ A, const u16* __restrict__ B, int n,
            float* __restrict__ slot) {
    int t = threadIdx.x;
    float local = 0.f;
    for (int i = blockIdx.x * 256 + t; i < n; i += gridDim.x * 256)
        local += b2f(A[i]) * b2f(B[i]);
    __shared__ float buf[256];
    float tot = block_sum(local, buf);
    if (t == 0) atomicAdd(slot, tot);
}

// three fp32 self-dots: ||A||^2 -> sA, ||B||^2 -> sB, ||C||^2 -> sC (grid = 64)
__global__ __launch_bounds__(256)
void dot3(const float* __restrict__ A, const float* __restrict__ B, const float* __restrict__ C,
          int na, int nb, int nc, float* __restrict__ sA, float* __restrict__ sB, float* __restrict__ sC) {
    const float* p; int n, b0, nblk; float* slot;
    if (blockIdx.x < 32)      { p = A; n = na; b0 = 0;  nblk = 32; slot = sA; }
    else if (blockIdx.x < 48) { p = B; n = nb; b0 = 32; nblk = 16; slot = sB; }
    else                      { p = C; n = nc; b0 = 48; nblk = 16; slot = sC; }
    int t = threadIdx.x;
    float local = 0.f;
    for (int i = (blockIdx.x - b0) * 256 + t; i < n; i += nblk * 256) {
        float v = p[i]; local += v * v;
    }
    __shared__ float buf[256];
    float tot = block_sum(local, buf);
    if (t == 0) atomicAdd(slot, tot);
}

// slots: 0 marg, 1 sail, 2 exp, 3 imp, 4 ot, 5 norm1, 6 norm2, 7 dot, 8 gw1, 9 gw2, 10 sandwich
__global__ void combine(const float* __restrict__ s, float* __restrict__ out) {
    if (threadIdx.x == 0 && blockIdx.x == 0) {
        float Np = 2048.f;
        float Nu2 = 4096.f * 4096.f;
        float total = s[0]
                    + s[1] / (Np * Np)
                    + s[2] / Np
                    - s[3] / Np
                    + s[4]
                    + (s[5] + s[6] - 2.f * s[7]) / Nu2
                    + s[8] + s[9] - 2.f * s[10];
        out[0] = total;
    }
}

// ------------------------------------------------------------------
extern "C" void kernel_launch(void* const* d_in, const int* in_sizes, int n_in,
                              void* d_out, int out_size, void* d_ws, size_t ws_size,
                              hipStream_t stream) {
    const float* fXp_in = (const float*)d_in[0];   // 2048 x 256
    const float* fYp_in = (const float*)d_in[1];   // 2048 x 256
    const float* X_in   = (const float*)d_in[2];   // 4096 x 768
    const float* Y_in   = (const float*)d_in[3];   // 4096 x 512
    const float* fX_in  = (const float*)d_in[4];   // 4096 x 256
    const float* fY_in  = (const float*)d_in[5];   // 4096 x 256
    const float* Xa_in  = (const float*)d_in[6];   // 4096 x 768
    const float* Ya_in  = (const float*)d_in[7];   // 4096 x 512
    float* out = (float*)d_out;

    char* w = (char*)d_ws;
    size_t off = 0;
    auto alloc = [&](size_t bytes) -> char* {
        char* p = w + off;
        off += (bytes + 255) & ~(size_t)255;
        return p;
    };

    const size_t N = 4096, Np = 2048, DX = 768, DY = 512, DF = 256;

    // ---- five shared 32 MB N x N slots (lifetime-scheduled) ----
    const size_t SLOT = N * N * 2;
    char* S1 = alloc(SLOT);
    char* S2 = alloc(SLOT);
    char* S3 = alloc(SLOT);
    char* S4 = alloc(SLOT);
    char* S5 = alloc(SLOT);

    // S1: Xa -> Cu -> T1T
    u16* Xa   = (u16*)S1;
    u16* Cu   = (u16*)S1;
    u16* T1T  = (u16*)S1;          // 512 x 4096 bf16, after Cu dead
    // S2: Ya -> CuT -> XuT+YuT
    u16* Ya   = (u16*)S2;
    u16* CuT  = (u16*)S2;
    u16* XuT  = (u16*)S2;          // 768 x 4096
    u16* YuT  = (u16*)(S2 + N * DX * 2);   // 512 x 4096
    // S3: Ca -> XsT+YsT
    u16* Ca   = (u16*)S3;
    u16* XsT  = (u16*)S3;          // 768 x 4096 (au-scaled)
    u16* YsT  = (u16*)(S3 + N * DX * 2);   // 512 x 4096 (bu-scaled)
    // S4: XaT+YaT -> XS -> XnT+YnT -> CaT
    u16* XaT  = (u16*)S4;
    u16* YaT  = (u16*)(S4 + N * DX * 2);
    float* XS = (float*)S4;
    u16* XnT  = (u16*)S4;
    u16* YnT  = (u16*)(S4 + N * DX * 2);
    u16* CaT  = (u16*)S4;
    // S5: YS -> Tb -> plan
    float* YS = (float*)S5;
    u16* Tb   = (u16*)S5;
    u16* plan = (u16*)S5;

    // ---- dedicated bf16 buffers ----
    u16* fXp  = (u16*)alloc(Np * DF * 2);
    u16* fYp  = (u16*)alloc(Np * DF * 2);
    u16* fXn  = (u16*)alloc(N * DF * 2);
    u16* fYn  = (u16*)alloc(N * DF * 2);
    u16* fXnT = (u16*)alloc(N * DF * 2);
    u16* fYnT = (u16*)alloc(N * DF * 2);
    u16* Xu   = (u16*)alloc(N * DX * 2);
    u16* Yu   = (u16*)alloc(N * DY * 2);
    u16* Xn   = (u16*)alloc(N * DX * 2);
    u16* Yn   = (u16*)alloc(N * DY * 2);
    // batch1 bf16 outputs (contiguous, order matches fp32 accumulators)
    u16* Sxx  = (u16*)alloc(DX * DX * 2);
    u16* Syy  = (u16*)alloc(DY * DY * 2);
    u16* SxyT = (u16*)alloc(DY * DX * 2);
    // batch2 bf16 outputs (contiguous)
    u16* Gx   = (u16*)alloc(DX * DX * 2);
    u16* Gy   = (u16*)alloc(DY * DY * 2);
    u16* Gfx  = (u16*)alloc(DF * DF * 2);
    u16* Gfy  = (u16*)alloc(DF * DF * 2);
    u16* A1b  = (u16*)alloc(DX * DF * 2);
    u16* B1Tb = (u16*)alloc(DY * DF * 2);
    u16* Hb   = (u16*)alloc(DX * DY * 2);
    u16* cosp = (u16*)alloc(Np * Np * 2);
    u16* cospT= (u16*)alloc(Np * Np * 2);
    float* ap = (float*)alloc(Np * 4);
    float* bp = (float*)alloc(Np * 4);
    float* au = (float*)alloc(N * 4);
    float* bu = (float*)alloc(N * 4);

    // ---- zero zone (ONE memset): slots + potentials + fp32 accumulators ----
    char* zero_begin = w + off;
    float* slots = (float*)alloc(64 * 4);
    float* up = (float*)alloc(Np * 4);
    float* vp = (float*)alloc(Np * 4);
    float* uu = (float*)alloc(N * 4);
    float* vu = (float*)alloc(N * 4);
    float* ua = (float*)alloc(N * 4);
    float* va = (float*)alloc(N * 4);
    float* SxxF  = (float*)alloc(DX * DX * 4);   // batch1 fp32 (contiguous)
    float* SyyF  = (float*)alloc(DY * DY * 4);
    float* SxyTF = (float*)alloc(DY * DX * 4);
    float* GxF   = (float*)alloc(DX * DX * 4);   // batch2 fp32 (contiguous)
    float* GyF   = (float*)alloc(DY * DY * 4);
    float* GfxF  = (float*)alloc(DF * DF * 4);
    float* GfyF  = (float*)alloc(DF * DF * 4);
    float* A1F   = (float*)alloc(DX * DF * 4);
    float* B1F   = (float*)alloc(DY * DF * 4);
    float* HbF   = (float*)alloc(DX * DY * 4);
    float* H2    = (float*)alloc(DX * DY * 4);
    float* D1    = (float*)alloc(DX * DY * 4);
    float* W1F   = (float*)alloc(DX * DX * 4);   // Xu^T diag(au) Xu
    float* W2F   = (float*)alloc(DY * DY * 4);   // Yu^T diag(bu) Yu
    float* MF    = (float*)alloc(DX * DY * 4);   // Xu^T plan Yu
    size_t zero_bytes = (size_t)((w + off) - zero_begin);

    const float SCALE = 20.f;   // 1/eps

#define GEMM_F32(A_, B_, C_, M_, N_, K_, al_) \
    gemm_bt<0><<<dim3((N_) / 128, (M_) / 128), 256, 0, stream>>>((A_), (B_), (C_), nullptr, (M_), (N_), (K_), (K_), (al_))
#define GEMM_B16(A_, B_, C_, M_, N_, K_, al_) \
    gemm_bt<1><<<dim3((N_) / 128, (M_) / 128), 256, 0, stream>>>((A_), (B_), nullptr, (C_), (M_), (N_), (K_), (K_), (al_))
#define GEMM_SKF(A_, B_, CF_, M_, N_, Kfull_, SPL_, al_) \
    gemm_bt<3><<<dim3((N_) / 128, (M_) / 128, (SPL_)), 256, 0, stream>>>((A_), (B_), (CF_), nullptr, (M_), (N_), (Kfull_) / (SPL_), (Kfull_), (al_))

    hipMemsetAsync(zero_begin, 0, zero_bytes, stream);

    // ===== 1. all row-normalizations (8 problems, one dispatch) =====
    {
        RNArgs a;
        a.d[0] = {Xa_in, Xa, 768, 4096};
        a.d[1] = {Ya_in, Ya, 512, 8192};
        a.d[2] = {fXp_in, fXp, 256, 10240};
        a.d[3] = {fYp_in, fYp, 256, 12288};
        a.d[4] = {fX_in, fXn, 256, 16384};
        a.d[5] = {fY_in, fYn, 256, 20480};
        a.d[6] = {X_in, Xu, 768, 24576};
        a.d[7] = {Y_in, Yu, 512, 28672};
        a.n = 8;
        rownorm_batch<<<7168, 256, 0, stream>>>(a);
    }

    // ===== 2. transposes batch A: XaT, YaT, fXnT, fYnT =====
    {
        TPArgs a;
        a.d[0] = {Xa, XaT, 4096, 768, 24, 3072, nullptr};
        a.d[1] = {Ya, YaT, 4096, 512, 16, 5120, nullptr};
        a.d[2] = {fXn, fXnT, 4096, 256, 8, 6144, nullptr};
        a.d[3] = {fYn, fYnT, 4096, 256, 8, 7168, nullptr};
        a.n = 4;
        transpose_batch<<<7168, 256, 0, stream>>>(a);
    }

    // ===== 3. batch1: anchor covariances (split-K8) + cast =====
    {
        BGArgs g;
        g.d[0] = {XaT, XaT, SxxF, 768, 768, 6, 36};
        g.d[1] = {YaT, YaT, SyyF, 512, 512, 4, 52};
        g.d[2] = {YaT, XaT, SxyTF, 512, 768, 6, 76};
        g.n = 3; g.alpha = 1.f / 4096.f;
        bgemm<<<dim3(76, 8), 256, 0, stream>>>(g);
        cast_f2b<<<256, 256, 0, stream>>>(SxxF, Sxx, 768 * 768 + 512 * 512 + 512 * 768);
    }

    // ===== 4. Mahalanobis normalization =====
    GEMM_F32(Xu, Sxx, XS, 4096, 768, 768, 1.f);   // -> S4 (XaT/YaT dead)
    GEMM_F32(Yu, Syy, YS, 4096, 512, 512, 1.f);   // -> S5
    mahal_w<<<1024, 256, 0, stream>>>(Xu, XS, Xn, 4096, 768);
    mahal_w<<<1024, 256, 0, stream>>>(Yu, YS, Yn, 4096, 512);

    // ===== 5. transposes batch B: XnT, YnT (clobber XS in S4) =====
    {
        TPArgs a;
        a.d[0] = {Xn, XnT, 4096, 768, 24, 3072, nullptr};
        a.d[1] = {Yn, YnT, 4096, 512, 16, 5120, nullptr};
        a.n = 2;
        transpose_batch<<<5120, 256, 0, stream>>>(a);
    }

    // ===== 6. batch2: L_div gram matrices (split-K8) + cast =====
    {
        BGArgs g;
        g.d[0] = {XnT, XnT, GxF, 768, 768, 6, 36};
        g.d[1] = {YnT, YnT, GyF, 512, 512, 4, 52};
        g.d[2] = {fXnT, fXnT, GfxF, 256, 256, 2, 56};
        g.d[3] = {fYnT, fYnT, GfyF, 256, 256, 2, 60};
        g.d[4] = {XnT, fXnT, A1F, 768, 256, 2, 72};
        g.d[5] = {YnT, fYnT, B1F, 512, 256, 2, 80};
        g.n = 6; g.alpha = 1.f;
        bgemm<<<dim3(80, 8), 256, 0, stream>>>(g);
        cast_f2b<<<256, 256, 0, stream>>>(GxF, Gx,
            768 * 768 + 512 * 512 + 256 * 256 + 256 * 256 + 768 * 256 + 512 * 256);
    }

    // ===== 7. pairs cost matrices =====
    GEMM_B16(fXp, fYp, cosp, 2048, 2048, 256, 1.f);
    GEMM_B16(fYp, fXp, cospT, 2048, 2048, 256, 1.f);

    // ===== 8. L_div tail =====
    GEMM_SKF(Gx, SxyT, HbF, 768, 512, 768, 4, 1.f);
    cast_f2b<<<256, 256, 0, stream>>>(HbF, Hb, 768 * 512);
    GEMM_SKF(Hb, Gy, H2, 768, 512, 512, 4, 1.f);
    GEMM_SKF(A1b, B1Tb, D1, 768, 512, 256, 2, 1.f);
    dotT<<<192, 256, 0, stream>>>(H2, SxyT, 768, 512, slots + 5);
    dot_bb<<<64, 256, 0, stream>>>(Gfx, Gfy, 256 * 256, slots + 6);
    dotT<<<192, 256, 0, stream>>>(D1, SxyT, 768, 512, slots + 7);

    // ===== 9. cost matrices for both big sinkhorns =====
    GEMM_B16(Xn, SxyT, Tb, 4096, 512, 768, 1.f);     // -> S5 (YS dead)
    GEMM_B16(Tb, Yn, Ca, 4096, 4096, 512, 1.f);      // -> S3
    GEMM_B16(Yn, Tb, CaT, 4096, 4096, 512, 1.f);     // -> S4 (XnT/YnT dead)
    GEMM_B16(fXn, fYn, Cu, 4096, 4096, 256, 1.f);    // -> S1
    GEMM_B16(fYn, fXn, CuT, 4096, 4096, 256, 1.f);   // -> S2

    // ===== 10. triple-fused sinkhorn (latent + anchor + pairs), 10 iters =====
    {
        float lm12 = -logf(4096.f), lm3 = -logf(2048.f);
        for (int it = 0; it < 10; ++it) {
            row_lse_tri<<<2560, 256, 0, stream>>>(Cu, vu, uu, Ca, va, ua, cosp, vp, up, SCALE, lm12, lm3);
            row_lse_tri<<<2560, 256, 0, stream>>>(CuT, uu, vu, CaT, ua, va, cospT, up, vp, SCALE, lm12, lm3);
        }
    }

    // ===== 11. plan + all marginal row/col sums (one dispatch) =====
    plan_quad<<<3072, 256, 0, stream>>>(Cu, CuT, cosp, cospT, uu, vu, up, vp,
                                        plan, au, bu, ap, bp, SCALE);
    marg4<<<4, 256, 0, stream>>>(ap, bp, au, bu, slots + 0);
    diag2<<<1, 256, 0, stream>>>(cosp, up, vp, 2048, SCALE, slots + 2, slots + 3);
    sail_row_w<<<512, 256, 0, stream>>>(cosp, 2048, 10.f, slots + 1);

    // ===== 12. L_ot (reads Ca + Cu before they are clobbered) =====
    ot_row_w<<<1024, 256, 0, stream>>>(Ca, Cu, ua, va, uu, vu, 4096, 4096, SCALE, slots + 4);

    // ===== 13. GW via low-rank identities =====
    // transposes batch C: XuT, YuT (S2; CuT dead), XsT=au-scaled, YsT=bu-scaled (S3; Ca dead)
    {
        TPArgs a;
        a.d[0] = {Xu, XuT, 4096, 768, 24, 3072, nullptr};
        a.d[1] = {Yu, YuT, 4096, 512, 16, 5120, nullptr};
        a.d[2] = {Xu, XsT, 4096, 768, 24, 8192, au};
        a.d[3] = {Yu, YsT, 4096, 512, 16, 10240, bu};
        a.n = 4;
        transpose_batch<<<10240, 256, 0, stream>>>(a);
    }
    // T1T[d,i] = sum_j Yu[j,d] * plan[i,j]  (= (plan @ Yu)^T), into S1 (Cu dead)
    GEMM_B16(YuT, plan, T1T, 512, 4096, 4096, 1.f);
    // W1 = Xu^T diag(au) Xu, W2 = Yu^T diag(bu) Yu  (split-K8 batched)
    {
        BGArgs g;
        g.d[0] = {XsT, XuT, W1F, 768, 768, 6, 36};
        g.d[1] = {YsT, YuT, W2F, 512, 512, 4, 52};
        g.n = 2; g.alpha = 1.f;
        bgemm<<<dim3(52, 8), 256, 0, stream>>>(g);
    }
    // M = Xu^T plan Yu = XuT @ T1T^T  (split-K8)
    {
        BGArgs g;
        g.d[0] = {XuT, T1T, MF, 768, 512, 4, 24};
        g.n = 1; g.alpha = 1.f;
        bgemm<<<dim3(24, 8), 256, 0, stream>>>(g);
    }
    // gw1 = ||W1||^2, gw2 = ||W2||^2, sandwich = ||M||^2
    dot3<<<64, 256, 0, stream>>>(W1F, W2F, MF, 768 * 768, 512 * 512, 768 * 512,
                                 slots + 8, slots + 9, slots + 10);

    combine<<<1, 1, 0, stream>>>(slots, out);

#undef GEMM_F32
#undef GEMM_B16
#undef GEMM_SKF
}

// Round 7
// 917.222 us; speedup vs baseline: 3.7397x; 1.0751x over previous
//
#include <hip/hip_runtime.h>
#include <hip/hip_bf16.h>
#include <math.h>

using u16 = unsigned short;
using s8v = __attribute__((ext_vector_type(8))) short;   // 8 bf16 (4 VGPRs) - MFMA A/B frag
using s4v = __attribute__((ext_vector_type(4))) short;   // 4 bf16
using f4v = __attribute__((ext_vector_type(4))) float;   // MFMA C/D frag

__device__ __forceinline__ float b2f(u16 x) {
    unsigned int u = ((unsigned int)x) << 16;
    return __uint_as_float(u);
}
__device__ __forceinline__ u16 f2b(float f) {
    unsigned int x = __float_as_uint(f);
    unsigned int r = x + 0x7fffu + ((x >> 16) & 1u);   // RNE
    return (u16)(r >> 16);
}

// async global->LDS, 16B per lane; lds base wave-uniform (lane scatter = lane*16)
__device__ __forceinline__ void a16(u16* lds, const u16* g) {
    __builtin_amdgcn_global_load_lds((__attribute__((address_space(1))) void*)g,
                                     (__attribute__((address_space(3))) void*)lds,
                                     16, 0, 0);
}

// ---------------- reductions ----------------
__device__ __forceinline__ float block_sum(float v, float* buf) {
    int t = threadIdx.x;
    buf[t] = v; __syncthreads();
    for (int s = 128; s > 0; s >>= 1) {
        if (t < s) buf[t] += buf[t + s];
        __syncthreads();
    }
    float r = buf[0];
    __syncthreads();
    return r;
}

__device__ __forceinline__ float wave_sum(float v) {
#pragma unroll
    for (int off = 32; off; off >>= 1) v += __shfl_xor(v, off, 64);
    return v;
}

__device__ __forceinline__ void block_atomic4(float wval, float* slot) {
    __shared__ float wb[4];
    int lane = threadIdx.x & 63, wv = threadIdx.x >> 6;
    if (lane == 0) wb[wv] = wval;
    __syncthreads();
    if (threadIdx.x == 0) atomicAdd(slot, wb[0] + wb[1] + wb[2] + wb[3]);
}

// ---------------- GEMM core ----------------
#define TBM 128
#define TBN 128
#define TBK 32

// single-problem GEMM. EPI: 1 -> bf16 C, 3 -> atomicAdd fp32 C (split-K via blockIdx.z)
template<int EPI>
__global__ __launch_bounds__(256)
void gemm_bt(const u16* __restrict__ A, const u16* __restrict__ B,
             float* __restrict__ Cf, u16* __restrict__ Cb,
             int M, int N, int K, int ld, float alpha)
{
    __shared__ __align__(16) u16 As[TBM * TBK];
    __shared__ __align__(16) u16 Bs[TBN * TBK];

    const int tid  = threadIdx.x;
    const int lane = tid & 63;
    const int wave = tid >> 6;
    const int wm   = (wave >> 1) * 64;
    const int wn   = (wave & 1) * 64;
    const int l16  = lane & 15;
    const int q4   = lane >> 4;
    const size_t row0 = (size_t)blockIdx.y * TBM;
    const size_t col0 = (size_t)blockIdx.x * TBN;
    const int kOff = blockIdx.z * K;

    f4v acc[4][4];
#pragma unroll
    for (int mt = 0; mt < 4; ++mt)
#pragma unroll
        for (int nt = 0; nt < 4; ++nt)
#pragma unroll
            for (int r = 0; r < 4; ++r)
                acc[mt][nt][r] = 0.f;

    const int ar0 = wave * 32 + (lane >> 2);
    const int ar1 = ar0 + 16;
    const int akk = (lane & 3) * 8;
    const u16* gA0 = A + (row0 + ar0) * ld + kOff + akk;
    const u16* gA1 = A + (row0 + ar1) * ld + kOff + akk;
    const u16* gB0 = B + (col0 + ar0) * ld + kOff + akk;
    const u16* gB1 = B + (col0 + ar1) * ld + kOff + akk;
    u16* lA0 = As + wave * 1024;
    u16* lA1 = As + wave * 1024 + 512;
    u16* lB0 = Bs + wave * 1024;
    u16* lB1 = Bs + wave * 1024 + 512;

    for (int k0 = 0; k0 < K; k0 += TBK) {
        __syncthreads();
        a16(lA0, gA0 + k0);
        a16(lA1, gA1 + k0);
        a16(lB0, gB0 + k0);
        a16(lB1, gB1 + k0);
        __syncthreads();

        s8v af[4], bfr[4];
#pragma unroll
        for (int mt = 0; mt < 4; ++mt)
            af[mt] = *(const s8v*)(As + (wm + mt * 16 + l16) * TBK + q4 * 8);
#pragma unroll
        for (int nt = 0; nt < 4; ++nt)
            bfr[nt] = *(const s8v*)(Bs + (wn + nt * 16 + l16) * TBK + q4 * 8);
#pragma unroll
        for (int mt = 0; mt < 4; ++mt)
#pragma unroll
            for (int nt = 0; nt < 4; ++nt)
                acc[mt][nt] = __builtin_amdgcn_mfma_f32_16x16x32_bf16(af[mt], bfr[nt], acc[mt][nt], 0, 0, 0);
    }

#pragma unroll
    for (int mt = 0; mt < 4; ++mt)
#pragma unroll
        for (int nt = 0; nt < 4; ++nt)
#pragma unroll
            for (int r = 0; r < 4; ++r) {
                size_t row = row0 + wm + mt * 16 + q4 * 4 + r;
                size_t col = col0 + wn + nt * 16 + l16;
                float v = acc[mt][nt][r] * alpha;
                if (EPI == 1) Cb[row * (size_t)N + col] = f2b(v);
                else          atomicAdd(&Cf[row * (size_t)N + col], v);
            }
}

// ---------------- generalized batched GEMM ----------------
// per-problem: A,B row-major with row stride ld; C = A@B^T. Kc = K-chunk per z-slice.
// EPI: 0 -> store fp32 (z must be 1), 1 -> store bf16 (z=1),
//      2 -> dot epilogue: atomicAdd(slot, sum(C .* W^T)) with W[col*WL+row],
//      3 -> atomicAdd fp32 C (split-K)
struct BGN {
    const u16* A; const u16* B;
    float* Cf; u16* Cb;
    const u16* W; float* slot;
    int M, N, Kc, ld, WL, tN, tEnd;
};
struct BGNArgs { BGN d[6]; int n; float alpha; };

template<int EPI>
__global__ __launch_bounds__(256)
void bgemmN(BGNArgs g)
{
    __shared__ __align__(16) u16 As[TBM * TBK];
    __shared__ __align__(16) u16 Bs[TBN * TBK];

    int bi = 0;
    while (bi < g.n - 1 && (int)blockIdx.x >= g.d[bi].tEnd) ++bi;
    const BGN& d = g.d[bi];
    const int tStart = bi ? g.d[bi - 1].tEnd : 0;
    const int local = blockIdx.x - tStart;
    const int tm = local / d.tN;
    const int tn = local - tm * d.tN;

    const int tid  = threadIdx.x;
    const int lane = tid & 63;
    const int wave = tid >> 6;
    const int wm   = (wave >> 1) * 64;
    const int wn   = (wave & 1) * 64;
    const int l16  = lane & 15;
    const int q4   = lane >> 4;
    const size_t row0 = (size_t)tm * TBM;
    const size_t col0 = (size_t)tn * TBN;
    const int kOff = blockIdx.y * d.Kc;
    const int ld = d.ld;

    f4v acc[4][4];
#pragma unroll
    for (int mt = 0; mt < 4; ++mt)
#pragma unroll
        for (int nt = 0; nt < 4; ++nt)
#pragma unroll
            for (int r = 0; r < 4; ++r)
                acc[mt][nt][r] = 0.f;

    const int ar0 = wave * 32 + (lane >> 2);
    const int ar1 = ar0 + 16;
    const int akk = (lane & 3) * 8;
    const u16* gA0 = d.A + (row0 + ar0) * ld + kOff + akk;
    const u16* gA1 = d.A + (row0 + ar1) * ld + kOff + akk;
    const u16* gB0 = d.B + (col0 + ar0) * ld + kOff + akk;
    const u16* gB1 = d.B + (col0 + ar1) * ld + kOff + akk;
    u16* lA0 = As + wave * 1024;
    u16* lA1 = As + wave * 1024 + 512;
    u16* lB0 = Bs + wave * 1024;
    u16* lB1 = Bs + wave * 1024 + 512;

    for (int k0 = 0; k0 < d.Kc; k0 += TBK) {
        __syncthreads();
        a16(lA0, gA0 + k0);
        a16(lA1, gA1 + k0);
        a16(lB0, gB0 + k0);
        a16(lB1, gB1 + k0);
        __syncthreads();

        s8v af[4], bfr[4];
#pragma unroll
        for (int mt = 0; mt < 4; ++mt)
            af[mt] = *(const s8v*)(As + (wm + mt * 16 + l16) * TBK + q4 * 8);
#pragma unroll
        for (int nt = 0; nt < 4; ++nt)
            bfr[nt] = *(const s8v*)(Bs + (wn + nt * 16 + l16) * TBK + q4 * 8);
#pragma unroll
        for (int mt = 0; mt < 4; ++mt)
#pragma unroll
            for (int nt = 0; nt < 4; ++nt)
                acc[mt][nt] = __builtin_amdgcn_mfma_f32_16x16x32_bf16(af[mt], bfr[nt], acc[mt][nt], 0, 0, 0);
    }

    if (EPI == 2) {
        float local2 = 0.f;
#pragma unroll
        for (int mt = 0; mt < 4; ++mt)
#pragma unroll
            for (int nt = 0; nt < 4; ++nt)
#pragma unroll
                for (int r = 0; r < 4; ++r) {
                    size_t row = row0 + wm + mt * 16 + q4 * 4 + r;
                    size_t col = col0 + wn + nt * 16 + l16;
                    local2 += acc[mt][nt][r] * b2f(d.W[col * (size_t)d.WL + row]);
                }
        __shared__ float red[256];
        float tot = block_sum(local2 * g.alpha, red);
        if (tid == 0) atomicAdd(d.slot, tot);
    } else {
#pragma unroll
        for (int mt = 0; mt < 4; ++mt)
#pragma unroll
            for (int nt = 0; nt < 4; ++nt)
#pragma unroll
                for (int r = 0; r < 4; ++r) {
                    size_t row = row0 + wm + mt * 16 + q4 * 4 + r;
                    size_t col = col0 + wn + nt * 16 + l16;
                    float v = acc[mt][nt][r] * g.alpha;
                    if (EPI == 0)      d.Cf[row * (size_t)d.N + col] = v;
                    else if (EPI == 1) d.Cb[row * (size_t)d.N + col] = f2b(v);
                    else               atomicAdd(&d.Cf[row * (size_t)d.N + col], v);
                }
    }
}

// ---------------- batched rownorm ----------------
struct RN { const float* in; u16* out; int C; int rEnd; };
struct RNArgs { RN d[8]; int n; };

__global__ __launch_bounds__(256)
void rownorm_batch(RNArgs a) {
    int gw = (blockIdx.x * 256 + threadIdx.x) >> 6;
    int lane = threadIdx.x & 63;
    int i = 0;
    while (i < a.n - 1 && gw >= a.d[i].rEnd) ++i;
    if (gw >= a.d[i].rEnd) return;
    int row = gw - (i ? a.d[i - 1].rEnd : 0);
    int C = a.d[i].C;
    const float4* r4 = (const float4*)(a.d[i].in + (size_t)row * C);
    int nv = C >> 2;
    float ss = 0.f;
    for (int c = lane; c < nv; c += 64) {
        float4 v = r4[c];
        ss += v.x * v.x + v.y * v.y + v.z * v.z + v.w * v.w;
    }
    ss = wave_sum(ss);
    float inv = 1.f / fmaxf(sqrtf(ss), 1e-8f);
    s4v* o4 = (s4v*)(a.d[i].out + (size_t)row * C);
    for (int c = lane; c < nv; c += 64) {
        float4 v = r4[c];
        s4v o;
        o[0] = (short)f2b(v.x * inv); o[1] = (short)f2b(v.y * inv);
        o[2] = (short)f2b(v.z * inv); o[3] = (short)f2b(v.w * inv);
        o4[c] = o;
    }
}

__global__ __launch_bounds__(256)
void mahal_w(const u16* __restrict__ Xh, const float* __restrict__ XS,
             u16* __restrict__ out, int nrows, int C) {
    int row = (blockIdx.x * 256 + threadIdx.x) >> 6;
    int lane = threadIdx.x & 63;
    if (row >= nrows) return;
    const s4v* x4 = (const s4v*)(Xh + (size_t)row * C);
    const float4* s4 = (const float4*)(XS + (size_t)row * C);
    int nv = C >> 2;
    float s = 0.f;
    for (int c = lane; c < nv; c += 64) {
        s4v x = x4[c]; float4 v = s4[c];
        s += b2f((u16)x[0]) * v.x + b2f((u16)x[1]) * v.y
           + b2f((u16)x[2]) * v.z + b2f((u16)x[3]) * v.w;
    }
    s = wave_sum(s);
    float inv = 1.f / fmaxf(sqrtf(fmaxf(s, 0.f)), 1e-8f);
    s4v* o4 = (s4v*)(out + (size_t)row * C);
    for (int c = lane; c < nv; c += 64) {
        s4v x = x4[c], o;
#pragma unroll
        for (int k = 0; k < 4; ++k) o[k] = (short)f2b(b2f((u16)x[k]) * inv);
        o4[c] = o;
    }
}

// ---------------- batched 32x32 transpose (optional per-input-row scale) ------
struct TP { const u16* in; u16* out; int R, C, tC, tEnd; const float* s; };
struct TPArgs { TP d[6]; int n; };

__global__ __launch_bounds__(256)
void transpose_batch(TPArgs a) {
    __shared__ u16 tile[32][33];
    int t = blockIdx.x;
    int i = 0;
    while (i < a.n - 1 && t >= a.d[i].tEnd) ++i;
    int local = t - (i ? a.d[i - 1].tEnd : 0);
    const TP& d = a.d[i];
    int ty = local / d.tC, tx = local - ty * d.tC;
    int bx = tx * 32, by = ty * 32;
    int lx = threadIdx.x & 31;
    int lyy = threadIdx.x >> 5;
    for (int r = lyy; r < 32; r += 8)
        tile[r][lx] = d.in[(size_t)(by + r) * d.C + bx + lx];
    __syncthreads();
    for (int r = lyy; r < 32; r += 8) {
        u16 val = tile[lx][r];
        if (d.s) val = f2b(b2f(val) * d.s[by + lx]);
        d.out[(size_t)(bx + r) * d.R + by + lx] = val;
    }
}

__global__ __launch_bounds__(256)
void cast_f2b(const float* __restrict__ in, u16* __restrict__ out, int n) {
    for (int i = blockIdx.x * 256 + threadIdx.x; i < n; i += gridDim.x * 256)
        out[i] = f2b(in[i]);
}

// ---------------- sinkhorn row pass (no-max sum-exp; logits bounded) ----------
__device__ __forceinline__ float row_sumexp(const u16* __restrict__ rowp,
                                            const float* __restrict__ vin,
                                            int ny, float scale, int lane) {
    const s8v* r8 = (const s8v*)rowp;
    const float4* v4 = (const float4*)vin;
    int nv = ny >> 3;
    float s = 0.f;
    for (int c = lane; c < nv; c += 64) {
        s8v v8 = r8[c];
        float4 va = v4[c * 2], vb = v4[c * 2 + 1];
        s += __expf(b2f((u16)v8[0]) * scale + va.x);
        s += __expf(b2f((u16)v8[1]) * scale + va.y);
        s += __expf(b2f((u16)v8[2]) * scale + va.z);
        s += __expf(b2f((u16)v8[3]) * scale + va.w);
        s += __expf(b2f((u16)v8[4]) * scale + vb.x);
        s += __expf(b2f((u16)v8[5]) * scale + vb.y);
        s += __expf(b2f((u16)v8[6]) * scale + vb.z);
        s += __expf(b2f((u16)v8[7]) * scale + vb.w);
    }
    return wave_sum(s);
}

// three problems per pass: P1 (4096), P2 (4096), P3 (2048)
__global__ __launch_bounds__(256)
void row_lse_tri(const u16* __restrict__ C1, const float* __restrict__ v1, float* __restrict__ u1,
                 const u16* __restrict__ C2, const float* __restrict__ v2, float* __restrict__ u2,
                 const u16* __restrict__ C3, const float* __restrict__ v3, float* __restrict__ u3,
                 float scale, float lm12, float lm3) {
    int gw = (blockIdx.x * 256 + threadIdx.x) >> 6;
    int lane = threadIdx.x & 63;
    if (gw < 4096) {
        float s = row_sumexp(C1 + (size_t)gw * 4096, v1, 4096, scale, lane);
        if (lane == 0) u1[gw] = lm12 - __logf(s);
    } else if (gw < 8192) {
        int row = gw - 4096;
        float s = row_sumexp(C2 + (size_t)row * 4096, v2, 4096, scale, lane);
        if (lane == 0) u2[row] = lm12 - __logf(s);
    } else {
        int row = gw - 8192;
        if (row >= 2048) return;
        float s = row_sumexp(C3 + (size_t)row * 2048, v3, 2048, scale, lane);
        if (lane == 0) u3[row] = lm3 - __logf(s);
    }
}

// plan row body: writes plan row (optional), returns rowsum
__device__ __forceinline__ float plan_body(const u16* __restrict__ rowp, u16* __restrict__ prow,
                                           float ui, const float* __restrict__ vin,
                                           int ny, float scale, int lane) {
    const s8v* r8 = (const s8v*)rowp;
    s8v* p8 = (s8v*)prow;
    const float4* v4 = (const float4*)vin;
    int nv = ny >> 3;
    float s = 0.f;
    for (int c = lane; c < nv; c += 64) {
        s8v v8 = r8[c], pb;
        float4 va = v4[c * 2], vb = v4[c * 2 + 1];
        float vv[8] = {va.x, va.y, va.z, va.w, vb.x, vb.y, vb.z, vb.w};
#pragma unroll
        for (int k = 0; k < 8; ++k) {
            float p = __expf(b2f((u16)v8[k]) * scale + ui + vv[k]);
            s += p;
            pb[k] = (short)f2b(p);
        }
        if (p8) p8[c] = pb;
    }
    return wave_sum(s);
}

// 4 problems: plan(Cu), colsums(CuT), pairs rowsums (cosp), pairs colsums (cospT)
__global__ __launch_bounds__(256)
void plan_quad(const u16* __restrict__ Cu, const u16* __restrict__ CuT,
               const u16* __restrict__ cosp, const u16* __restrict__ cospT,
               const float* __restrict__ uu, const float* __restrict__ vu,
               const float* __restrict__ up, const float* __restrict__ vp,
               u16* __restrict__ plan,
               float* __restrict__ au, float* __restrict__ bu,
               float* __restrict__ ap, float* __restrict__ bp, float scale) {
    int gw = (blockIdx.x * 256 + threadIdx.x) >> 6;
    int lane = threadIdx.x & 63;
    if (gw < 4096) {
        float s = plan_body(Cu + (size_t)gw * 4096, plan + (size_t)gw * 4096, uu[gw], vu, 4096, scale, lane);
        if (lane == 0) au[gw] = s;
    } else if (gw < 8192) {
        int r = gw - 4096;
        float s = plan_body(CuT + (size_t)r * 4096, nullptr, vu[r], uu, 4096, scale, lane);
        if (lane == 0) bu[r] = s;
    } else if (gw < 10240) {
        int r = gw - 8192;
        float s = plan_body(cosp + (size_t)r * 2048, nullptr, up[r], vp, 2048, scale, lane);
        if (lane == 0) ap[r] = s;
    } else {
        int r = gw - 10240;
        if (r >= 2048) return;
        float s = plan_body(cospT + (size_t)r * 2048, nullptr, vp[r], up, 2048, scale, lane);
        if (lane == 0) bp[r] = s;
    }
}

// 4 marginal-deviation reductions in one dispatch
__global__ __launch_bounds__(256)
void marg4(const float* __restrict__ ap, const float* __restrict__ bp,
           const float* __restrict__ au, const float* __restrict__ bu,
           float* __restrict__ slot) {
    const float* sv; int n; float target;
    if (blockIdx.x == 0)      { sv = ap; n = 2048; target = 1.f / 2048.f; }
    else if (blockIdx.x == 1) { sv = bp; n = 2048; target = 1.f / 2048.f; }
    else if (blockIdx.x == 2) { sv = au; n = 4096; target = 1.f / 4096.f; }
    else                      { sv = bu; n = 4096; target = 1.f / 4096.f; }
    int t = threadIdx.x;
    float s = 0.f;
    for (int i = t; i < n; i += 256) { float d = sv[i] - target; s += d * d; }
    __shared__ float buf[256];
    float tot = block_sum(s, buf);
    if (t == 0) atomicAdd(slot, tot);
}

__global__ __launch_bounds__(256)
void ot_row_w(const u16* __restrict__ Ca, const u16* __restrict__ Cu,
              const float* __restrict__ ua, const float* __restrict__ va,
              const float* __restrict__ uu, const float* __restrict__ vu,
              int nrows, int ny, float scale, float* __restrict__ slot) {
    int row = (blockIdx.x * 256 + threadIdx.x) >> 6;
    int lane = threadIdx.x & 63;
    float local = 0.f;
    if (row < nrows) {
        const s8v* ra = (const s8v*)(Ca + (size_t)row * ny);
        const s8v* ru = (const s8v*)(Cu + (size_t)row * ny);
        const float4* va4 = (const float4*)va;
        const float4* vu4 = (const float4*)vu;
        float uai = ua[row], uui = uu[row];
        int nv = ny >> 3;
        for (int c = lane; c < nv; c += 64) {
            s8v a8 = ra[c], u8 = ru[c];
            float4 a0 = va4[c * 2], a1 = va4[c * 2 + 1];
            float4 u0 = vu4[c * 2], u1 = vu4[c * 2 + 1];
            float av[8] = {a0.x, a0.y, a0.z, a0.w, a1.x, a1.y, a1.z, a1.w};
            float uv[8] = {u0.x, u0.y, u0.z, u0.w, u1.x, u1.y, u1.z, u1.w};
#pragma unroll
            for (int k = 0; k < 8; ++k) {
                float lpa = b2f((u16)a8[k]) * scale + uai + av[k];
                float lpu = b2f((u16)u8[k]) * scale + uui + uv[k];
                local += __expf(lpa) * (lpa - lpu);
            }
        }
    }
    local = wave_sum(local);
    block_atomic4(local, slot);
}

__global__ __launch_bounds__(256)
void sail_row_w(const u16* __restrict__ cosb, int n, float temp, float* __restrict__ slot) {
    int row = (blockIdx.x * 256 + threadIdx.x) >> 6;
    int lane = threadIdx.x & 63;
    float local = 0.f;
    if (row < n) {
        const s8v* r8 = (const s8v*)(cosb + (size_t)row * n);
        int nv = n >> 3;
        for (int c = lane; c < nv; c += 64) {
            s8v v8 = r8[c];
#pragma unroll
            for (int k = 0; k < 8; ++k) {
                int j = c * 8 + k;
                float cv = b2f((u16)v8[k]);
                float wgt = cv * ((j == row) ? temp : -temp);
                local -= fminf(wgt, 0.f) - log1pf(__expf(-fabsf(wgt)));
            }
        }
    }
    local = wave_sum(local);
    block_atomic4(local, slot);
}

__global__ __launch_bounds__(256)
void diag2(const u16* __restrict__ cosb, const float* __restrict__ up,
           const float* __restrict__ vp, int n, float scale,
           float* __restrict__ slotExp, float* __restrict__ slotImp) {
    int t = threadIdx.x;
    float e = 0.f, im = 0.f;
    float logn = logf((float)n);
    for (int i = t; i < n; i += 256) {
        float c = b2f(cosb[(size_t)i * n + i]);
        e  += (1.f - c) * 0.5f;
        im += scale * c + up[i] + vp[i] + logn;
    }
    __shared__ float buf[256];
    float te = block_sum(e, buf);
    float ti = block_sum(im, buf);
    if (t == 0) { atomicAdd(slotExp, te); atomicAdd(slotImp, ti); }
}

__global__ __launch_bounds__(256)
void dot_bb(const u16* __restrict__ A, const u16* __restrict__ B, int n,
            float* __restrict__ slot) {
    int t = threadIdx.x;
    float local = 0.f;
    for (int i = blockIdx.x * 256 + t; i < n; i += gridDim.x * 256)
        local += b2f(A[i]) * b2f(B[i]);
    __shared__ float buf[256];
    float tot = block_sum(local, buf);
    if (t == 0) atomicAdd(slot, tot);
}

// three fp32 self-dots
__global__ __launch_bounds__(256)
void dot3(const float* __restrict__ A, const float* __restrict__ B, const float* __restrict__ C,
          int na, int nb, int nc, float* __restrict__ sA, float* __restrict__ sB, float* __restrict__ sC) {
    const float* p; int n, b0, nblk; float* slot;
    if (blockIdx.x < 32)      { p = A; n = na; b0 = 0;  nblk = 32; slot = sA; }
    else if (blockIdx.x < 48) { p = B; n = nb; b0 = 32; nblk = 16; slot = sB; }
    else                      { p = C; n = nc; b0 = 48; nblk = 16; slot = sC; }
    int t = threadIdx.x;
    float local = 0.f;
    for (int i = (blockIdx.x - b0) * 256 + t; i < n; i += nblk * 256) {
        float v = p[i]; local += v * v;
    }
    __shared__ float buf[256];
    float tot = block_sum(local, buf);
    if (t == 0) atomicAdd(slot, tot);
}

// slots: 0 marg, 1 sail, 2 exp, 3 imp, 4 ot, 5 norm1, 6 norm2, 7 dot, 8 gw1, 9 gw2, 10 sandwich
__global__ void combine(const float* __restrict__ s, float* __restrict__ out) {
    if (threadIdx.x == 0 && blockIdx.x == 0) {
        float Np = 2048.f;
        float Nu2 = 4096.f * 4096.f;
        float total = s[0]
                    + s[1] / (Np * Np)
                    + s[2] / Np
                    - s[3] / Np
                    + s[4]
                    + (s[5] + s[6] - 2.f * s[7]) / Nu2
                    + s[8] + s[9] - 2.f * s[10];
        out[0] = total;
    }
}

// ------------------------------------------------------------------
extern "C" void kernel_launch(void* const* d_in, const int* in_sizes, int n_in,
                              void* d_out, int out_size, void* d_ws, size_t ws_size,
                              hipStream_t stream) {
    const float* fXp_in = (const float*)d_in[0];   // 2048 x 256
    const float* fYp_in = (const float*)d_in[1];   // 2048 x 256
    const float* X_in   = (const float*)d_in[2];   // 4096 x 768
    const float* Y_in   = (const float*)d_in[3];   // 4096 x 512
    const float* fX_in  = (const float*)d_in[4];   // 4096 x 256
    const float* fY_in  = (const float*)d_in[5];   // 4096 x 256
    const float* Xa_in  = (const float*)d_in[6];   // 4096 x 768
    const float* Ya_in  = (const float*)d_in[7];   // 4096 x 512
    float* out = (float*)d_out;

    char* w = (char*)d_ws;
    size_t off = 0;
    auto alloc = [&](size_t bytes) -> char* {
        char* p = w + off;
        off += (bytes + 255) & ~(size_t)255;
        return p;
    };

    const size_t N = 4096, Np = 2048, DX = 768, DY = 512, DF = 256;

    // ---- five shared 32 MB N x N slots (lifetime-scheduled) ----
    const size_t SLOT = N * N * 2;
    char* S1 = alloc(SLOT);
    char* S2 = alloc(SLOT);
    char* S3 = alloc(SLOT);
    char* S4 = alloc(SLOT);
    char* S5 = alloc(SLOT);

    // S1: Xa -> Cu -> T1T(bf16)
    u16* Xa   = (u16*)S1;
    u16* Cu   = (u16*)S1;
    u16* T1T  = (u16*)S1;
    // S2: Ya -> CuT -> XuT+YuT
    u16* Ya   = (u16*)S2;
    u16* CuT  = (u16*)S2;
    u16* XuT  = (u16*)S2;
    u16* YuT  = (u16*)(S2 + N * DX * 2);
    // S3: Ca -> XsT+YsT
    u16* Ca   = (u16*)S3;
    u16* XsT  = (u16*)S3;
    u16* YsT  = (u16*)(S3 + N * DX * 2);
    // S4: XaT+YaT -> XS -> XnT+YnT -> CaT -> T1F(fp32)
    u16* XaT  = (u16*)S4;
    u16* YaT  = (u16*)(S4 + N * DX * 2);
    float* XS = (float*)S4;
    u16* XnT  = (u16*)S4;
    u16* YnT  = (u16*)(S4 + N * DX * 2);
    u16* CaT  = (u16*)S4;
    float* T1F= (float*)S4;
    // S5: YS -> Tb -> plan
    float* YS = (float*)S5;
    u16* Tb   = (u16*)S5;
    u16* plan = (u16*)S5;

    // ---- dedicated bf16 buffers ----
    u16* fXp  = (u16*)alloc(Np * DF * 2);
    u16* fYp  = (u16*)alloc(Np * DF * 2);
    u16* fXn  = (u16*)alloc(N * DF * 2);
    u16* fYn  = (u16*)alloc(N * DF * 2);
    u16* fXnT = (u16*)alloc(N * DF * 2);
    u16* fYnT = (u16*)alloc(N * DF * 2);
    u16* Xu   = (u16*)alloc(N * DX * 2);
    u16* Yu   = (u16*)alloc(N * DY * 2);
    u16* Xn   = (u16*)alloc(N * DX * 2);
    u16* Yn   = (u16*)alloc(N * DY * 2);
    // batch1 bf16 outputs (contiguous, order matches fp32 accumulators)
    u16* Sxx  = (u16*)alloc(DX * DX * 2);
    u16* Syy  = (u16*)alloc(DY * DY * 2);
    u16* SxyT = (u16*)alloc(DY * DX * 2);
    // batch2 bf16 outputs (contiguous)
    u16* Gx   = (u16*)alloc(DX * DX * 2);
    u16* Gy   = (u16*)alloc(DY * DY * 2);
    u16* Gfx  = (u16*)alloc(DF * DF * 2);
    u16* Gfy  = (u16*)alloc(DF * DF * 2);
    u16* A1b  = (u16*)alloc(DX * DF * 2);
    u16* B1Tb = (u16*)alloc(DY * DF * 2);
    u16* Hb   = (u16*)alloc(DX * DY * 2);
    u16* cosp = (u16*)alloc(Np * Np * 2);
    u16* cospT= (u16*)alloc(Np * Np * 2);
    float* ap = (float*)alloc(Np * 4);
    float* bp = (float*)alloc(Np * 4);
    float* au = (float*)alloc(N * 4);
    float* bu = (float*)alloc(N * 4);

    // ---- zero zone (ONE memset): slots + potentials + fp32 accumulators ----
    char* zero_begin = w + off;
    float* slots = (float*)alloc(64 * 4);
    float* up = (float*)alloc(Np * 4);
    float* vp = (float*)alloc(Np * 4);
    float* uu = (float*)alloc(N * 4);
    float* vu = (float*)alloc(N * 4);
    float* ua = (float*)alloc(N * 4);
    float* va = (float*)alloc(N * 4);
    float* SxxF  = (float*)alloc(DX * DX * 4);   // batch1 fp32 (contiguous)
    float* SyyF  = (float*)alloc(DY * DY * 4);
    float* SxyTF = (float*)alloc(DY * DX * 4);
    float* GxF   = (float*)alloc(DX * DX * 4);   // batch2 fp32 (contiguous)
    float* GyF   = (float*)alloc(DY * DY * 4);
    float* GfxF  = (float*)alloc(DF * DF * 4);
    float* GfyF  = (float*)alloc(DF * DF * 4);
    float* A1F   = (float*)alloc(DX * DF * 4);
    float* B1F   = (float*)alloc(DY * DF * 4);
    float* HbF   = (float*)alloc(DX * DY * 4);
    float* W1F   = (float*)alloc(DX * DX * 4);   // Xu^T diag(au) Xu
    float* W2F   = (float*)alloc(DY * DY * 4);   // Yu^T diag(bu) Yu
    float* MF    = (float*)alloc(DX * DY * 4);   // Xu^T plan Yu
    size_t zero_bytes = (size_t)((w + off) - zero_begin);

    const float SCALE = 20.f;   // 1/eps

    hipMemsetAsync(zero_begin, 0, zero_bytes, stream);

    // ===== 1. all row-normalizations (one dispatch) =====
    {
        RNArgs a;
        a.d[0] = {Xa_in, Xa, 768, 4096};
        a.d[1] = {Ya_in, Ya, 512, 8192};
        a.d[2] = {fXp_in, fXp, 256, 10240};
        a.d[3] = {fYp_in, fYp, 256, 12288};
        a.d[4] = {fX_in, fXn, 256, 16384};
        a.d[5] = {fY_in, fYn, 256, 20480};
        a.d[6] = {X_in, Xu, 768, 24576};
        a.d[7] = {Y_in, Yu, 512, 28672};
        a.n = 8;
        rownorm_batch<<<7168, 256, 0, stream>>>(a);
    }

    // ===== 2. transposes A: XaT, YaT, fXnT, fYnT =====
    {
        TPArgs a;
        a.d[0] = {Xa, XaT, 4096, 768, 24, 3072, nullptr};
        a.d[1] = {Ya, YaT, 4096, 512, 16, 5120, nullptr};
        a.d[2] = {fXn, fXnT, 4096, 256, 8, 6144, nullptr};
        a.d[3] = {fYn, fYnT, 4096, 256, 8, 7168, nullptr};
        a.n = 4;
        transpose_batch<<<7168, 256, 0, stream>>>(a);
    }

    // ===== 3. batch1: anchor covariances (split-K8) + cast =====
    {
        BGNArgs g;
        g.d[0] = {XaT, XaT, SxxF, nullptr, nullptr, nullptr, 768, 768, 512, 4096, 0, 6, 36};
        g.d[1] = {YaT, YaT, SyyF, nullptr, nullptr, nullptr, 512, 512, 512, 4096, 0, 4, 52};
        g.d[2] = {YaT, XaT, SxyTF, nullptr, nullptr, nullptr, 512, 768, 512, 4096, 0, 6, 76};
        g.n = 3; g.alpha = 1.f / 4096.f;
        bgemmN<3><<<dim3(76, 8), 256, 0, stream>>>(g);
        cast_f2b<<<256, 256, 0, stream>>>(SxxF, Sxx, 768 * 768 + 512 * 512 + 512 * 768);
    }

    // ===== 4. Mahalanobis: XS/YS in one batched dispatch =====
    {
        BGNArgs g;
        g.d[0] = {Xu, Sxx, XS, nullptr, nullptr, nullptr, 4096, 768, 768, 768, 0, 6, 192};
        g.d[1] = {Yu, Syy, YS, nullptr, nullptr, nullptr, 4096, 512, 512, 512, 0, 4, 320};
        g.n = 2; g.alpha = 1.f;
        bgemmN<0><<<dim3(320, 1), 256, 0, stream>>>(g);
    }
    mahal_w<<<1024, 256, 0, stream>>>(Xu, XS, Xn, 4096, 768);
    mahal_w<<<1024, 256, 0, stream>>>(Yu, YS, Yn, 4096, 512);

    // ===== 5. transposes B: XnT, YnT (clobber XS in S4) =====
    {
        TPArgs a;
        a.d[0] = {Xn, XnT, 4096, 768, 24, 3072, nullptr};
        a.d[1] = {Yn, YnT, 4096, 512, 16, 5120, nullptr};
        a.n = 2;
        transpose_batch<<<5120, 256, 0, stream>>>(a);
    }

    // ===== 6. batch2: L_div gram matrices (split-K8) + cast =====
    {
        BGNArgs g;
        g.d[0] = {XnT, XnT, GxF, nullptr, nullptr, nullptr, 768, 768, 512, 4096, 0, 6, 36};
        g.d[1] = {YnT, YnT, GyF, nullptr, nullptr, nullptr, 512, 512, 512, 4096, 0, 4, 52};
        g.d[2] = {fXnT, fXnT, GfxF, nullptr, nullptr, nullptr, 256, 256, 512, 4096, 0, 2, 56};
        g.d[3] = {fYnT, fYnT, GfyF, nullptr, nullptr, nullptr, 256, 256, 512, 4096, 0, 2, 60};
        g.d[4] = {XnT, fXnT, A1F, nullptr, nullptr, nullptr, 768, 256, 512, 4096, 0, 2, 72};
        g.d[5] = {YnT, fYnT, B1F, nullptr, nullptr, nullptr, 512, 256, 512, 4096, 0, 2, 80};
        g.n = 6; g.alpha = 1.f;
        bgemmN<3><<<dim3(80, 8), 256, 0, stream>>>(g);
        cast_f2b<<<256, 256, 0, stream>>>(GxF, Gx,
            768 * 768 + 512 * 512 + 256 * 256 + 256 * 256 + 768 * 256 + 512 * 256);
    }

    // ===== 7. cost matrices Cu, cosp, Tb in ONE batched bf16 dispatch =====
    {
        BGNArgs g;
        g.d[0] = {fXn, fYn, nullptr, Cu, nullptr, nullptr, 4096, 4096, 256, 256, 0, 32, 1024};
        g.d[1] = {fXp, fYp, nullptr, cosp, nullptr, nullptr, 2048, 2048, 256, 256, 0, 16, 1280};
        g.d[2] = {Xn, SxyT, nullptr, Tb, nullptr, nullptr, 4096, 512, 768, 768, 0, 4, 1408};
        g.n = 3; g.alpha = 1.f;
        bgemmN<1><<<dim3(1408, 1), 256, 0, stream>>>(g);
    }
    // Ca = Tb @ Yn^T (single, 1024 blocks)
    gemm_bt<1><<<dim3(32, 32), 256, 0, stream>>>(Tb, Yn, nullptr, Ca, 4096, 4096, 512, 512, 1.f);

    // ===== 8. transposes C: CuT, cospT, CaT (replaces 3 GEMMs) =====
    {
        TPArgs a;
        a.d[0] = {Cu, CuT, 4096, 4096, 128, 16384, nullptr};
        a.d[1] = {cosp, cospT, 2048, 2048, 64, 20480, nullptr};
        a.d[2] = {Ca, CaT, 4096, 4096, 128, 36864, nullptr};
        a.n = 3;
        transpose_batch<<<36864, 256, 0, stream>>>(a);
    }

    // ===== 9. L_div tail: Hb, then H2/D1 with fused Sxy-dot epilogues =====
    gemm_bt<3><<<dim3(4, 6, 4), 256, 0, stream>>>(Gx, SxyT, HbF, nullptr, 768, 512, 192, 768, 1.f);
    cast_f2b<<<256, 256, 0, stream>>>(HbF, Hb, 768 * 512);
    {
        BGNArgs g;
        // norm1 = sum((Hb @ Gy^T) .* Sxy):  W[col*768+row] = SxyT[col][row]
        g.d[0] = {Hb, Gy, nullptr, nullptr, SxyT, slots + 5, 768, 512, 128, 512, 768, 4, 24};
        // dot   = sum((A1 @ B1T^T) .* Sxy)
        g.d[1] = {A1b, B1Tb, nullptr, nullptr, SxyT, slots + 7, 768, 512, 64, 256, 768, 4, 48};
        g.n = 2; g.alpha = 1.f;
        bgemmN<2><<<dim3(48, 4), 256, 0, stream>>>(g);
    }
    dot_bb<<<64, 256, 0, stream>>>(Gfx, Gfy, 256 * 256, slots + 6);

    // ===== 10. triple-fused sinkhorn (latent + anchor + pairs), 10 iters =====
    {
        float lm12 = -logf(4096.f), lm3 = -logf(2048.f);
        for (int it = 0; it < 10; ++it) {
            row_lse_tri<<<2560, 256, 0, stream>>>(Cu, vu, uu, Ca, va, ua, cosp, vp, up, SCALE, lm12, lm3);
            row_lse_tri<<<2560, 256, 0, stream>>>(CuT, uu, vu, CaT, ua, va, cospT, up, vp, SCALE, lm12, lm3);
        }
    }

    // ===== 11. plan + all marginal row/col sums (one dispatch) =====
    plan_quad<<<3072, 256, 0, stream>>>(Cu, CuT, cosp, cospT, uu, vu, up, vp,
                                        plan, au, bu, ap, bp, SCALE);
    marg4<<<4, 256, 0, stream>>>(ap, bp, au, bu, slots + 0);
    diag2<<<1, 256, 0, stream>>>(cosp, up, vp, 2048, SCALE, slots + 2, slots + 3);
    sail_row_w<<<512, 256, 0, stream>>>(cosp, 2048, 10.f, slots + 1);

    // ===== 12. L_ot (reads Ca + Cu before they are clobbered) =====
    ot_row_w<<<1024, 256, 0, stream>>>(Ca, Cu, ua, va, uu, vu, 4096, 4096, SCALE, slots + 4);

    // ===== 13. GW via low-rank identities =====
    // transposes D: XuT, YuT (S2; CuT dead), XsT=au-scaled, YsT=bu-scaled (S3; Ca dead)
    {
        TPArgs a;
        a.d[0] = {Xu, XuT, 4096, 768, 24, 3072, nullptr};
        a.d[1] = {Yu, YuT, 4096, 512, 16, 5120, nullptr};
        a.d[2] = {Xu, XsT, 4096, 768, 24, 8192, au};
        a.d[3] = {Yu, YsT, 4096, 512, 16, 10240, bu};
        a.n = 4;
        transpose_batch<<<10240, 256, 0, stream>>>(a);
    }
    // zero T1F (S4; CaT dead after sinkhorn)
    hipMemsetAsync(T1F, 0, 512 * 4096 * 4, stream);
    // ONE split-K8 batch: T1F = YuT @ plan^T (512x4096, K=4096), W1, W2
    {
        BGNArgs g;
        g.d[0] = {YuT, plan, T1F, nullptr, nullptr, nullptr, 512, 4096, 512, 4096, 0, 32, 128};
        g.d[1] = {XsT, XuT, W1F, nullptr, nullptr, nullptr, 768, 768, 512, 4096, 0, 6, 164};
        g.d[2] = {YsT, YuT, W2F, nullptr, nullptr, nullptr, 512, 512, 512, 4096, 0, 4, 180};
        g.n = 3; g.alpha = 1.f;
        bgemmN<3><<<dim3(180, 8), 256, 0, stream>>>(g);
    }
    cast_f2b<<<512, 256, 0, stream>>>(T1F, T1T, 512 * 4096);   // -> S1 (Cu dead)
    // M = XuT @ T1T^T  (split-K8)
    {
        BGNArgs g;
        g.d[0] = {XuT, T1T, MF, nullptr, nullptr, nullptr, 768, 512, 512, 4096, 0, 4, 24};
        g.n = 1; g.alpha = 1.f;
        bgemmN<3><<<dim3(24, 8), 256, 0, stream>>>(g);
    }
    // gw1 = ||W1||^2, gw2 = ||W2||^2, sandwich = ||M||^2
    dot3<<<64, 256, 0, stream>>>(W1F, W2F, MF, 768 * 768, 512 * 512, 768 * 512,
                                 slots + 8, slots + 9, slots + 10);

    combine<<<1, 1, 0, stream>>>(slots, out);
}

// Round 8
// 847.694 us; speedup vs baseline: 4.0464x; 1.0820x over previous
//
#include <hip/hip_runtime.h>
#include <hip/hip_bf16.h>
#include <math.h>

using u16 = unsigned short;
using s8v = __attribute__((ext_vector_type(8))) short;   // 8 bf16 (4 VGPRs) - MFMA A/B frag
using s4v = __attribute__((ext_vector_type(4))) short;   // 4 bf16
using f4v = __attribute__((ext_vector_type(4))) float;   // MFMA C/D frag

__device__ __forceinline__ float b2f(u16 x) {
    unsigned int u = ((unsigned int)x) << 16;
    return __uint_as_float(u);
}
__device__ __forceinline__ u16 f2b(float f) {
    unsigned int x = __float_as_uint(f);
    unsigned int r = x + 0x7fffu + ((x >> 16) & 1u);   // RNE
    return (u16)(r >> 16);
}

// async global->LDS, 16B per lane; lds base wave-uniform (lane scatter = lane*16)
__device__ __forceinline__ void a16(u16* lds, const u16* g) {
    __builtin_amdgcn_global_load_lds((__attribute__((address_space(1))) void*)g,
                                     (__attribute__((address_space(3))) void*)lds,
                                     16, 0, 0);
}

// ---------------- reductions ----------------
__device__ __forceinline__ float block_sum(float v, float* buf) {
    int t = threadIdx.x;
    buf[t] = v; __syncthreads();
    for (int s = 128; s > 0; s >>= 1) {
        if (t < s) buf[t] += buf[t + s];
        __syncthreads();
    }
    float r = buf[0];
    __syncthreads();
    return r;
}

__device__ __forceinline__ float wave_sum(float v) {
#pragma unroll
    for (int off = 32; off; off >>= 1) v += __shfl_xor(v, off, 64);
    return v;
}

__device__ __forceinline__ void block_atomic4(float wval, float* slot) {
    __shared__ float wb[4];
    int lane = threadIdx.x & 63, wv = threadIdx.x >> 6;
    if (lane == 0) wb[wv] = wval;
    __syncthreads();
    if (threadIdx.x == 0) atomicAdd(slot, wb[0] + wb[1] + wb[2] + wb[3]);
}

// ---------------- GEMM core ----------------
#define TBM 128
#define TBN 128
#define TBK 32

// single-problem GEMM. EPI: 1 -> bf16 C, 3 -> atomicAdd fp32 C (split-K via blockIdx.z)
template<int EPI>
__global__ __launch_bounds__(256)
void gemm_bt(const u16* __restrict__ A, const u16* __restrict__ B,
             float* __restrict__ Cf, u16* __restrict__ Cb,
             int M, int N, int K, int ld, float alpha)
{
    __shared__ __align__(16) u16 As[TBM * TBK];
    __shared__ __align__(16) u16 Bs[TBN * TBK];

    const int tid  = threadIdx.x;
    const int lane = tid & 63;
    const int wave = tid >> 6;
    const int wm   = (wave >> 1) * 64;
    const int wn   = (wave & 1) * 64;
    const int l16  = lane & 15;
    const int q4   = lane >> 4;
    const size_t row0 = (size_t)blockIdx.y * TBM;
    const size_t col0 = (size_t)blockIdx.x * TBN;
    const int kOff = blockIdx.z * K;

    f4v acc[4][4];
#pragma unroll
    for (int mt = 0; mt < 4; ++mt)
#pragma unroll
        for (int nt = 0; nt < 4; ++nt)
#pragma unroll
            for (int r = 0; r < 4; ++r)
                acc[mt][nt][r] = 0.f;

    const int ar0 = wave * 32 + (lane >> 2);
    const int ar1 = ar0 + 16;
    const int akk = (lane & 3) * 8;
    const u16* gA0 = A + (row0 + ar0) * ld + kOff + akk;
    const u16* gA1 = A + (row0 + ar1) * ld + kOff + akk;
    const u16* gB0 = B + (col0 + ar0) * ld + kOff + akk;
    const u16* gB1 = B + (col0 + ar1) * ld + kOff + akk;
    u16* lA0 = As + wave * 1024;
    u16* lA1 = As + wave * 1024 + 512;
    u16* lB0 = Bs + wave * 1024;
    u16* lB1 = Bs + wave * 1024 + 512;

    for (int k0 = 0; k0 < K; k0 += TBK) {
        __syncthreads();
        a16(lA0, gA0 + k0);
        a16(lA1, gA1 + k0);
        a16(lB0, gB0 + k0);
        a16(lB1, gB1 + k0);
        __syncthreads();

        s8v af[4], bfr[4];
#pragma unroll
        for (int mt = 0; mt < 4; ++mt)
            af[mt] = *(const s8v*)(As + (wm + mt * 16 + l16) * TBK + q4 * 8);
#pragma unroll
        for (int nt = 0; nt < 4; ++nt)
            bfr[nt] = *(const s8v*)(Bs + (wn + nt * 16 + l16) * TBK + q4 * 8);
#pragma unroll
        for (int mt = 0; mt < 4; ++mt)
#pragma unroll
            for (int nt = 0; nt < 4; ++nt)
                acc[mt][nt] = __builtin_amdgcn_mfma_f32_16x16x32_bf16(af[mt], bfr[nt], acc[mt][nt], 0, 0, 0);
    }

#pragma unroll
    for (int mt = 0; mt < 4; ++mt)
#pragma unroll
        for (int nt = 0; nt < 4; ++nt)
#pragma unroll
            for (int r = 0; r < 4; ++r) {
                size_t row = row0 + wm + mt * 16 + q4 * 4 + r;
                size_t col = col0 + wn + nt * 16 + l16;
                float v = acc[mt][nt][r] * alpha;
                if (EPI == 1) Cb[row * (size_t)N + col] = f2b(v);
                else          atomicAdd(&Cf[row * (size_t)N + col], v);
            }
}

// ---------------- generalized batched GEMM ----------------
// per-problem: A,B row-major with row stride ld; C = A@B^T. Kc = K-chunk per z-slice.
// EPI: 0 -> store fp32 (z=1), 1 -> store bf16 (z=1),
//      2 -> dot epilogue: atomicAdd(slot, sum(C .* W^T)) with W[col*WL+row],
//      3 -> atomicAdd fp32 C (split-K),
//      4 -> store fp32 to per-slice buffer Cf + z*M*N (split-K, no atomics)
struct BGN {
    const u16* A; const u16* B;
    float* Cf; u16* Cb;
    const u16* W; float* slot;
    int M, N, Kc, ld, WL, tN, tEnd;
};
struct BGNArgs { BGN d[6]; int n; float alpha; };

template<int EPI>
__global__ __launch_bounds__(256)
void bgemmN(BGNArgs g)
{
    __shared__ __align__(16) u16 As[TBM * TBK];
    __shared__ __align__(16) u16 Bs[TBN * TBK];

    int bi = 0;
    while (bi < g.n - 1 && (int)blockIdx.x >= g.d[bi].tEnd) ++bi;
    const BGN& d = g.d[bi];
    const int tStart = bi ? g.d[bi - 1].tEnd : 0;
    const int local = blockIdx.x - tStart;
    const int tm = local / d.tN;
    const int tn = local - tm * d.tN;

    const int tid  = threadIdx.x;
    const int lane = tid & 63;
    const int wave = tid >> 6;
    const int wm   = (wave >> 1) * 64;
    const int wn   = (wave & 1) * 64;
    const int l16  = lane & 15;
    const int q4   = lane >> 4;
    const size_t row0 = (size_t)tm * TBM;
    const size_t col0 = (size_t)tn * TBN;
    const int kOff = blockIdx.y * d.Kc;
    const int ld = d.ld;

    f4v acc[4][4];
#pragma unroll
    for (int mt = 0; mt < 4; ++mt)
#pragma unroll
        for (int nt = 0; nt < 4; ++nt)
#pragma unroll
            for (int r = 0; r < 4; ++r)
                acc[mt][nt][r] = 0.f;

    const int ar0 = wave * 32 + (lane >> 2);
    const int ar1 = ar0 + 16;
    const int akk = (lane & 3) * 8;
    const u16* gA0 = d.A + (row0 + ar0) * ld + kOff + akk;
    const u16* gA1 = d.A + (row0 + ar1) * ld + kOff + akk;
    const u16* gB0 = d.B + (col0 + ar0) * ld + kOff + akk;
    const u16* gB1 = d.B + (col0 + ar1) * ld + kOff + akk;
    u16* lA0 = As + wave * 1024;
    u16* lA1 = As + wave * 1024 + 512;
    u16* lB0 = Bs + wave * 1024;
    u16* lB1 = Bs + wave * 1024 + 512;

    for (int k0 = 0; k0 < d.Kc; k0 += TBK) {
        __syncthreads();
        a16(lA0, gA0 + k0);
        a16(lA1, gA1 + k0);
        a16(lB0, gB0 + k0);
        a16(lB1, gB1 + k0);
        __syncthreads();

        s8v af[4], bfr[4];
#pragma unroll
        for (int mt = 0; mt < 4; ++mt)
            af[mt] = *(const s8v*)(As + (wm + mt * 16 + l16) * TBK + q4 * 8);
#pragma unroll
        for (int nt = 0; nt < 4; ++nt)
            bfr[nt] = *(const s8v*)(Bs + (wn + nt * 16 + l16) * TBK + q4 * 8);
#pragma unroll
        for (int mt = 0; mt < 4; ++mt)
#pragma unroll
            for (int nt = 0; nt < 4; ++nt)
                acc[mt][nt] = __builtin_amdgcn_mfma_f32_16x16x32_bf16(af[mt], bfr[nt], acc[mt][nt], 0, 0, 0);
    }

    if (EPI == 2) {
        float local2 = 0.f;
#pragma unroll
        for (int mt = 0; mt < 4; ++mt)
#pragma unroll
            for (int nt = 0; nt < 4; ++nt)
#pragma unroll
                for (int r = 0; r < 4; ++r) {
                    size_t row = row0 + wm + mt * 16 + q4 * 4 + r;
                    size_t col = col0 + wn + nt * 16 + l16;
                    local2 += acc[mt][nt][r] * b2f(d.W[col * (size_t)d.WL + row]);
                }
        __shared__ float red[256];
        float tot = block_sum(local2 * g.alpha, red);
        if (tid == 0) atomicAdd(d.slot, tot);
    } else {
        float* Cs = (EPI == 4) ? d.Cf + (size_t)blockIdx.y * d.M * d.N : d.Cf;
#pragma unroll
        for (int mt = 0; mt < 4; ++mt)
#pragma unroll
            for (int nt = 0; nt < 4; ++nt)
#pragma unroll
                for (int r = 0; r < 4; ++r) {
                    size_t row = row0 + wm + mt * 16 + q4 * 4 + r;
                    size_t col = col0 + wn + nt * 16 + l16;
                    float v = acc[mt][nt][r] * g.alpha;
                    if (EPI == 0)      d.Cf[row * (size_t)d.N + col] = v;
                    else if (EPI == 1) d.Cb[row * (size_t)d.N + col] = f2b(v);
                    else if (EPI == 4) Cs[row * (size_t)d.N + col] = v;
                    else               atomicAdd(&d.Cf[row * (size_t)d.N + col], v);
                }
    }
}

// ---------------- batched rownorm ----------------
struct RN { const float* in; u16* out; int C; int rEnd; };
struct RNArgs { RN d[8]; int n; };

__global__ __launch_bounds__(256)
void rownorm_batch(RNArgs a) {
    int gw = (blockIdx.x * 256 + threadIdx.x) >> 6;
    int lane = threadIdx.x & 63;
    int i = 0;
    while (i < a.n - 1 && gw >= a.d[i].rEnd) ++i;
    if (gw >= a.d[i].rEnd) return;
    int row = gw - (i ? a.d[i - 1].rEnd : 0);
    int C = a.d[i].C;
    const float4* r4 = (const float4*)(a.d[i].in + (size_t)row * C);
    int nv = C >> 2;
    float ss = 0.f;
    for (int c = lane; c < nv; c += 64) {
        float4 v = r4[c];
        ss += v.x * v.x + v.y * v.y + v.z * v.z + v.w * v.w;
    }
    ss = wave_sum(ss);
    float inv = 1.f / fmaxf(sqrtf(ss), 1e-8f);
    s4v* o4 = (s4v*)(a.d[i].out + (size_t)row * C);
    for (int c = lane; c < nv; c += 64) {
        float4 v = r4[c];
        s4v o;
        o[0] = (short)f2b(v.x * inv); o[1] = (short)f2b(v.y * inv);
        o[2] = (short)f2b(v.z * inv); o[3] = (short)f2b(v.w * inv);
        o4[c] = o;
    }
}

__global__ __launch_bounds__(256)
void mahal_w(const u16* __restrict__ Xh, const float* __restrict__ XS,
             u16* __restrict__ out, int nrows, int C) {
    int row = (blockIdx.x * 256 + threadIdx.x) >> 6;
    int lane = threadIdx.x & 63;
    if (row >= nrows) return;
    const s4v* x4 = (const s4v*)(Xh + (size_t)row * C);
    const float4* s4 = (const float4*)(XS + (size_t)row * C);
    int nv = C >> 2;
    float s = 0.f;
    for (int c = lane; c < nv; c += 64) {
        s4v x = x4[c]; float4 v = s4[c];
        s += b2f((u16)x[0]) * v.x + b2f((u16)x[1]) * v.y
           + b2f((u16)x[2]) * v.z + b2f((u16)x[3]) * v.w;
    }
    s = wave_sum(s);
    float inv = 1.f / fmaxf(sqrtf(fmaxf(s, 0.f)), 1e-8f);
    s4v* o4 = (s4v*)(out + (size_t)row * C);
    for (int c = lane; c < nv; c += 64) {
        s4v x = x4[c], o;
#pragma unroll
        for (int k = 0; k < 4; ++k) o[k] = (short)f2b(b2f((u16)x[k]) * inv);
        o4[c] = o;
    }
}

// ---------------- batched 32x32 transpose (optional per-input-row scale) ------
struct TP { const u16* in; u16* out; int R, C, tC, tEnd; const float* s; };
struct TPArgs { TP d[6]; int n; };

__global__ __launch_bounds__(256)
void transpose_batch(TPArgs a) {
    __shared__ u16 tile[32][33];
    int t = blockIdx.x;
    int i = 0;
    while (i < a.n - 1 && t >= a.d[i].tEnd) ++i;
    int local = t - (i ? a.d[i - 1].tEnd : 0);
    const TP& d = a.d[i];
    int ty = local / d.tC, tx = local - ty * d.tC;
    int bx = tx * 32, by = ty * 32;
    int lx = threadIdx.x & 31;
    int lyy = threadIdx.x >> 5;
    for (int r = lyy; r < 32; r += 8)
        tile[r][lx] = d.in[(size_t)(by + r) * d.C + bx + lx];
    __syncthreads();
    for (int r = lyy; r < 32; r += 8) {
        u16 val = tile[lx][r];
        if (d.s) val = f2b(b2f(val) * d.s[by + lx]);
        d.out[(size_t)(bx + r) * d.R + by + lx] = val;
    }
}

__global__ __launch_bounds__(256)
void cast_f2b(const float* __restrict__ in, u16* __restrict__ out, int n) {
    for (int i = blockIdx.x * 256 + threadIdx.x; i < n; i += gridDim.x * 256)
        out[i] = f2b(in[i]);
}

// ---------------- sinkhorn row pass (no-max sum-exp; logits bounded) ----------
__device__ __forceinline__ float row_sumexp(const u16* __restrict__ rowp,
                                            const float* __restrict__ vin,
                                            int ny, float scale, int lane) {
    const s8v* r8 = (const s8v*)rowp;
    const float4* v4 = (const float4*)vin;
    int nv = ny >> 3;
    float s = 0.f;
    for (int c = lane; c < nv; c += 64) {
        s8v v8 = r8[c];
        float4 va = v4[c * 2], vb = v4[c * 2 + 1];
        s += __expf(b2f((u16)v8[0]) * scale + va.x);
        s += __expf(b2f((u16)v8[1]) * scale + va.y);
        s += __expf(b2f((u16)v8[2]) * scale + va.z);
        s += __expf(b2f((u16)v8[3]) * scale + va.w);
        s += __expf(b2f((u16)v8[4]) * scale + vb.x);
        s += __expf(b2f((u16)v8[5]) * scale + vb.y);
        s += __expf(b2f((u16)v8[6]) * scale + vb.z);
        s += __expf(b2f((u16)v8[7]) * scale + vb.w);
    }
    return wave_sum(s);
}

// three problems per pass: P1 (4096), P2 (4096), P3 (2048)
__global__ __launch_bounds__(256)
void row_lse_tri(const u16* __restrict__ C1, const float* __restrict__ v1, float* __restrict__ u1,
                 const u16* __restrict__ C2, const float* __restrict__ v2, float* __restrict__ u2,
                 const u16* __restrict__ C3, const float* __restrict__ v3, float* __restrict__ u3,
                 float scale, float lm12, float lm3) {
    int gw = (blockIdx.x * 256 + threadIdx.x) >> 6;
    int lane = threadIdx.x & 63;
    if (gw < 4096) {
        float s = row_sumexp(C1 + (size_t)gw * 4096, v1, 4096, scale, lane);
        if (lane == 0) u1[gw] = lm12 - __logf(s);
    } else if (gw < 8192) {
        int row = gw - 4096;
        float s = row_sumexp(C2 + (size_t)row * 4096, v2, 4096, scale, lane);
        if (lane == 0) u2[row] = lm12 - __logf(s);
    } else {
        int row = gw - 8192;
        if (row >= 2048) return;
        float s = row_sumexp(C3 + (size_t)row * 2048, v3, 2048, scale, lane);
        if (lane == 0) u3[row] = lm3 - __logf(s);
    }
}

// fused: plan+au+L_ot (Cu & Ca rows) for blocks [0,1024); pairs rowsums for [1024,1536)
__global__ __launch_bounds__(256)
void plan_ot(const u16* __restrict__ Cu, const u16* __restrict__ Ca,
             const u16* __restrict__ cosp,
             const float* __restrict__ uu, const float* __restrict__ vu,
             const float* __restrict__ ua, const float* __restrict__ va,
             const float* __restrict__ up, const float* __restrict__ vp,
             u16* __restrict__ plan,
             float* __restrict__ au, float* __restrict__ ap,
             float* __restrict__ slotOt, float scale) {
    int gw = (blockIdx.x * 256 + threadIdx.x) >> 6;
    int lane = threadIdx.x & 63;
    if (blockIdx.x < 1024) {
        int i = gw;
        const s8v* ru = (const s8v*)(Cu + (size_t)i * 4096);
        const s8v* ra = (const s8v*)(Ca + (size_t)i * 4096);
        s8v* p8 = (s8v*)(plan + (size_t)i * 4096);
        const float4* vu4 = (const float4*)vu;
        const float4* va4 = (const float4*)va;
        float uui = uu[i], uai = ua[i];
        float sa = 0.f, ot = 0.f;
        for (int c = lane; c < 512; c += 64) {
            s8v u8 = ru[c], a8 = ra[c], pb;
            float4 u0 = vu4[c * 2], u1 = vu4[c * 2 + 1];
            float4 a0 = va4[c * 2], a1 = va4[c * 2 + 1];
            float uv[8] = {u0.x, u0.y, u0.z, u0.w, u1.x, u1.y, u1.z, u1.w};
            float av[8] = {a0.x, a0.y, a0.z, a0.w, a1.x, a1.y, a1.z, a1.w};
#pragma unroll
            for (int k = 0; k < 8; ++k) {
                float lpu = b2f((u16)u8[k]) * scale + uui + uv[k];
                float p = __expf(lpu);
                sa += p;
                pb[k] = (short)f2b(p);
                float lpa = b2f((u16)a8[k]) * scale + uai + av[k];
                ot += __expf(lpa) * (lpa - lpu);
            }
            p8[c] = pb;
        }
        sa = wave_sum(sa);
        if (lane == 0) au[i] = sa;
        ot = wave_sum(ot);
        block_atomic4(ot, slotOt);
    } else {
        int r = gw - 4096;
        const s8v* r8 = (const s8v*)(cosp + (size_t)r * 2048);
        const float4* vp4 = (const float4*)vp;
        float ui = up[r], s = 0.f;
        for (int c = lane; c < 256; c += 64) {
            s8v v8 = r8[c];
            float4 v0 = vp4[c * 2], v1 = vp4[c * 2 + 1];
            float vv[8] = {v0.x, v0.y, v0.z, v0.w, v1.x, v1.y, v1.z, v1.w};
#pragma unroll
            for (int k = 0; k < 8; ++k)
                s += __expf(b2f((u16)v8[k]) * scale + ui + vv[k]);
        }
        s = wave_sum(s);
        if (lane == 0) ap[r] = s;
    }
}

// 2 marginal-deviation reductions (b-marginals are analytically uniform -> 0)
__global__ __launch_bounds__(256)
void marg2(const float* __restrict__ ap, const float* __restrict__ au,
           float* __restrict__ slot) {
    const float* sv; int n; float target;
    if (blockIdx.x == 0) { sv = ap; n = 2048; target = 1.f / 2048.f; }
    else                 { sv = au; n = 4096; target = 1.f / 4096.f; }
    int t = threadIdx.x;
    float s = 0.f;
    for (int i = t; i < n; i += 256) { float d = sv[i] - target; s += d * d; }
    __shared__ float buf[256];
    float tot = block_sum(s, buf);
    if (t == 0) atomicAdd(slot, tot);
}

__global__ __launch_bounds__(256)
void sail_row_w(const u16* __restrict__ cosb, int n, float temp, float* __restrict__ slot) {
    int row = (blockIdx.x * 256 + threadIdx.x) >> 6;
    int lane = threadIdx.x & 63;
    float local = 0.f;
    if (row < n) {
        const s8v* r8 = (const s8v*)(cosb + (size_t)row * n);
        int nv = n >> 3;
        for (int c = lane; c < nv; c += 64) {
            s8v v8 = r8[c];
#pragma unroll
            for (int k = 0; k < 8; ++k) {
                int j = c * 8 + k;
                float cv = b2f((u16)v8[k]);
                float wgt = cv * ((j == row) ? temp : -temp);
                local -= fminf(wgt, 0.f) - log1pf(__expf(-fabsf(wgt)));
            }
        }
    }
    local = wave_sum(local);
    block_atomic4(local, slot);
}

__global__ __launch_bounds__(256)
void diag2(const u16* __restrict__ cosb, const float* __restrict__ up,
           const float* __restrict__ vp, int n, float scale,
           float* __restrict__ slotExp, float* __restrict__ slotImp) {
    int t = threadIdx.x;
    float e = 0.f, im = 0.f;
    float logn = logf((float)n);
    for (int i = t; i < n; i += 256) {
        float c = b2f(cosb[(size_t)i * n + i]);
        e  += (1.f - c) * 0.5f;
        im += scale * c + up[i] + vp[i] + logn;
    }
    __shared__ float buf[256];
    float te = block_sum(e, buf);
    float ti = block_sum(im, buf);
    if (t == 0) { atomicAdd(slotExp, te); atomicAdd(slotImp, ti); }
}

__global__ __launch_bounds__(256)
void dot_bb(const u16* __restrict__ A, const u16* __restrict__ B, int n,
            float* __restrict__ slot) {
    int t = threadIdx.x;
    float local = 0.f;
    for (int i = blockIdx.x * 256 + t; i < n; i += gridDim.x * 256)
        local += b2f(A[i]) * b2f(B[i]);
    __shared__ float buf[256];
    float tot = block_sum(local, buf);
    if (t == 0) atomicAdd(slot, tot);
}

// reduce split-K slices: T1T bf16 (4 slices) + ||W1||^2 + ||(1/4096)W2||^2
__global__ __launch_bounds__(256)
void gw_reduce(const float* __restrict__ T1S, u16* __restrict__ T1T,
               const float* __restrict__ W1S, const float* __restrict__ W2S,
               float* __restrict__ s8, float* __restrict__ s9) {
    int b = blockIdx.x, t = threadIdx.x;
    if (b < 512) {
        const int n = 512 * 4096, st = n;
        for (int i = b * 256 + t; i < n; i += 512 * 256)
            T1T[i] = f2b(T1S[i] + T1S[i + st] + T1S[i + 2 * st] + T1S[i + 3 * st]);
    } else if (b < 548) {
        const int n = 768 * 768, st = n;
        float local = 0.f;
        for (int i = (b - 512) * 256 + t; i < n; i += 36 * 256) {
            float v = W1S[i] + W1S[i + st] + W1S[i + 2 * st] + W1S[i + 3 * st];
            local += v * v;
        }
        __shared__ float buf[256];
        float tot = block_sum(local, buf);
        if (t == 0) atomicAdd(s8, tot);
    } else {
        const int n = 512 * 512, st = n;
        const float sc = 1.f / 4096.f;
        float local = 0.f;
        for (int i = (b - 548) * 256 + t; i < n; i += 16 * 256) {
            float v = (W2S[i] + W2S[i + st] + W2S[i + 2 * st] + W2S[i + 3 * st]) * sc;
            local += v * v;
        }
        __shared__ float buf[256];
        float tot = block_sum(local, buf);
        if (t == 0) atomicAdd(s9, tot);
    }
}

__global__ __launch_bounds__(256)
void sumsq(const float* __restrict__ p, int n, float* __restrict__ slot) {
    int t = threadIdx.x;
    float local = 0.f;
    for (int i = blockIdx.x * 256 + t; i < n; i += gridDim.x * 256) {
        float v = p[i]; local += v * v;
    }
    __shared__ float buf[256];
    float tot = block_sum(local, buf);
    if (t == 0) atomicAdd(slot, tot);
}

// slots: 0 marg, 1 sail, 2 exp, 3 imp, 4 ot, 5 norm1, 6 norm2, 7 dot, 8 gw1, 9 gw2, 10 sandwich
__global__ void combine(const float* __restrict__ s, float* __restrict__ out) {
    if (threadIdx.x == 0 && blockIdx.x == 0) {
        float Np = 2048.f;
        float Nu2 = 4096.f * 4096.f;
        float total = s[0]
                    + s[1] / (Np * Np)
                    + s[2] / Np
                    - s[3] / Np
                    + s[4]
                    + (s[5] + s[6] - 2.f * s[7]) / Nu2
                    + s[8] + s[9] - 2.f * s[10];
        out[0] = total;
    }
}

// ------------------------------------------------------------------
extern "C" void kernel_launch(void* const* d_in, const int* in_sizes, int n_in,
                              void* d_out, int out_size, void* d_ws, size_t ws_size,
                              hipStream_t stream) {
    const float* fXp_in = (const float*)d_in[0];   // 2048 x 256
    const float* fYp_in = (const float*)d_in[1];   // 2048 x 256
    const float* X_in   = (const float*)d_in[2];   // 4096 x 768
    const float* Y_in   = (const float*)d_in[3];   // 4096 x 512
    const float* fX_in  = (const float*)d_in[4];   // 4096 x 256
    const float* fY_in  = (const float*)d_in[5];   // 4096 x 256
    const float* Xa_in  = (const float*)d_in[6];   // 4096 x 768
    const float* Ya_in  = (const float*)d_in[7];   // 4096 x 512
    float* out = (float*)d_out;

    char* w = (char*)d_ws;
    size_t off = 0;
    auto alloc = [&](size_t bytes) -> char* {
        char* p = w + off;
        off += (bytes + 255) & ~(size_t)255;
        return p;
    };

    const size_t N = 4096, Np = 2048, DX = 768, DY = 512, DF = 256;

    // ---- five shared 32 MB N x N slots (lifetime-scheduled) ----
    const size_t SLOT = N * N * 2;
    char* S1 = alloc(SLOT);
    char* S2 = alloc(SLOT);
    char* S3 = alloc(SLOT);
    char* S4 = alloc(SLOT);
    char* S5 = alloc(SLOT);

    // S1: Xa -> Cu -> T1T(bf16)
    u16* Xa   = (u16*)S1;
    u16* Cu   = (u16*)S1;
    u16* T1T  = (u16*)S1;
    // S2: Ya -> CuT -> XuT+YuT
    u16* Ya   = (u16*)S2;
    u16* CuT  = (u16*)S2;
    u16* XuT  = (u16*)S2;
    u16* YuT  = (u16*)(S2 + N * DX * 2);
    // S3: Ca -> XsT + W1S + W2S
    u16* Ca   = (u16*)S3;
    u16* XsT  = (u16*)S3;                          // 6 MB
    float* W1S = (float*)(S3 + 8 * 1024 * 1024);   // 4 x 2.36 MB = 9.44 MB
    float* W2S = (float*)(S3 + 20 * 1024 * 1024);  // 4 x 1.05 MB = 4.19 MB
    // S4: XaT+YaT -> XS -> XnT+YnT -> CaT -> T1S (4 slices, exactly 32 MB)
    u16* XaT  = (u16*)S4;
    u16* YaT  = (u16*)(S4 + N * DX * 2);
    float* XS = (float*)S4;
    u16* XnT  = (u16*)S4;
    u16* YnT  = (u16*)(S4 + N * DX * 2);
    u16* CaT  = (u16*)S4;
    float* T1S= (float*)S4;
    // S5: YS -> Tb -> plan
    float* YS = (float*)S5;
    u16* Tb   = (u16*)S5;
    u16* plan = (u16*)S5;

    // ---- dedicated bf16 buffers ----
    u16* fXp  = (u16*)alloc(Np * DF * 2);
    u16* fYp  = (u16*)alloc(Np * DF * 2);
    u16* fXn  = (u16*)alloc(N * DF * 2);
    u16* fYn  = (u16*)alloc(N * DF * 2);
    u16* fXnT = (u16*)alloc(N * DF * 2);
    u16* fYnT = (u16*)alloc(N * DF * 2);
    u16* Xu   = (u16*)alloc(N * DX * 2);
    u16* Yu   = (u16*)alloc(N * DY * 2);
    u16* Xn   = (u16*)alloc(N * DX * 2);
    u16* Yn   = (u16*)alloc(N * DY * 2);
    // batch1 bf16 outputs (contiguous, order matches fp32 accumulators)
    u16* Sxx  = (u16*)alloc(DX * DX * 2);
    u16* Syy  = (u16*)alloc(DY * DY * 2);
    u16* SxyT = (u16*)alloc(DY * DX * 2);
    // batch2 bf16 outputs (contiguous)
    u16* Gx   = (u16*)alloc(DX * DX * 2);
    u16* Gy   = (u16*)alloc(DY * DY * 2);
    u16* Gfx  = (u16*)alloc(DF * DF * 2);
    u16* Gfy  = (u16*)alloc(DF * DF * 2);
    u16* A1b  = (u16*)alloc(DX * DF * 2);
    u16* B1Tb = (u16*)alloc(DY * DF * 2);
    u16* Hb   = (u16*)alloc(DX * DY * 2);
    u16* cosp = (u16*)alloc(Np * Np * 2);
    u16* cospT= (u16*)alloc(Np * Np * 2);
    float* ap = (float*)alloc(Np * 4);
    float* au = (float*)alloc(N * 4);

    // ---- zero zone (ONE memset): slots + potentials + fp32 atomic targets ----
    char* zero_begin = w + off;
    float* slots = (float*)alloc(64 * 4);
    float* up = (float*)alloc(Np * 4);
    float* vp = (float*)alloc(Np * 4);
    float* uu = (float*)alloc(N * 4);
    float* vu = (float*)alloc(N * 4);
    float* ua = (float*)alloc(N * 4);
    float* va = (float*)alloc(N * 4);
    float* SxxF  = (float*)alloc(DX * DX * 4);   // batch1 fp32 (contiguous)
    float* SyyF  = (float*)alloc(DY * DY * 4);
    float* SxyTF = (float*)alloc(DY * DX * 4);
    float* GxF   = (float*)alloc(DX * DX * 4);   // batch2 fp32 (contiguous)
    float* GyF   = (float*)alloc(DY * DY * 4);
    float* GfxF  = (float*)alloc(DF * DF * 4);
    float* GfyF  = (float*)alloc(DF * DF * 4);
    float* A1F   = (float*)alloc(DX * DF * 4);
    float* B1F   = (float*)alloc(DY * DF * 4);
    float* HbF   = (float*)alloc(DX * DY * 4);
    float* MF    = (float*)alloc(DX * DY * 4);   // Xu^T plan Yu (atomic target)
    size_t zero_bytes = (size_t)((w + off) - zero_begin);

    const float SCALE = 20.f;   // 1/eps

    hipMemsetAsync(zero_begin, 0, zero_bytes, stream);

    // ===== 1. all row-normalizations (one dispatch) =====
    {
        RNArgs a;
        a.d[0] = {Xa_in, Xa, 768, 4096};
        a.d[1] = {Ya_in, Ya, 512, 8192};
        a.d[2] = {fXp_in, fXp, 256, 10240};
        a.d[3] = {fYp_in, fYp, 256, 12288};
        a.d[4] = {fX_in, fXn, 256, 16384};
        a.d[5] = {fY_in, fYn, 256, 20480};
        a.d[6] = {X_in, Xu, 768, 24576};
        a.d[7] = {Y_in, Yu, 512, 28672};
        a.n = 8;
        rownorm_batch<<<7168, 256, 0, stream>>>(a);
    }

    // ===== 2. transposes A: XaT, YaT, fXnT, fYnT =====
    {
        TPArgs a;
        a.d[0] = {Xa, XaT, 4096, 768, 24, 3072, nullptr};
        a.d[1] = {Ya, YaT, 4096, 512, 16, 5120, nullptr};
        a.d[2] = {fXn, fXnT, 4096, 256, 8, 6144, nullptr};
        a.d[3] = {fYn, fYnT, 4096, 256, 8, 7168, nullptr};
        a.n = 4;
        transpose_batch<<<7168, 256, 0, stream>>>(a);
    }

    // ===== 3. batch1: anchor covariances (split-K8, atomic) + cast =====
    {
        BGNArgs g;
        g.d[0] = {XaT, XaT, SxxF, nullptr, nullptr, nullptr, 768, 768, 512, 4096, 0, 6, 36};
        g.d[1] = {YaT, YaT, SyyF, nullptr, nullptr, nullptr, 512, 512, 512, 4096, 0, 4, 52};
        g.d[2] = {YaT, XaT, SxyTF, nullptr, nullptr, nullptr, 512, 768, 512, 4096, 0, 6, 76};
        g.n = 3; g.alpha = 1.f / 4096.f;
        bgemmN<3><<<dim3(76, 8), 256, 0, stream>>>(g);
        cast_f2b<<<256, 256, 0, stream>>>(SxxF, Sxx, 768 * 768 + 512 * 512 + 512 * 768);
    }

    // ===== 4. Mahalanobis: XS/YS in one batched dispatch =====
    {
        BGNArgs g;
        g.d[0] = {Xu, Sxx, XS, nullptr, nullptr, nullptr, 4096, 768, 768, 768, 0, 6, 192};
        g.d[1] = {Yu, Syy, YS, nullptr, nullptr, nullptr, 4096, 512, 512, 512, 0, 4, 320};
        g.n = 2; g.alpha = 1.f;
        bgemmN<0><<<dim3(320, 1), 256, 0, stream>>>(g);
    }
    mahal_w<<<1024, 256, 0, stream>>>(Xu, XS, Xn, 4096, 768);
    mahal_w<<<1024, 256, 0, stream>>>(Yu, YS, Yn, 4096, 512);

    // ===== 5. transposes B: XnT, YnT (clobber XS in S4) =====
    {
        TPArgs a;
        a.d[0] = {Xn, XnT, 4096, 768, 24, 3072, nullptr};
        a.d[1] = {Yn, YnT, 4096, 512, 16, 5120, nullptr};
        a.n = 2;
        transpose_batch<<<5120, 256, 0, stream>>>(a);
    }

    // ===== 6. batch2: L_div gram matrices (split-K8, atomic) + cast =====
    {
        BGNArgs g;
        g.d[0] = {XnT, XnT, GxF, nullptr, nullptr, nullptr, 768, 768, 512, 4096, 0, 6, 36};
        g.d[1] = {YnT, YnT, GyF, nullptr, nullptr, nullptr, 512, 512, 512, 4096, 0, 4, 52};
        g.d[2] = {fXnT, fXnT, GfxF, nullptr, nullptr, nullptr, 256, 256, 512, 4096, 0, 2, 56};
        g.d[3] = {fYnT, fYnT, GfyF, nullptr, nullptr, nullptr, 256, 256, 512, 4096, 0, 2, 60};
        g.d[4] = {XnT, fXnT, A1F, nullptr, nullptr, nullptr, 768, 256, 512, 4096, 0, 2, 72};
        g.d[5] = {YnT, fYnT, B1F, nullptr, nullptr, nullptr, 512, 256, 512, 4096, 0, 2, 80};
        g.n = 6; g.alpha = 1.f;
        bgemmN<3><<<dim3(80, 8), 256, 0, stream>>>(g);
        cast_f2b<<<256, 256, 0, stream>>>(GxF, Gx,
            768 * 768 + 512 * 512 + 256 * 256 + 256 * 256 + 768 * 256 + 512 * 256);
    }

    // ===== 7. cost matrices Cu, cosp, Tb in ONE batched bf16 dispatch =====
    {
        BGNArgs g;
        g.d[0] = {fXn, fYn, nullptr, Cu, nullptr, nullptr, 4096, 4096, 256, 256, 0, 32, 1024};
        g.d[1] = {fXp, fYp, nullptr, cosp, nullptr, nullptr, 2048, 2048, 256, 256, 0, 16, 1280};
        g.d[2] = {Xn, SxyT, nullptr, Tb, nullptr, nullptr, 4096, 512, 768, 768, 0, 4, 1408};
        g.n = 3; g.alpha = 1.f;
        bgemmN<1><<<dim3(1408, 1), 256, 0, stream>>>(g);
    }
    // Ca = Tb @ Yn^T
    gemm_bt<1><<<dim3(32, 32), 256, 0, stream>>>(Tb, Yn, nullptr, Ca, 4096, 4096, 512, 512, 1.f);

    // ===== 8. transposes C: CuT, cospT, CaT =====
    {
        TPArgs a;
        a.d[0] = {Cu, CuT, 4096, 4096, 128, 16384, nullptr};
        a.d[1] = {cosp, cospT, 2048, 2048, 64, 20480, nullptr};
        a.d[2] = {Ca, CaT, 4096, 4096, 128, 36864, nullptr};
        a.n = 3;
        transpose_batch<<<36864, 256, 0, stream>>>(a);
    }

    // ===== 9. L_div tail: Hb, then H2/D1 with fused Sxy-dot epilogues =====
    gemm_bt<3><<<dim3(4, 6, 4), 256, 0, stream>>>(Gx, SxyT, HbF, nullptr, 768, 512, 192, 768, 1.f);
    cast_f2b<<<256, 256, 0, stream>>>(HbF, Hb, 768 * 512);
    {
        BGNArgs g;
        g.d[0] = {Hb, Gy, nullptr, nullptr, SxyT, slots + 5, 768, 512, 128, 512, 768, 4, 24};
        g.d[1] = {A1b, B1Tb, nullptr, nullptr, SxyT, slots + 7, 768, 512, 64, 256, 768, 4, 48};
        g.n = 2; g.alpha = 1.f;
        bgemmN<2><<<dim3(48, 4), 256, 0, stream>>>(g);
    }
    dot_bb<<<64, 256, 0, stream>>>(Gfx, Gfy, 256 * 256, slots + 6);

    // ===== 10. triple-fused sinkhorn (latent + anchor + pairs), 10 iters =====
    {
        float lm12 = -logf(4096.f), lm3 = -logf(2048.f);
        for (int it = 0; it < 10; ++it) {
            row_lse_tri<<<2560, 256, 0, stream>>>(Cu, vu, uu, Ca, va, ua, cosp, vp, up, SCALE, lm12, lm3);
            row_lse_tri<<<2560, 256, 0, stream>>>(CuT, uu, vu, CaT, ua, va, cospT, up, vp, SCALE, lm12, lm3);
        }
    }

    // ===== 11. fused plan + au + L_ot + pairs rowsums (one dispatch) =====
    plan_ot<<<1536, 256, 0, stream>>>(Cu, Ca, cosp, uu, vu, ua, va, up, vp,
                                      plan, au, ap, slots + 4, SCALE);
    marg2<<<2, 256, 0, stream>>>(ap, au, slots + 0);
    diag2<<<1, 256, 0, stream>>>(cosp, up, vp, 2048, SCALE, slots + 2, slots + 3);
    sail_row_w<<<512, 256, 0, stream>>>(cosp, 2048, 10.f, slots + 1);

    // ===== 12. GW via low-rank identities (slice split-K, no atomics) =====
    // transposes D: XuT, YuT (S2; CuT dead), XsT = au-scaled (S3; Ca dead)
    {
        TPArgs a;
        a.d[0] = {Xu, XuT, 4096, 768, 24, 3072, nullptr};
        a.d[1] = {Yu, YuT, 4096, 512, 16, 5120, nullptr};
        a.d[2] = {Xu, XsT, 4096, 768, 24, 8192, au};
        a.n = 3;
        transpose_batch<<<8192, 256, 0, stream>>>(a);
    }
    // ONE slice-split-K4 batch: T1S = YuT @ plan^T slices, W1S, W2S (streaming stores)
    {
        BGNArgs g;
        g.d[0] = {YuT, plan, T1S, nullptr, nullptr, nullptr, 512, 4096, 1024, 4096, 0, 32, 128};
        g.d[1] = {XsT, XuT, W1S, nullptr, nullptr, nullptr, 768, 768, 1024, 4096, 0, 6, 164};
        g.d[2] = {YuT, YuT, W2S, nullptr, nullptr, nullptr, 512, 512, 1024, 4096, 0, 4, 180};
        g.n = 3; g.alpha = 1.f;
        bgemmN<4><<<dim3(180, 4), 256, 0, stream>>>(g);
    }
    // reduce slices: T1T bf16 (S1; Cu dead), ||W1||^2 -> slot8, ||W2/4096||^2 -> slot9
    gw_reduce<<<564, 256, 0, stream>>>(T1S, T1T, W1S, W2S, slots + 8, slots + 9);
    // M = XuT @ T1T^T (split-K8 atomic into MF, zeroed)
    {
        BGNArgs g;
        g.d[0] = {XuT, T1T, MF, nullptr, nullptr, nullptr, 768, 512, 512, 4096, 0, 4, 24};
        g.n = 1; g.alpha = 1.f;
        bgemmN<3><<<dim3(24, 8), 256, 0, stream>>>(g);
    }
    sumsq<<<32, 256, 0, stream>>>(MF, 768 * 512, slots + 10);

    combine<<<1, 1, 0, stream>>>(slots, out);
}